// Round 2
// baseline (2021.958 us; speedup 1.0000x reference)
//
#include <hip/hip_runtime.h>
#include <hip/hip_bf16.h>

// ---------------- sizes ----------------
#define BB 32
#define TW 40
#define NN 50
#define CIN 2
#define HH 128
#define CO 64
#define EE 800
#define TT 38      // Tw - 2
#define TT2 36     // TT - 2
#define TPOOL 34   // TT2 - 2
#define NCO 3200   // N*Co

// ws layout (floats)
#define OFF_T0   0
#define SZ_T0    (BB*TT*NN*HH)            // 7,782,400
#define OFF_T2   (OFF_T0 + SZ_T0)
#define SZ_T2    (BB*TT2*NN*CO)           // 3,686,400
#define OFF_U    (OFF_T2 + SZ_T2)
#define SZ_U     (3*NCO*BB)               // 307,200
#define OFF_PL   (OFF_U + SZ_U)
#define SZ_PL    (BB*128)                 // 4,096
#define OFF_ST   (OFF_PL + SZ_PL)
#define SZ_ST    128

// ---------------- kernel 1: gated temporal conv #1 ----------------
// X (B,40,50,2) -> T0 (B,38,50,128), conv along t, relu(P*sigmoid(Q)+R)
__global__ __launch_bounds__(128) void k_tconv1(
    const float* __restrict__ X,
    const float* __restrict__ w1, const float* __restrict__ b1,
    const float* __restrict__ w2, const float* __restrict__ b2,
    const float* __restrict__ w3, const float* __restrict__ b3,
    float* __restrict__ T0)
{
    int blk = blockIdx.x;                // (b*38+t)*50+n
    int h = threadIdx.x;                 // 0..127
    int n = blk % NN;
    int bt = blk / NN;
    int t = bt % TT;
    int b = bt / TT;

    const float* xp = X + ((size_t)(b * TW + t) * NN + n) * CIN;
    float xin[6];
#pragma unroll
    for (int k = 0; k < 3; k++) {
        xin[k * 2 + 0] = xp[k * (NN * CIN) + 0];
        xin[k * 2 + 1] = xp[k * (NN * CIN) + 1];
    }
    float P = b1[h], Q = b2[h], R = b3[h];
#pragma unroll
    for (int q = 0; q < 6; q++) {
        P += xin[q] * w1[q * HH + h];
        Q += xin[q] * w2[q * HH + h];
        R += xin[q] * w3[q * HH + h];
    }
    float sg = 1.f / (1.f + expf(-Q));
    float v = P * sg + R;
    v = v > 0.f ? v : 0.f;
    T0[(size_t)blk * HH + h] = v;
}

// ---------------- kernel 2: Chebyshev graph conv (per graph, in-place T0->G) ----------------
// out[n,o] = relu( b[o] + Tx0·(W0-W2) + Tx1·W1 + 2*prop(Tx1)·W2 )
__global__ __launch_bounds__(256) void k_cheb(
    const int* __restrict__ EI,
    const float* __restrict__ W,      // (3,128,128)
    const float* __restrict__ bias,   // (128,)
    float* __restrict__ T0G)
{
    __shared__ float A[NN * HH];
    __shared__ float Bf[NN * HH];
    __shared__ float we[EE];
    __shared__ float dis[NN];
    __shared__ int deg[NN];

    int s = blockIdx.x;              // 0..1215
    int tid = threadIdx.x;
    int b = s / TT, t = s % TT;
    const int* row = EI + (size_t)(b * TW + t) * 2 * EE;
    const int* col = row + EE;
    float* x = T0G + (size_t)s * (NN * HH);

    for (int i = tid; i < NN * HH; i += 256) A[i] = x[i];
    if (tid < NN) deg[tid] = 0;
    __syncthreads();
    for (int e = tid; e < EE; e += 256) atomicAdd(&deg[row[e]], 1);
    __syncthreads();
    if (tid < NN) dis[tid] = deg[tid] > 0 ? rsqrtf((float)deg[tid]) : 0.f;
    __syncthreads();
    for (int e = tid; e < EE; e += 256) we[e] = -dis[row[e]] * dis[col[e]];

    int o = tid & 127;
    int n0 = tid >> 7;               // 0 or 1
    float acc[25];
    float bo = bias[o];
#pragma unroll
    for (int i = 0; i < 25; i++) acc[i] = bo;

    const float* W0 = W;
    const float* W1 = W + HH * HH;
    const float* W2 = W + 2 * HH * HH;

    // einsum k=0 with folded -Tx0*W2 term
    for (int ff = 0; ff < HH; ff += 4) {
        float wv0 = W0[(ff + 0) * HH + o] - W2[(ff + 0) * HH + o];
        float wv1 = W0[(ff + 1) * HH + o] - W2[(ff + 1) * HH + o];
        float wv2 = W0[(ff + 2) * HH + o] - W2[(ff + 2) * HH + o];
        float wv3 = W0[(ff + 3) * HH + o] - W2[(ff + 3) * HH + o];
#pragma unroll
        for (int i = 0; i < 25; i++) {
            const float4 av = *(const float4*)&A[(n0 + 2 * i) * HH + ff];
            acc[i] += av.x * wv0 + av.y * wv1 + av.z * wv2 + av.w * wv3;
        }
    }

    // prop A -> Bf  (Tx1)
    for (int i = tid; i < NN * HH; i += 256) Bf[i] = 0.f;
    __syncthreads();   // we[] + Bf zeros ready; A reads for prop happen after
    int c = tid & 127;
    int e0 = (tid >> 7) * (EE / 2);
    for (int e = e0; e < e0 + EE / 2; e++) {
        int r = row[e]; int cc = col[e];
        atomicAdd(&Bf[r * HH + c], we[e] * A[cc * HH + c]);
    }
    __syncthreads();

    // einsum k=1
    for (int ff = 0; ff < HH; ff += 4) {
        float wv0 = W1[(ff + 0) * HH + o];
        float wv1 = W1[(ff + 1) * HH + o];
        float wv2 = W1[(ff + 2) * HH + o];
        float wv3 = W1[(ff + 3) * HH + o];
#pragma unroll
        for (int i = 0; i < 25; i++) {
            const float4 av = *(const float4*)&Bf[(n0 + 2 * i) * HH + ff];
            acc[i] += av.x * wv0 + av.y * wv1 + av.z * wv2 + av.w * wv3;
        }
    }

    // prop Bf -> A (A no longer needed as Tx0; scatter needs zeroed target)
    for (int i = tid; i < NN * HH; i += 256) A[i] = 0.f;
    __syncthreads();
    for (int e = e0; e < e0 + EE / 2; e++) {
        int r = row[e]; int cc = col[e];
        atomicAdd(&A[r * HH + c], we[e] * Bf[cc * HH + c]);
    }
    __syncthreads();

    // einsum k=2: contribution 2*prop(Tx1)*W2
    for (int ff = 0; ff < HH; ff += 4) {
        float wv0 = 2.f * W2[(ff + 0) * HH + o];
        float wv1 = 2.f * W2[(ff + 1) * HH + o];
        float wv2 = 2.f * W2[(ff + 2) * HH + o];
        float wv3 = 2.f * W2[(ff + 3) * HH + o];
#pragma unroll
        for (int i = 0; i < 25; i++) {
            const float4 av = *(const float4*)&A[(n0 + 2 * i) * HH + ff];
            acc[i] += av.x * wv0 + av.y * wv1 + av.z * wv2 + av.w * wv3;
        }
    }

    // relu + in-place store (this block's slice only; fully loaded at start)
#pragma unroll
    for (int i = 0; i < 25; i++) {
        float v = acc[i];
        v = v > 0.f ? v : 0.f;
        x[(n0 + 2 * i) * HH + o] = v;
    }
}

// ---------------- kernel 3: gated temporal conv #2 ----------------
// G (B,38,50,128) -> T2 (B,36,50,64)
__global__ __launch_bounds__(256) void k_tconv2(
    const float* __restrict__ G,
    const float* __restrict__ w1, const float* __restrict__ b1,
    const float* __restrict__ w2, const float* __restrict__ b2,
    const float* __restrict__ w3, const float* __restrict__ b3,
    float* __restrict__ T2)
{
    __shared__ float A[NN * HH];
    int blk = blockIdx.x;            // b*36+t
    int b = blk / TT2, t = blk % TT2;
    int tid = threadIdx.x;
    int o = tid & 63;
    int nq = tid >> 6;               // 0..3 (wave-uniform)
    const int NJ = (nq < 2) ? 13 : 12;

    float accP[13], accQ[13], accR[13];
#pragma unroll
    for (int j = 0; j < 13; j++) { accP[j] = 0.f; accQ[j] = 0.f; accR[j] = 0.f; }

    for (int k = 0; k < 3; k++) {
        __syncthreads();
        const float* src = G + (size_t)(b * TT + t + k) * (NN * HH);
        for (int i = tid; i < NN * HH; i += 256) A[i] = src[i];
        __syncthreads();
        const float* wk1 = w1 + k * HH * CO;
        const float* wk2 = w2 + k * HH * CO;
        const float* wk3 = w3 + k * HH * CO;
        for (int ff = 0; ff < HH; ff += 4) {
            float vP[4], vQ[4], vR[4];
#pragma unroll
            for (int u = 0; u < 4; u++) {
                vP[u] = wk1[(ff + u) * CO + o];
                vQ[u] = wk2[(ff + u) * CO + o];
                vR[u] = wk3[(ff + u) * CO + o];
            }
            for (int j = 0; j < NJ; j++) {
                const float4 av = *(const float4*)&A[(nq + 4 * j) * HH + ff];
                accP[j] += av.x * vP[0] + av.y * vP[1] + av.z * vP[2] + av.w * vP[3];
                accQ[j] += av.x * vQ[0] + av.y * vQ[1] + av.z * vQ[2] + av.w * vQ[3];
                accR[j] += av.x * vR[0] + av.y * vR[1] + av.z * vR[2] + av.w * vR[3];
            }
        }
    }
    float bP = b1[o], bQ = b2[o], bR = b3[o];
    for (int j = 0; j < NJ; j++) {
        float q = accQ[j] + bQ;
        float sg = 1.f / (1.f + expf(-q));
        float v = (accP[j] + bP) * sg + (accR[j] + bR);
        v = v > 0.f ? v : 0.f;
        T2[((size_t)blk * NN + (nq + 4 * j)) * CO + o] = v;
    }
}

// ---------------- kernel 4: BN stats per node ----------------
__global__ __launch_bounds__(256) void k_bnstats(const float* __restrict__ T2, float* __restrict__ stats)
{
    int n = blockIdx.x;              // 0..49
    int tid = threadIdx.x;
    float s = 0.f, ss = 0.f;
    const int TOT = BB * TT2 * CO;   // 73728
    for (int i = tid; i < TOT; i += 256) {
        int o = i & 63;
        int bt = i >> 6;             // 0..1151
        float v = T2[((size_t)bt * NN + n) * CO + o];
        s += v; ss += v * v;
    }
    __shared__ float rs[256], rss[256];
    rs[tid] = s; rss[tid] = ss;
    __syncthreads();
    for (int off = 128; off > 0; off >>= 1) {
        if (tid < off) { rs[tid] += rs[tid + off]; rss[tid] += rss[tid + off]; }
        __syncthreads();
    }
    if (tid == 0) {
        float m = rs[0] / (float)TOT;
        float var = rss[0] / (float)TOT - m * m;
        stats[n] = m;
        stats[NN + n] = rsqrtf(var + 1e-5f);
    }
}

// ---------------- kernel 5: windowed t-sums with BN folded ----------------
// U[k,j,b] = sum_{t=0..33} BN(T2[b, t+k, j])
__global__ __launch_bounds__(256) void k_u(
    const float* __restrict__ T2, const float* __restrict__ stats,
    const float* __restrict__ gamma, const float* __restrict__ beta,
    float* __restrict__ U)
{
    int idx = blockIdx.x * 256 + threadIdx.x;     // (b*3+k)*3200 + j
    if (idx >= BB * 3 * NCO) return;
    int j = idx % NCO;
    int bk = idx / NCO;
    int k = bk % 3;
    int b = bk / 3;
    int n = j >> 6;
    float m = stats[n], is = stats[NN + n];
    float g = gamma[n], be = beta[n];
    float sum = 0.f;
    const float* p = T2 + ((size_t)b * TT2 + k) * NCO + j;
    for (int t = 0; t < TPOOL; t++) sum += p[(size_t)t * NCO];
    float r = (sum - (float)TPOOL * m) * (is * g) + (float)TPOOL * be;
    U[((size_t)(k * NCO + j)) * BB + b] = r;
}

// ---------------- kernel 6: conv3 reduced GEMM + pool ----------------
// pooled[b,o] = conv3_b[o] + (1/34) * sum_{k,j} W3[o,k,j]*U[k,j,b]
__global__ __launch_bounds__(256) void k_pool(
    const float* __restrict__ W3, const float* __restrict__ b3c,
    const float* __restrict__ U, float* __restrict__ pooled)
{
    int o = blockIdx.x;              // 0..127
    int tid = threadIdx.x;
    float acc[32];
#pragma unroll
    for (int b = 0; b < 32; b++) acc[b] = 0.f;
    const float* wp = W3 + (size_t)o * (3 * NCO);
    for (int idx = tid; idx < 3 * NCO; idx += 256) {
        float w = wp[idx];
        const float4* up4 = (const float4*)(U + (size_t)idx * BB);
#pragma unroll
        for (int b4 = 0; b4 < 8; b4++) {
            float4 u = up4[b4];
            acc[b4 * 4 + 0] += w * u.x;
            acc[b4 * 4 + 1] += w * u.y;
            acc[b4 * 4 + 2] += w * u.z;
            acc[b4 * 4 + 3] += w * u.w;
        }
    }
    __shared__ float red[4 * 32];
    int lane = tid & 63, wid = tid >> 6;
#pragma unroll
    for (int b = 0; b < 32; b++) {
        float v = acc[b];
        for (int off = 32; off > 0; off >>= 1) v += __shfl_down(v, off, 64);
        if (lane == 0) red[wid * 32 + b] = v;
    }
    __syncthreads();
    if (tid < 32) {
        float sum = red[tid] + red[32 + tid] + red[64 + tid] + red[96 + tid];
        pooled[tid * 128 + o] = b3c[o] + sum * (1.f / (float)TPOOL);
    }
}

// ---------------- kernel 7: final FC ----------------
__global__ __launch_bounds__(256) void k_final(
    const float* __restrict__ pooled, const float* __restrict__ f1w,
    const float* __restrict__ f1b, float* __restrict__ out)
{
    int idx = blockIdx.x * 256 + threadIdx.x;
    if (idx >= BB * NCO) return;
    int q = idx % NCO;
    int b = idx / NCO;
    float acc = f1b[q];
    const float* pp = pooled + b * 128;
    for (int o = 0; o < 128; o++) acc += pp[o] * f1w[(size_t)o * NCO + q];
    out[idx] = acc;
}

// ---------------- launch ----------------
extern "C" void kernel_launch(void* const* d_in, const int* in_sizes, int n_in,
                              void* d_out, int out_size, void* d_ws, size_t ws_size,
                              hipStream_t stream)
{
    const float* X       = (const float*)d_in[0];
    const int*   EI      = (const int*)d_in[1];
    const float* tc1_w1  = (const float*)d_in[2];
    const float* tc1_b1  = (const float*)d_in[3];
    const float* tc1_w2  = (const float*)d_in[4];
    const float* tc1_b2  = (const float*)d_in[5];
    const float* tc1_w3  = (const float*)d_in[6];
    const float* tc1_b3  = (const float*)d_in[7];
    const float* cheb_w  = (const float*)d_in[8];
    const float* cheb_b  = (const float*)d_in[9];
    const float* tc2_w1  = (const float*)d_in[10];
    const float* tc2_b1  = (const float*)d_in[11];
    const float* tc2_w2  = (const float*)d_in[12];
    const float* tc2_b2  = (const float*)d_in[13];
    const float* tc2_w3  = (const float*)d_in[14];
    const float* tc2_b3  = (const float*)d_in[15];
    const float* bn_g    = (const float*)d_in[16];
    const float* bn_b    = (const float*)d_in[17];
    const float* conv3_w = (const float*)d_in[18];
    const float* conv3_b = (const float*)d_in[19];
    const float* f1_w    = (const float*)d_in[20];
    const float* f1_b    = (const float*)d_in[21];

    float* ws = (float*)d_ws;
    float* T0G    = ws + OFF_T0;
    float* T2     = ws + OFF_T2;
    float* U      = ws + OFF_U;
    float* pooled = ws + OFF_PL;
    float* stats  = ws + OFF_ST;

    k_tconv1<<<BB * TT * NN, 128, 0, stream>>>(X, tc1_w1, tc1_b1, tc1_w2, tc1_b2, tc1_w3, tc1_b3, T0G);
    k_cheb<<<BB * TT, 256, 0, stream>>>(EI, cheb_w, cheb_b, T0G);
    k_tconv2<<<BB * TT2, 256, 0, stream>>>(T0G, tc2_w1, tc2_b1, tc2_w2, tc2_b2, tc2_w3, tc2_b3, T2);
    k_bnstats<<<NN, 256, 0, stream>>>(T2, stats);
    k_u<<<(BB * 3 * NCO + 255) / 256, 256, 0, stream>>>(T2, stats, bn_g, bn_b, U);
    k_pool<<<128, 256, 0, stream>>>(conv3_w, conv3_b, U, pooled);
    k_final<<<(BB * NCO + 255) / 256, 256, 0, stream>>>(pooled, f1_w, f1_b, (float*)d_out);
}

// Round 3
// 519.932 us; speedup vs baseline: 3.8889x; 3.8889x over previous
//
#include <hip/hip_runtime.h>
#include <hip/hip_bf16.h>

// ---------------- sizes ----------------
#define BB 32
#define TW 40
#define NN 50
#define HH 128
#define CO 64
#define EE 800
#define TT 38      // Tw - 2
#define TT2 36     // TT - 2
#define TPOOL 34   // TT2 - 2
#define NCO 3200   // N*Co
#define SS (BB*TT) // 1216 graphs
#define ME (SS*NN)     // 60800 einsum rows
#define MT (BB*TT2*NN) // 57600 tconv2 rows

// ws layout (floats). Peak live set: T0 + P1 + P2 (+ small weights) ~ 94 MB.
#define OFF_T0   0
#define SZ_T0    (SS*NN*HH)               // 7,782,400
#define OFF_P1   (OFF_T0 + SZ_T0)
#define OFF_P2   (OFF_P1 + SZ_T0)
#define OFF_W    (OFF_P2 + SZ_T0)         // Veff (49152) + Wcat (73728)
#define SZ_W     (384*128 + 384*192)
// overlays (dead regions reused):
//   T2     -> OFF_P2 (P2 dead after einsum)     needs 3,686,400 < SZ_T0
//   U      -> OFF_P1 (P1 dead after einsum)     needs 307,200
//   pooled -> OFF_P1 + 307200                   needs 4096
//   stats  -> OFF_P1 + 311296                   needs 128

// ---------------- kernel 1: gated temporal conv #1 ----------------
__global__ __launch_bounds__(128) void k_tconv1(
    const float* __restrict__ X,
    const float* __restrict__ w1, const float* __restrict__ b1,
    const float* __restrict__ w2, const float* __restrict__ b2,
    const float* __restrict__ w3, const float* __restrict__ b3,
    float* __restrict__ T0)
{
    int blk = blockIdx.x;                // (b*38+t)*50+n
    int h = threadIdx.x;
    int n = blk % NN;
    int bt = blk / NN;
    int t = bt % TT;
    int b = bt / TT;

    const float* xp = X + ((size_t)(b * TW + t) * NN + n) * 2;
    float xin[6];
#pragma unroll
    for (int k = 0; k < 3; k++) {
        xin[k * 2 + 0] = xp[k * (NN * 2) + 0];
        xin[k * 2 + 1] = xp[k * (NN * 2) + 1];
    }
    float P = b1[h], Q = b2[h], R = b3[h];
#pragma unroll
    for (int q = 0; q < 6; q++) {
        P += xin[q] * w1[q * HH + h];
        Q += xin[q] * w2[q * HH + h];
        R += xin[q] * w3[q * HH + h];
    }
    float sg = 1.f / (1.f + expf(-Q));
    float v = P * sg + R;
    T0[(size_t)blk * HH + h] = v > 0.f ? v : 0.f;
}

// ---------------- kernel 2: weight prep ----------------
// Veff[384][128] = [W0-W2 ; W1 ; 2*W2]   (cheb folded recurrence)
// Wcat[384][192] : col o*3+g = tc2_w{g+1}[k][f][o], row kk=k*128+f
__global__ __launch_bounds__(256) void k_wprep(
    const float* __restrict__ cw,
    const float* __restrict__ tw1, const float* __restrict__ tw2, const float* __restrict__ tw3,
    float* __restrict__ Veff, float* __restrict__ Wcat)
{
    int idx = blockIdx.x * 256 + threadIdx.x;
    if (idx < 384 * 128) {
        int kk = idx >> 7, o = idx & 127;
        float v;
        if (kk < 128)      v = cw[kk * 128 + o] - cw[2 * 16384 + kk * 128 + o];
        else if (kk < 256) v = cw[16384 + (kk - 128) * 128 + o];
        else               v = 2.f * cw[32768 + (kk - 256) * 128 + o];
        Veff[idx] = v;
    } else if (idx < 384 * 128 + 384 * 192) {
        int j = idx - 384 * 128;
        int kk = j / 192, col = j % 192;
        int o = col / 3, g = col % 3;
        const float* src = (g == 0) ? tw1 : (g == 1) ? tw2 : tw3;
        Wcat[j] = src[kk * 64 + o];
    }
}

// ---------------- kernel 3: Cheb propagation via dense Laplacian ----------------
// Per graph: build L (50x50) in LDS from edges, P1 = L*T0_s, P2 = L*P1.
#define LST 52   // padded L/A row strides
__global__ __launch_bounds__(256) void k_prop(
    const int* __restrict__ EI,
    const float* __restrict__ T0,
    float* __restrict__ P1, float* __restrict__ P2)
{
    __shared__ float Lm[52 * LST];       // rows 50,51 + cols 50,51 zero
    __shared__ float Abuf[52 * HH];      // rows 50,51 zero
    __shared__ float Bbuf[52 * HH];
    __shared__ float dis[NN];
    __shared__ int   deg[NN];

    int s = blockIdx.x;
    int tid = threadIdx.x;
    int b = s / TT, t = s % TT;
    const int* row = EI + (size_t)(b * TW + t) * 2 * EE;
    const int* col = row + EE;

    for (int i = tid; i < 52 * LST; i += 256) Lm[i] = 0.f;
    for (int i = tid; i < 52 * HH; i += 256) Abuf[i] = (i < NN * HH) ? T0[(size_t)s * (NN * HH) + i] : 0.f;
    for (int i = NN * HH + tid; i < 52 * HH; i += 256) Bbuf[i] = 0.f;
    if (tid < NN) deg[tid] = 0;
    __syncthreads();
    for (int e = tid; e < EE; e += 256) atomicAdd(&deg[row[e]], 1);
    __syncthreads();
    if (tid < NN) dis[tid] = deg[tid] > 0 ? rsqrtf((float)deg[tid]) : 0.f;
    __syncthreads();
    for (int e = tid; e < EE; e += 256) {
        int r = row[e], c = col[e];
        atomicAdd(&Lm[r * LST + c], -dis[r] * dis[c]);
    }
    __syncthreads();

    int c = tid & 63;                    // channels c and c+64
    int g = tid >> 6;                    // wave id -> row group (uniform per wave)
    int n0 = g * 13;

    float acc0[13], acc1[13];

    // ---- prop1: B = L*A ----
#pragma unroll
    for (int j = 0; j < 13; j++) { acc0[j] = 0.f; acc1[j] = 0.f; }
    for (int mc = 0; mc < 13; mc++) {
        float a0[4], a1[4];
#pragma unroll
        for (int u = 0; u < 4; u++) {
            a0[u] = Abuf[(mc * 4 + u) * HH + c];
            a1[u] = Abuf[(mc * 4 + u) * HH + c + 64];
        }
        const float* lrow = &Lm[n0 * LST + mc * 4];
#pragma unroll
        for (int j = 0; j < 13; j++) {
            float4 l = *(const float4*)(lrow + j * LST);
            acc0[j] += l.x * a0[0] + l.y * a0[1] + l.z * a0[2] + l.w * a0[3];
            acc1[j] += l.x * a1[0] + l.y * a1[1] + l.z * a1[2] + l.w * a1[3];
        }
    }
#pragma unroll
    for (int j = 0; j < 13; j++) {
        int n = n0 + j;
        if (n < NN) {
            Bbuf[n * HH + c] = acc0[j];
            Bbuf[n * HH + c + 64] = acc1[j];
            P1[(size_t)s * (NN * HH) + n * HH + c] = acc0[j];
            P1[(size_t)s * (NN * HH) + n * HH + c + 64] = acc1[j];
        }
    }
    __syncthreads();

    // ---- prop2: P2 = L*B ----
#pragma unroll
    for (int j = 0; j < 13; j++) { acc0[j] = 0.f; acc1[j] = 0.f; }
    for (int mc = 0; mc < 13; mc++) {
        float a0[4], a1[4];
#pragma unroll
        for (int u = 0; u < 4; u++) {
            a0[u] = Bbuf[(mc * 4 + u) * HH + c];
            a1[u] = Bbuf[(mc * 4 + u) * HH + c + 64];
        }
        const float* lrow = &Lm[n0 * LST + mc * 4];
#pragma unroll
        for (int j = 0; j < 13; j++) {
            float4 l = *(const float4*)(lrow + j * LST);
            acc0[j] += l.x * a0[0] + l.y * a0[1] + l.z * a0[2] + l.w * a0[3];
            acc1[j] += l.x * a1[0] + l.y * a1[1] + l.z * a1[2] + l.w * a1[3];
        }
    }
#pragma unroll
    for (int j = 0; j < 13; j++) {
        int n = n0 + j;
        if (n < NN) {
            P2[(size_t)s * (NN * HH) + n * HH + c] = acc0[j];
            P2[(size_t)s * (NN * HH) + n * HH + c + 64] = acc1[j];
        }
    }
}

// ---------------- kernel 4: cheb einsum GEMM ----------------
// G[r][o] = relu(bias[o] + sum_kk [T0;P1;P2][r][kk] * Veff[kk][o]), in-place into T0.
__global__ __launch_bounds__(256) void k_einsum(
    const float* __restrict__ P1, const float* __restrict__ P2,
    const float* __restrict__ Veff, const float* __restrict__ bias,
    float* __restrict__ T0)
{
    __shared__ float At[32 * 128];   // [kk][m]
    __shared__ float Wt[32 * 128];   // [kk][o]
    int tid = threadIdx.x;
    int M0 = blockIdx.x * 128;
    int tm = tid & 15, to = tid >> 4;

    float acc[8][8];
#pragma unroll
    for (int i = 0; i < 8; i++)
#pragma unroll
        for (int j = 0; j < 8; j++) acc[i][j] = 0.f;

    for (int kt = 0; kt < 12; kt++) {
        const float* src = (kt < 4) ? T0 : (kt < 8) ? P1 : P2;
        const int f0 = (kt & 3) << 5;
        {   // stage A (transposed)
            const int m = tid >> 1, half = tid & 1;
            const float* p = src + (size_t)(M0 + m) * 128 + f0 + half * 16;
#pragma unroll
            for (int q = 0; q < 4; q++) {
                float4 v = *(const float4*)(p + q * 4);
                int kb = half * 16 + q * 4;
                At[(kb + 0) * 128 + m] = v.x;
                At[(kb + 1) * 128 + m] = v.y;
                At[(kb + 2) * 128 + m] = v.z;
                At[(kb + 3) * 128 + m] = v.w;
            }
        }
        {   // stage W
            const int kk = tid >> 3, oq = tid & 7;
            const float* p = Veff + (size_t)(kt * 32 + kk) * 128 + oq * 16;
            float* q0 = &Wt[kk * 128 + oq * 16];
#pragma unroll
            for (int q = 0; q < 4; q++) *(float4*)(q0 + q * 4) = *(const float4*)(p + q * 4);
        }
        __syncthreads();
#pragma unroll 2
        for (int kk = 0; kk < 32; kk++) {
            float4 a0 = *(const float4*)&At[kk * 128 + tm * 8];
            float4 a1 = *(const float4*)&At[kk * 128 + tm * 8 + 4];
            float4 w0 = *(const float4*)&Wt[kk * 128 + to * 8];
            float4 w1 = *(const float4*)&Wt[kk * 128 + to * 8 + 4];
            float a[8] = {a0.x, a0.y, a0.z, a0.w, a1.x, a1.y, a1.z, a1.w};
            float w[8] = {w0.x, w0.y, w0.z, w0.w, w1.x, w1.y, w1.z, w1.w};
#pragma unroll
            for (int i = 0; i < 8; i++)
#pragma unroll
                for (int j = 0; j < 8; j++) acc[i][j] += a[i] * w[j];
        }
        __syncthreads();
    }

    float4 bv0 = *(const float4*)&bias[to * 8];
    float4 bv1 = *(const float4*)&bias[to * 8 + 4];
    float bb[8] = {bv0.x, bv0.y, bv0.z, bv0.w, bv1.x, bv1.y, bv1.z, bv1.w};
#pragma unroll
    for (int i = 0; i < 8; i++) {
        size_t r = (size_t)(M0 + tm * 8 + i);
        float o0[4], o1[4];
#pragma unroll
        for (int j = 0; j < 4; j++) {
            float v = acc[i][j] + bb[j];
            o0[j] = v > 0.f ? v : 0.f;
            float v2 = acc[i][j + 4] + bb[j + 4];
            o1[j] = v2 > 0.f ? v2 : 0.f;
        }
        *(float4*)&T0[r * 128 + to * 8]     = make_float4(o0[0], o0[1], o0[2], o0[3]);
        *(float4*)&T0[r * 128 + to * 8 + 4] = make_float4(o1[0], o1[1], o1[2], o1[3]);
    }
}

// ---------------- kernel 5: tconv2 GEMM with gated epilogue ----------------
// rows r=(b*36+t)*50+n, K=384 (3 taps x 128), N=192 (gate-interleaved), out T2[r][64]
__global__ __launch_bounds__(256) void k_tc2(
    const float* __restrict__ G, const float* __restrict__ Wcat,
    const float* __restrict__ b1, const float* __restrict__ b2, const float* __restrict__ b3,
    float* __restrict__ T2)
{
    __shared__ float At[32 * 64];    // [kk][m]
    __shared__ float Wt[32 * 192];   // [kk][j]
    __shared__ int gb[64];
    int tid = threadIdx.x;
    int M0 = blockIdx.x * 64;
    if (tid < 64) {
        int r = M0 + tid;
        int b = r / 1800, rem = r % 1800;
        gb[tid] = ((b * TT + rem / NN) * NN + rem % NN) * 128;
    }
    __syncthreads();
    const int mload = tid >> 2, qload = tid & 3;
    const int abase = gb[mload];
    int tm = tid & 15, to = tid >> 4;

    float acc[4][12];
#pragma unroll
    for (int i = 0; i < 4; i++)
#pragma unroll
        for (int j = 0; j < 12; j++) acc[i][j] = 0.f;

    for (int kt = 0; kt < 12; kt++) {
        const int k3 = kt >> 2;
        const int f0 = (kt & 3) << 5;
        {   // stage A
            const float* p = G + abase + k3 * (NN * HH) + f0 + qload * 8;
            float4 v0 = *(const float4*)p;
            float4 v1 = *(const float4*)(p + 4);
            int kb = qload * 8;
            At[(kb + 0) * 64 + mload] = v0.x;
            At[(kb + 1) * 64 + mload] = v0.y;
            At[(kb + 2) * 64 + mload] = v0.z;
            At[(kb + 3) * 64 + mload] = v0.w;
            At[(kb + 4) * 64 + mload] = v1.x;
            At[(kb + 5) * 64 + mload] = v1.y;
            At[(kb + 6) * 64 + mload] = v1.z;
            At[(kb + 7) * 64 + mload] = v1.w;
        }
        {   // stage W
            const int kk = tid >> 3, oq = tid & 7;
            const float* wp = Wcat + (size_t)(kt * 32 + kk) * 192 + oq * 24;
            float* q0 = &Wt[kk * 192 + oq * 24];
#pragma unroll
            for (int q = 0; q < 6; q++) *(float4*)(q0 + q * 4) = *(const float4*)(wp + q * 4);
        }
        __syncthreads();
#pragma unroll 2
        for (int kk = 0; kk < 32; kk++) {
            float4 a = *(const float4*)&At[kk * 64 + tm * 4];
            float4 w0 = *(const float4*)&Wt[kk * 192 + to * 12];
            float4 w1 = *(const float4*)&Wt[kk * 192 + to * 12 + 4];
            float4 w2 = *(const float4*)&Wt[kk * 192 + to * 12 + 8];
            float av[4] = {a.x, a.y, a.z, a.w};
            float wv[12] = {w0.x, w0.y, w0.z, w0.w, w1.x, w1.y, w1.z, w1.w, w2.x, w2.y, w2.z, w2.w};
#pragma unroll
            for (int i = 0; i < 4; i++)
#pragma unroll
                for (int j = 0; j < 12; j++) acc[i][j] += av[i] * wv[j];
        }
        __syncthreads();
    }

    const int o0 = to * 4;
    float bP[4], bQ[4], bR[4];
#pragma unroll
    for (int u = 0; u < 4; u++) { bP[u] = b1[o0 + u]; bQ[u] = b2[o0 + u]; bR[u] = b3[o0 + u]; }
#pragma unroll
    for (int i = 0; i < 4; i++) {
        size_t r = (size_t)(M0 + tm * 4 + i);
        float ov[4];
#pragma unroll
        for (int u = 0; u < 4; u++) {
            float P = acc[i][u * 3 + 0] + bP[u];
            float Q = acc[i][u * 3 + 1] + bQ[u];
            float R = acc[i][u * 3 + 2] + bR[u];
            float sg = 1.f / (1.f + expf(-Q));
            float v = P * sg + R;
            ov[u] = v > 0.f ? v : 0.f;
        }
        *(float4*)&T2[r * CO + o0] = make_float4(ov[0], ov[1], ov[2], ov[3]);
    }
}

// ---------------- kernel 6: BN stats per node ----------------
__global__ __launch_bounds__(256) void k_bnstats(const float* __restrict__ T2, float* __restrict__ stats)
{
    int n = blockIdx.x;
    int tid = threadIdx.x;
    float s = 0.f, ss = 0.f;
    const int TOT = BB * TT2 * CO;   // 73728
    for (int i = tid; i < TOT; i += 256) {
        int o = i & 63;
        int bt = i >> 6;
        float v = T2[((size_t)bt * NN + n) * CO + o];
        s += v; ss += v * v;
    }
    __shared__ float rs[256], rss[256];
    rs[tid] = s; rss[tid] = ss;
    __syncthreads();
    for (int off = 128; off > 0; off >>= 1) {
        if (tid < off) { rs[tid] += rs[tid + off]; rss[tid] += rss[tid + off]; }
        __syncthreads();
    }
    if (tid == 0) {
        float m = rs[0] / (float)TOT;
        float var = rss[0] / (float)TOT - m * m;
        stats[n] = m;
        stats[NN + n] = rsqrtf(var + 1e-5f);
    }
}

// ---------------- kernel 7: windowed t-sums with BN folded ----------------
__global__ __launch_bounds__(256) void k_u(
    const float* __restrict__ T2, const float* __restrict__ stats,
    const float* __restrict__ gamma, const float* __restrict__ beta,
    float* __restrict__ U)
{
    int idx = blockIdx.x * 256 + threadIdx.x;     // (b*3+k)*3200 + j
    if (idx >= BB * 3 * NCO) return;
    int j = idx % NCO;
    int bk = idx / NCO;
    int k = bk % 3;
    int b = bk / 3;
    int n = j >> 6;
    float m = stats[n], is = stats[NN + n];
    float g = gamma[n], be = beta[n];
    float sum = 0.f;
    const float* p = T2 + ((size_t)b * TT2 + k) * NCO + j;
    for (int t = 0; t < TPOOL; t++) sum += p[(size_t)t * NCO];
    float r = (sum - (float)TPOOL * m) * (is * g) + (float)TPOOL * be;
    U[((size_t)(k * NCO + j)) * BB + b] = r;
}

// ---------------- kernel 8: conv3 reduced GEMM + pool ----------------
__global__ __launch_bounds__(256) void k_pool(
    const float* __restrict__ W3, const float* __restrict__ b3c,
    const float* __restrict__ U, float* __restrict__ pooled)
{
    int o = blockIdx.x;
    int tid = threadIdx.x;
    float acc[32];
#pragma unroll
    for (int b = 0; b < 32; b++) acc[b] = 0.f;
    const float* wp = W3 + (size_t)o * (3 * NCO);
    for (int idx = tid; idx < 3 * NCO; idx += 256) {
        float w = wp[idx];
        const float4* up4 = (const float4*)(U + (size_t)idx * BB);
#pragma unroll
        for (int b4 = 0; b4 < 8; b4++) {
            float4 u = up4[b4];
            acc[b4 * 4 + 0] += w * u.x;
            acc[b4 * 4 + 1] += w * u.y;
            acc[b4 * 4 + 2] += w * u.z;
            acc[b4 * 4 + 3] += w * u.w;
        }
    }
    __shared__ float red[4 * 32];
    int lane = tid & 63, wid = tid >> 6;
#pragma unroll
    for (int b = 0; b < 32; b++) {
        float v = acc[b];
        for (int off = 32; off > 0; off >>= 1) v += __shfl_down(v, off, 64);
        if (lane == 0) red[wid * 32 + b] = v;
    }
    __syncthreads();
    if (tid < 32) {
        float sum = red[tid] + red[32 + tid] + red[64 + tid] + red[96 + tid];
        pooled[tid * 128 + o] = b3c[o] + sum * (1.f / (float)TPOOL);
    }
}

// ---------------- kernel 9: final FC ----------------
__global__ __launch_bounds__(256) void k_final(
    const float* __restrict__ pooled, const float* __restrict__ f1w,
    const float* __restrict__ f1b, float* __restrict__ out)
{
    int idx = blockIdx.x * 256 + threadIdx.x;
    if (idx >= BB * NCO) return;
    int q = idx % NCO;
    int b = idx / NCO;
    float acc = f1b[q];
    const float* pp = pooled + b * 128;
    for (int o = 0; o < 128; o++) acc += pp[o] * f1w[(size_t)o * NCO + q];
    out[idx] = acc;
}

// ---------------- launch ----------------
extern "C" void kernel_launch(void* const* d_in, const int* in_sizes, int n_in,
                              void* d_out, int out_size, void* d_ws, size_t ws_size,
                              hipStream_t stream)
{
    const float* X       = (const float*)d_in[0];
    const int*   EI      = (const int*)d_in[1];
    const float* tc1_w1  = (const float*)d_in[2];
    const float* tc1_b1  = (const float*)d_in[3];
    const float* tc1_w2  = (const float*)d_in[4];
    const float* tc1_b2  = (const float*)d_in[5];
    const float* tc1_w3  = (const float*)d_in[6];
    const float* tc1_b3  = (const float*)d_in[7];
    const float* cheb_w  = (const float*)d_in[8];
    const float* cheb_b  = (const float*)d_in[9];
    const float* tc2_w1  = (const float*)d_in[10];
    const float* tc2_b1  = (const float*)d_in[11];
    const float* tc2_w2  = (const float*)d_in[12];
    const float* tc2_b2  = (const float*)d_in[13];
    const float* tc2_w3  = (const float*)d_in[14];
    const float* tc2_b3  = (const float*)d_in[15];
    const float* bn_g    = (const float*)d_in[16];
    const float* bn_b    = (const float*)d_in[17];
    const float* conv3_w = (const float*)d_in[18];
    const float* conv3_b = (const float*)d_in[19];
    const float* f1_w    = (const float*)d_in[20];
    const float* f1_b    = (const float*)d_in[21];

    float* ws = (float*)d_ws;
    float* T0G    = ws + OFF_T0;
    float* P1     = ws + OFF_P1;
    float* P2     = ws + OFF_P2;
    float* Veff   = ws + OFF_W;
    float* Wcat   = ws + OFF_W + 384 * 128;
    float* T2     = ws + OFF_P2;             // overlay: P2 dead after einsum
    float* U      = ws + OFF_P1;             // overlay: P1 dead after einsum
    float* pooled = ws + OFF_P1 + 307200;
    float* stats  = ws + OFF_P1 + 311296;

    k_tconv1<<<SS * NN, 128, 0, stream>>>(X, tc1_w1, tc1_b1, tc1_w2, tc1_b2, tc1_w3, tc1_b3, T0G);
    k_wprep<<<(384 * 128 + 384 * 192 + 255) / 256, 256, 0, stream>>>(cheb_w, tc2_w1, tc2_w2, tc2_w3, Veff, Wcat);
    k_prop<<<SS, 256, 0, stream>>>(EI, T0G, P1, P2);
    k_einsum<<<ME / 128, 256, 0, stream>>>(P1, P2, Veff, cheb_b, T0G);
    k_tc2<<<MT / 64, 256, 0, stream>>>(T0G, Wcat, tc2_b1, tc2_b2, tc2_b3, T2);
    k_bnstats<<<NN, 256, 0, stream>>>(T2, stats);
    k_u<<<(BB * 3 * NCO + 255) / 256, 256, 0, stream>>>(T2, stats, bn_g, bn_b, U);
    k_pool<<<128, 256, 0, stream>>>(conv3_w, conv3_b, U, pooled);
    k_final<<<(BB * NCO + 255) / 256, 256, 0, stream>>>(pooled, f1_w, f1_b, (float*)d_out);
}

// Round 4
// 424.107 us; speedup vs baseline: 4.7676x; 1.2259x over previous
//
#include <hip/hip_runtime.h>
#include <hip/hip_bf16.h>

// ---------------- sizes ----------------
#define BB 32
#define TW 40
#define NN 50
#define HH 128
#define CO 64
#define EE 800
#define TT 38      // Tw - 2
#define TT2 36     // TT - 2
#define TPOOL 34   // TT2 - 2
#define NCO 3200   // N*Co
#define SS (BB*TT) // 1216 graphs
#define ME (SS*NN)     // 60800 einsum rows (= 950*64)
#define MT (BB*TT2*NN) // 57600 tconv2 rows (= 900*64)

// ws layout (floats)
#define OFF_T0   0
#define SZ_T0    (SS*NN*HH)               // 7,782,400
#define OFF_P1   (OFF_T0 + SZ_T0)
#define OFF_P2   (OFF_P1 + SZ_T0)
#define OFF_W    (OFF_P2 + SZ_T0)         // bf16 split weights (ushort): 2*(49152+73728) = 245760 us = 61440 floats
#define SZ_W     (384*128 + 384*192)      // 122880 floats budget (only half used)
// overlays: T2 -> OFF_P2; U -> OFF_P1; pooled/stats/partial after U inside P1 region.

typedef __attribute__((ext_vector_type(8))) short s16x8;
typedef __attribute__((ext_vector_type(16))) float f32x16;

static __device__ __forceinline__ unsigned int f2bf_u(float x) {
    unsigned int u = __float_as_uint(x);
    return (u + 0x7fffu + ((u >> 16) & 1u)) >> 16;
}
static __device__ __forceinline__ float bfu2f(unsigned int h) {
    return __uint_as_float(h << 16);
}
// split 8 floats into hi/lo bf16 fragments
static __device__ __forceinline__ void cvt8(float4 v0, float4 v1, s16x8& hi, s16x8& lo) {
    float f[8] = {v0.x, v0.y, v0.z, v0.w, v1.x, v1.y, v1.z, v1.w};
#pragma unroll
    for (int j = 0; j < 8; j++) {
        unsigned int h = f2bf_u(f[j]);
        hi[j] = (short)h;
        lo[j] = (short)f2bf_u(f[j] - bfu2f(h));
    }
}

// ---------------- kernel 1: gated temporal conv #1 ----------------
__global__ __launch_bounds__(128) void k_tconv1(
    const float* __restrict__ X,
    const float* __restrict__ w1, const float* __restrict__ b1,
    const float* __restrict__ w2, const float* __restrict__ b2,
    const float* __restrict__ w3, const float* __restrict__ b3,
    float* __restrict__ T0)
{
    int blk = blockIdx.x;                // (b*38+t)*50+n
    int h = threadIdx.x;
    int n = blk % NN;
    int bt = blk / NN;
    int t = bt % TT;
    int b = bt / TT;

    const float* xp = X + ((size_t)(b * TW + t) * NN + n) * 2;
    float xin[6];
#pragma unroll
    for (int k = 0; k < 3; k++) {
        xin[k * 2 + 0] = xp[k * (NN * 2) + 0];
        xin[k * 2 + 1] = xp[k * (NN * 2) + 1];
    }
    float P = b1[h], Q = b2[h], R = b3[h];
#pragma unroll
    for (int q = 0; q < 6; q++) {
        P += xin[q] * w1[q * HH + h];
        Q += xin[q] * w2[q * HH + h];
        R += xin[q] * w3[q * HH + h];
    }
    float sg = 1.f / (1.f + expf(-Q));
    float v = P * sg + R;
    T0[(size_t)blk * HH + h] = v > 0.f ? v : 0.f;
}

// ---------------- kernel 2: weight prep (bf16 hi/lo split, transposed) ----------------
// VeffT[o=128][kk=384] = cheb fold: kk<128: W0-W2 ; kk<256: W1 ; else 2*W2   (col-major -> [o][kk])
// WcatT[j=192][kk=384]: j = g*64+o (g: 0=P,1=Q,2=R); value = tc2_w{g}[kk][o]
__global__ __launch_bounds__(256) void k_wprep(
    const float* __restrict__ cw,
    const float* __restrict__ tw1, const float* __restrict__ tw2, const float* __restrict__ tw3,
    unsigned short* __restrict__ VTh, unsigned short* __restrict__ VTl,
    unsigned short* __restrict__ WTh, unsigned short* __restrict__ WTl)
{
    int idx = blockIdx.x * 256 + threadIdx.x;
    float v;
    unsigned short* dh;
    unsigned short* dl;
    int dst;
    if (idx < 128 * 384) {
        int o = idx / 384, kk = idx % 384;
        if (kk < 128)      v = cw[kk * 128 + o] - cw[32768 + kk * 128 + o];
        else if (kk < 256) v = cw[16384 + (kk - 128) * 128 + o];
        else               v = 2.f * cw[32768 + (kk - 256) * 128 + o];
        dh = VTh; dl = VTl; dst = idx;
    } else if (idx < 128 * 384 + 192 * 384) {
        int j2 = idx - 128 * 384;
        int j = j2 / 384, kk = j2 % 384;
        int g = j >> 6, o = j & 63;
        const float* src = (g == 0) ? tw1 : (g == 1) ? tw2 : tw3;
        v = src[kk * 64 + o];
        dh = WTh; dl = WTl; dst = j2;
    } else return;
    unsigned int h = f2bf_u(v);
    dh[dst] = (unsigned short)h;
    dl[dst] = (unsigned short)f2bf_u(v - bfu2f(h));
}

// ---------------- kernel 3: Cheb propagation via dense Laplacian ----------------
#define LST 52
__global__ __launch_bounds__(256) void k_prop(
    const int* __restrict__ EI,
    const float* __restrict__ T0,
    float* __restrict__ P1, float* __restrict__ P2)
{
    __shared__ float Lm[52 * LST];
    __shared__ float Abuf[52 * HH];
    __shared__ float Bbuf[52 * HH];
    __shared__ float dis[NN];
    __shared__ int   deg[NN];

    int s = blockIdx.x;
    int tid = threadIdx.x;
    int b = s / TT, t = s % TT;
    const int* row = EI + (size_t)(b * TW + t) * 2 * EE;
    const int* col = row + EE;

    for (int i = tid; i < 52 * LST; i += 256) Lm[i] = 0.f;
    for (int i = tid; i < 52 * HH; i += 256) Abuf[i] = (i < NN * HH) ? T0[(size_t)s * (NN * HH) + i] : 0.f;
    for (int i = NN * HH + tid; i < 52 * HH; i += 256) Bbuf[i] = 0.f;
    if (tid < NN) deg[tid] = 0;
    __syncthreads();
    for (int e = tid; e < EE; e += 256) atomicAdd(&deg[row[e]], 1);
    __syncthreads();
    if (tid < NN) dis[tid] = deg[tid] > 0 ? rsqrtf((float)deg[tid]) : 0.f;
    __syncthreads();
    for (int e = tid; e < EE; e += 256) {
        int r = row[e], c = col[e];
        atomicAdd(&Lm[r * LST + c], -dis[r] * dis[c]);
    }
    __syncthreads();

    int c = tid & 63;
    int g = tid >> 6;
    int n0 = g * 13;

    float acc0[13], acc1[13];

#pragma unroll
    for (int j = 0; j < 13; j++) { acc0[j] = 0.f; acc1[j] = 0.f; }
    for (int mc = 0; mc < 13; mc++) {
        float a0[4], a1[4];
#pragma unroll
        for (int u = 0; u < 4; u++) {
            a0[u] = Abuf[(mc * 4 + u) * HH + c];
            a1[u] = Abuf[(mc * 4 + u) * HH + c + 64];
        }
        const float* lrow = &Lm[n0 * LST + mc * 4];
#pragma unroll
        for (int j = 0; j < 13; j++) {
            float4 l = *(const float4*)(lrow + j * LST);
            acc0[j] += l.x * a0[0] + l.y * a0[1] + l.z * a0[2] + l.w * a0[3];
            acc1[j] += l.x * a1[0] + l.y * a1[1] + l.z * a1[2] + l.w * a1[3];
        }
    }
#pragma unroll
    for (int j = 0; j < 13; j++) {
        int n = n0 + j;
        if (n < NN) {
            Bbuf[n * HH + c] = acc0[j];
            Bbuf[n * HH + c + 64] = acc1[j];
            P1[(size_t)s * (NN * HH) + n * HH + c] = acc0[j];
            P1[(size_t)s * (NN * HH) + n * HH + c + 64] = acc1[j];
        }
    }
    __syncthreads();

#pragma unroll
    for (int j = 0; j < 13; j++) { acc0[j] = 0.f; acc1[j] = 0.f; }
    for (int mc = 0; mc < 13; mc++) {
        float a0[4], a1[4];
#pragma unroll
        for (int u = 0; u < 4; u++) {
            a0[u] = Bbuf[(mc * 4 + u) * HH + c];
            a1[u] = Bbuf[(mc * 4 + u) * HH + c + 64];
        }
        const float* lrow = &Lm[n0 * LST + mc * 4];
#pragma unroll
        for (int j = 0; j < 13; j++) {
            float4 l = *(const float4*)(lrow + j * LST);
            acc0[j] += l.x * a0[0] + l.y * a0[1] + l.z * a0[2] + l.w * a0[3];
            acc1[j] += l.x * a1[0] + l.y * a1[1] + l.z * a1[2] + l.w * a1[3];
        }
    }
#pragma unroll
    for (int j = 0; j < 13; j++) {
        int n = n0 + j;
        if (n < NN) {
            P2[(size_t)s * (NN * HH) + n * HH + c] = acc0[j];
            P2[(size_t)s * (NN * HH) + n * HH + c + 64] = acc1[j];
        }
    }
}

// ---------------- kernel 4: cheb einsum via MFMA (split-bf16, fp32 accuracy) ----------------
// block: 64 rows x 128 cols, K=384 over [T0;P1;P2]. wave: 32 rows x 64 cols (2 n-tiles).
__global__ __launch_bounds__(256) void k_einsum(
    const float* __restrict__ T0, const float* __restrict__ P1, const float* __restrict__ P2,
    const unsigned short* __restrict__ VTh, const unsigned short* __restrict__ VTl,
    const float* __restrict__ bias, float* __restrict__ Gout)
{
    int tid = threadIdx.x;
    int lane = tid & 63;
    int w = tid >> 6;                    // wave id (uniform)
    int wrow = (w >> 1) * 32, wcol = (w & 1) * 64;
    int nl = lane & 31;
    int kh8 = (lane >> 5) * 8;
    size_t M0 = (size_t)blockIdx.x * 64;

    const float* srcs[3] = {T0, P1, P2};
    size_t arow = (M0 + wrow + nl) * 128 + kh8;

    int col0 = wcol + nl;
    const unsigned short* b0h = VTh + (size_t)col0 * 384 + kh8;
    const unsigned short* b0l = VTl + (size_t)col0 * 384 + kh8;
    const unsigned short* b1h = VTh + (size_t)(col0 + 32) * 384 + kh8;
    const unsigned short* b1l = VTl + (size_t)(col0 + 32) * 384 + kh8;

    f32x16 acc0, acc1;
#pragma unroll
    for (int r = 0; r < 16; r++) { acc0[r] = 0.f; acc1[r] = 0.f; }

    for (int kt = 0; kt < 12; kt++) {
        const float* ap = srcs[kt >> 2] + arow + (kt & 3) * 32;
#pragma unroll
        for (int kh = 0; kh < 2; kh++) {
            float4 v0 = *(const float4*)(ap + kh * 16);
            float4 v1 = *(const float4*)(ap + kh * 16 + 4);
            s16x8 ah, al;
            cvt8(v0, v1, ah, al);
            int ko = kt * 32 + kh * 16;
            s16x8 bh0 = *(const s16x8*)(b0h + ko);
            s16x8 bl0 = *(const s16x8*)(b0l + ko);
            s16x8 bh1 = *(const s16x8*)(b1h + ko);
            s16x8 bl1 = *(const s16x8*)(b1l + ko);
            acc0 = __builtin_amdgcn_mfma_f32_32x32x16_bf16(ah, bh0, acc0, 0, 0, 0);
            acc1 = __builtin_amdgcn_mfma_f32_32x32x16_bf16(ah, bh1, acc1, 0, 0, 0);
            acc0 = __builtin_amdgcn_mfma_f32_32x32x16_bf16(ah, bl0, acc0, 0, 0, 0);
            acc1 = __builtin_amdgcn_mfma_f32_32x32x16_bf16(ah, bl1, acc1, 0, 0, 0);
            acc0 = __builtin_amdgcn_mfma_f32_32x32x16_bf16(al, bh0, acc0, 0, 0, 0);
            acc1 = __builtin_amdgcn_mfma_f32_32x32x16_bf16(al, bh1, acc1, 0, 0, 0);
        }
    }

    float bv0 = bias[col0], bv1 = bias[col0 + 32];
    int rbase = (lane >> 5) * 4;
#pragma unroll
    for (int r = 0; r < 16; r++) {
        int rowl = (r & 3) + 8 * (r >> 2) + rbase;    // C/D row map (m74/m101-verified)
        size_t row = M0 + wrow + rowl;
        float v0 = acc0[r] + bv0; v0 = v0 > 0.f ? v0 : 0.f;
        float v1 = acc1[r] + bv1; v1 = v1 > 0.f ? v1 : 0.f;
        Gout[row * 128 + col0] = v0;
        Gout[row * 128 + col0 + 32] = v1;
    }
}

// ---------------- kernel 5: tconv2 via MFMA (split-bf16) + fused gate ----------------
// block: 64 rows x 192 cols (g-major: j = g*64+o). wave: 32 rows x (o-half 32) x 3 gates.
__global__ __launch_bounds__(256) void k_tc2(
    const float* __restrict__ G,
    const unsigned short* __restrict__ WTh, const unsigned short* __restrict__ WTl,
    const float* __restrict__ tb1, const float* __restrict__ tb2, const float* __restrict__ tb3,
    float* __restrict__ T2)
{
    int tid = threadIdx.x;
    int lane = tid & 63;
    int w = tid >> 6;
    int wrow = (w >> 1) * 32;
    int ohalf = (w & 1) * 32;
    int nl = lane & 31;
    int kh8 = (lane >> 5) * 8;
    int M0 = blockIdx.x * 64;

    // A row -> 3 tap base addresses in G
    int r_ = M0 + wrow + nl;
    int b = r_ / 1800, rem = r_ % 1800;
    int t = rem / 50, n = rem % 50;
    size_t base[3];
#pragma unroll
    for (int k3 = 0; k3 < 3; k3++)
        base[k3] = ((size_t)((b * TT) + t + k3) * NN + n) * HH + kh8;

    int jb = ohalf + nl;                 // o column this lane owns
    const unsigned short* bPh = WTh + (size_t)jb * 384 + kh8;
    const unsigned short* bPl = WTl + (size_t)jb * 384 + kh8;
    const unsigned short* bQh = bPh + (size_t)64 * 384;
    const unsigned short* bQl = bPl + (size_t)64 * 384;
    const unsigned short* bRh = bPh + (size_t)128 * 384;
    const unsigned short* bRl = bPl + (size_t)128 * 384;

    f32x16 aP, aQ, aR;
#pragma unroll
    for (int r = 0; r < 16; r++) { aP[r] = 0.f; aQ[r] = 0.f; aR[r] = 0.f; }

    for (int kt = 0; kt < 12; kt++) {
        const float* ap = G + base[kt >> 2] + (kt & 3) * 32;
#pragma unroll
        for (int kh = 0; kh < 2; kh++) {
            float4 v0 = *(const float4*)(ap + kh * 16);
            float4 v1 = *(const float4*)(ap + kh * 16 + 4);
            s16x8 ah, al;
            cvt8(v0, v1, ah, al);
            int ko = kt * 32 + kh * 16;
            s16x8 ph = *(const s16x8*)(bPh + ko);
            s16x8 pl = *(const s16x8*)(bPl + ko);
            s16x8 qh = *(const s16x8*)(bQh + ko);
            s16x8 ql = *(const s16x8*)(bQl + ko);
            s16x8 rh = *(const s16x8*)(bRh + ko);
            s16x8 rl = *(const s16x8*)(bRl + ko);
            aP = __builtin_amdgcn_mfma_f32_32x32x16_bf16(ah, ph, aP, 0, 0, 0);
            aQ = __builtin_amdgcn_mfma_f32_32x32x16_bf16(ah, qh, aQ, 0, 0, 0);
            aR = __builtin_amdgcn_mfma_f32_32x32x16_bf16(ah, rh, aR, 0, 0, 0);
            aP = __builtin_amdgcn_mfma_f32_32x32x16_bf16(ah, pl, aP, 0, 0, 0);
            aQ = __builtin_amdgcn_mfma_f32_32x32x16_bf16(ah, ql, aQ, 0, 0, 0);
            aR = __builtin_amdgcn_mfma_f32_32x32x16_bf16(ah, rl, aR, 0, 0, 0);
            aP = __builtin_amdgcn_mfma_f32_32x32x16_bf16(al, ph, aP, 0, 0, 0);
            aQ = __builtin_amdgcn_mfma_f32_32x32x16_bf16(al, qh, aQ, 0, 0, 0);
            aR = __builtin_amdgcn_mfma_f32_32x32x16_bf16(al, rh, aR, 0, 0, 0);
        }
    }

    float bP = tb1[jb], bQ = tb2[jb], bR = tb3[jb];
    int rbase = (lane >> 5) * 4;
#pragma unroll
    for (int r = 0; r < 16; r++) {
        int rowl = (r & 3) + 8 * (r >> 2) + rbase;
        size_t row = (size_t)(M0 + wrow + rowl);
        float P = aP[r] + bP;
        float Q = aQ[r] + bQ;
        float R = aR[r] + bR;
        float sg = 1.f / (1.f + expf(-Q));
        float v = P * sg + R;
        v = v > 0.f ? v : 0.f;
        T2[row * CO + jb] = v;
    }
}

// ---------------- kernel 6a: BN partial sums (8 chunks per node) ----------------
__global__ __launch_bounds__(256) void k_bnpart(const float* __restrict__ T2, float* __restrict__ partial)
{
    int n = blockIdx.x >> 3, c = blockIdx.x & 7;
    int tid = threadIdx.x;
    float s = 0.f, ss = 0.f;
    for (int i = tid; i < 144 * 64; i += 256) {
        int bt = c * 144 + (i >> 6), o = i & 63;
        float v = T2[((size_t)bt * NN + n) * CO + o];
        s += v; ss += v * v;
    }
    for (int off = 32; off > 0; off >>= 1) { s += __shfl_down(s, off, 64); ss += __shfl_down(ss, off, 64); }
    __shared__ float rs[4], rss[4];
    int lane = tid & 63, wv = tid >> 6;
    if (lane == 0) { rs[wv] = s; rss[wv] = ss; }
    __syncthreads();
    if (tid == 0) {
        partial[n * 8 + c] = rs[0] + rs[1] + rs[2] + rs[3];
        partial[400 + n * 8 + c] = rss[0] + rss[1] + rss[2] + rss[3];
    }
}

// ---------------- kernel 6b: BN finalize ----------------
__global__ __launch_bounds__(64) void k_bnfin(const float* __restrict__ partial, float* __restrict__ stats)
{
    int n = threadIdx.x;
    if (n < NN) {
        float s = 0.f, ss = 0.f;
#pragma unroll
        for (int c = 0; c < 8; c++) { s += partial[n * 8 + c]; ss += partial[400 + n * 8 + c]; }
        const float inv = 1.f / (float)(BB * TT2 * CO);
        float m = s * inv;
        float var = ss * inv - m * m;
        stats[n] = m;
        stats[NN + n] = rsqrtf(var + 1e-5f);
    }
}

// ---------------- kernel 7: windowed t-sums with BN folded ----------------
__global__ __launch_bounds__(256) void k_u(
    const float* __restrict__ T2, const float* __restrict__ stats,
    const float* __restrict__ gamma, const float* __restrict__ beta,
    float* __restrict__ U)
{
    int idx = blockIdx.x * 256 + threadIdx.x;     // (b*3+k)*3200 + j
    if (idx >= BB * 3 * NCO) return;
    int j = idx % NCO;
    int bk = idx / NCO;
    int k = bk % 3;
    int b = bk / 3;
    int n = j >> 6;
    float m = stats[n], is = stats[NN + n];
    float g = gamma[n], be = beta[n];
    float sum = 0.f;
    const float* p = T2 + ((size_t)b * TT2 + k) * NCO + j;
    for (int t = 0; t < TPOOL; t++) sum += p[(size_t)t * NCO];
    float r = (sum - (float)TPOOL * m) * (is * g) + (float)TPOOL * be;
    U[((size_t)(k * NCO + j)) * BB + b] = r;
}

// ---------------- kernel 8: conv3 reduced GEMM + pool ----------------
__global__ __launch_bounds__(256) void k_pool(
    const float* __restrict__ W3, const float* __restrict__ b3c,
    const float* __restrict__ U, float* __restrict__ pooled)
{
    int o = blockIdx.x;
    int tid = threadIdx.x;
    float acc[32];
#pragma unroll
    for (int b = 0; b < 32; b++) acc[b] = 0.f;
    const float* wp = W3 + (size_t)o * (3 * NCO);
    for (int idx = tid; idx < 3 * NCO; idx += 256) {
        float w = wp[idx];
        const float4* up4 = (const float4*)(U + (size_t)idx * BB);
#pragma unroll
        for (int b4 = 0; b4 < 8; b4++) {
            float4 u = up4[b4];
            acc[b4 * 4 + 0] += w * u.x;
            acc[b4 * 4 + 1] += w * u.y;
            acc[b4 * 4 + 2] += w * u.z;
            acc[b4 * 4 + 3] += w * u.w;
        }
    }
    __shared__ float red[4 * 32];
    int lane = tid & 63, wid = tid >> 6;
#pragma unroll
    for (int b = 0; b < 32; b++) {
        float v = acc[b];
        for (int off = 32; off > 0; off >>= 1) v += __shfl_down(v, off, 64);
        if (lane == 0) red[wid * 32 + b] = v;
    }
    __syncthreads();
    if (tid < 32) {
        float sum = red[tid] + red[32 + tid] + red[64 + tid] + red[96 + tid];
        pooled[tid * 128 + o] = b3c[o] + sum * (1.f / (float)TPOOL);
    }
}

// ---------------- kernel 9: final FC ----------------
__global__ __launch_bounds__(256) void k_final(
    const float* __restrict__ pooled, const float* __restrict__ f1w,
    const float* __restrict__ f1b, float* __restrict__ out)
{
    int idx = blockIdx.x * 256 + threadIdx.x;
    if (idx >= BB * NCO) return;
    int q = idx % NCO;
    int b = idx / NCO;
    float acc = f1b[q];
    const float* pp = pooled + b * 128;
    for (int o = 0; o < 128; o++) acc += pp[o] * f1w[(size_t)o * NCO + q];
    out[idx] = acc;
}

// ---------------- launch ----------------
extern "C" void kernel_launch(void* const* d_in, const int* in_sizes, int n_in,
                              void* d_out, int out_size, void* d_ws, size_t ws_size,
                              hipStream_t stream)
{
    const float* X       = (const float*)d_in[0];
    const int*   EI      = (const int*)d_in[1];
    const float* tc1_w1  = (const float*)d_in[2];
    const float* tc1_b1  = (const float*)d_in[3];
    const float* tc1_w2  = (const float*)d_in[4];
    const float* tc1_b2  = (const float*)d_in[5];
    const float* tc1_w3  = (const float*)d_in[6];
    const float* tc1_b3  = (const float*)d_in[7];
    const float* cheb_w  = (const float*)d_in[8];
    const float* cheb_b  = (const float*)d_in[9];
    const float* tc2_w1  = (const float*)d_in[10];
    const float* tc2_b1  = (const float*)d_in[11];
    const float* tc2_w2  = (const float*)d_in[12];
    const float* tc2_b2  = (const float*)d_in[13];
    const float* tc2_w3  = (const float*)d_in[14];
    const float* tc2_b3  = (const float*)d_in[15];
    const float* bn_g    = (const float*)d_in[16];
    const float* bn_b    = (const float*)d_in[17];
    const float* conv3_w = (const float*)d_in[18];
    const float* conv3_b = (const float*)d_in[19];
    const float* f1_w    = (const float*)d_in[20];
    const float* f1_b    = (const float*)d_in[21];

    float* ws = (float*)d_ws;
    float* T0G    = ws + OFF_T0;
    float* P1     = ws + OFF_P1;
    float* P2     = ws + OFF_P2;
    unsigned short* VTh = (unsigned short*)(ws + OFF_W);
    unsigned short* VTl = VTh + 128 * 384;
    unsigned short* WTh = VTl + 128 * 384;
    unsigned short* WTl = WTh + 192 * 384;
    float* T2     = ws + OFF_P2;             // overlay: P2 dead after einsum
    float* U      = ws + OFF_P1;             // overlay: P1 dead after einsum
    float* pooled = ws + OFF_P1 + 307200;
    float* stats  = ws + OFF_P1 + 311296;
    float* partial= ws + OFF_P1 + 312320;    // 800 floats

    k_tconv1<<<SS * NN, 128, 0, stream>>>(X, tc1_w1, tc1_b1, tc1_w2, tc1_b2, tc1_w3, tc1_b3, T0G);
    k_wprep<<<(128 * 384 + 192 * 384 + 255) / 256, 256, 0, stream>>>(cheb_w, tc2_w1, tc2_w2, tc2_w3, VTh, VTl, WTh, WTl);
    k_prop<<<SS, 256, 0, stream>>>(EI, T0G, P1, P2);
    k_einsum<<<ME / 64, 256, 0, stream>>>(T0G, P1, P2, VTh, VTl, cheb_b, T0G);
    k_tc2<<<MT / 64, 256, 0, stream>>>(T0G, WTh, WTl, tc2_b1, tc2_b2, tc2_b3, T2);
    k_bnpart<<<NN * 8, 256, 0, stream>>>(T2, partial);
    k_bnfin<<<1, 64, 0, stream>>>(partial, stats);
    k_u<<<(BB * 3 * NCO + 255) / 256, 256, 0, stream>>>(T2, stats, bn_g, bn_b, U);
    k_pool<<<128, 256, 0, stream>>>(conv3_w, conv3_b, U, pooled);
    k_final<<<(BB * NCO + 255) / 256, 256, 0, stream>>>(pooled, f1_w, f1_b, (float*)d_out);
}

// Round 5
// 414.153 us; speedup vs baseline: 4.8822x; 1.0240x over previous
//
#include <hip/hip_runtime.h>
#include <hip/hip_bf16.h>

// ---------------- sizes ----------------
#define BB 32
#define TW 40
#define NN 50
#define HH 128
#define CO 64
#define EE 800
#define TT 38      // Tw - 2
#define TT2 36     // TT - 2
#define TPOOL 34   // TT2 - 2
#define NCO 3200   // N*Co
#define SS (BB*TT) // 1216 graphs
#define ME (SS*NN)     // 60800 rows (= 950*64)
#define MT (BB*TT2*NN) // 57600 rows (= 900*64)

// ws layout (float units)
// [0, SZ_T0)            : T0h | T0l ushort planes (later overwritten in-place by G planes)
// [SZ_T0, 3*SZ_T0)      : P1h | P1l | P2h | P2l ushort planes
//   overlays: T2 f32 -> SZ_T0 (P1 region, dead after einsum)
//             U/pooled/stats/partial -> 2*SZ_T0 (P2 region)
// [3*SZ_T0, +122880)    : split weights VTh/VTl/WTh/WTl
#define SZ_T0    (ME*HH)                  // 7,782,400

typedef __attribute__((ext_vector_type(8))) short s16x8;
typedef __attribute__((ext_vector_type(16))) float f32x16;

static __device__ __forceinline__ unsigned int f2bf_u(float x) {
    unsigned int u = __float_as_uint(x);
    return (u + 0x7fffu + ((u >> 16) & 1u)) >> 16;
}
static __device__ __forceinline__ float bfu2f(unsigned int h) {
    return __uint_as_float(h << 16);
}
static __device__ __forceinline__ void splitst(float v, unsigned short* __restrict__ ph,
                                               unsigned short* __restrict__ pl, size_t off) {
    unsigned int h = f2bf_u(v);
    ph[off] = (unsigned short)h;
    pl[off] = (unsigned short)f2bf_u(v - bfu2f(h));
}

// ---------------- kernel 1: gated temporal conv #1 (writes split planes) ----------------
__global__ __launch_bounds__(128) void k_tconv1(
    const float* __restrict__ X,
    const float* __restrict__ w1, const float* __restrict__ b1,
    const float* __restrict__ w2, const float* __restrict__ b2,
    const float* __restrict__ w3, const float* __restrict__ b3,
    unsigned short* __restrict__ T0h, unsigned short* __restrict__ T0l)
{
    int blk = blockIdx.x;                // (b*38+t)*50+n
    int h = threadIdx.x;
    int n = blk % NN;
    int bt = blk / NN;
    int t = bt % TT;
    int b = bt / TT;

    const float* xp = X + ((size_t)(b * TW + t) * NN + n) * 2;
    float xin[6];
#pragma unroll
    for (int k = 0; k < 3; k++) {
        xin[k * 2 + 0] = xp[k * (NN * 2) + 0];
        xin[k * 2 + 1] = xp[k * (NN * 2) + 1];
    }
    float P = b1[h], Q = b2[h], R = b3[h];
#pragma unroll
    for (int q = 0; q < 6; q++) {
        P += xin[q] * w1[q * HH + h];
        Q += xin[q] * w2[q * HH + h];
        R += xin[q] * w3[q * HH + h];
    }
    float sg = 1.f / (1.f + expf(-Q));
    float v = P * sg + R;
    v = v > 0.f ? v : 0.f;
    splitst(v, T0h, T0l, (size_t)blk * HH + h);
}

// ---------------- kernel 2: weight prep (bf16 hi/lo split, transposed) ----------------
__global__ __launch_bounds__(256) void k_wprep(
    const float* __restrict__ cw,
    const float* __restrict__ tw1, const float* __restrict__ tw2, const float* __restrict__ tw3,
    unsigned short* __restrict__ VTh, unsigned short* __restrict__ VTl,
    unsigned short* __restrict__ WTh, unsigned short* __restrict__ WTl)
{
    int idx = blockIdx.x * 256 + threadIdx.x;
    float v;
    unsigned short* dh;
    unsigned short* dl;
    int dst;
    if (idx < 128 * 384) {
        int o = idx / 384, kk = idx % 384;
        if (kk < 128)      v = cw[kk * 128 + o] - cw[32768 + kk * 128 + o];
        else if (kk < 256) v = cw[16384 + (kk - 128) * 128 + o];
        else               v = 2.f * cw[32768 + (kk - 256) * 128 + o];
        dh = VTh; dl = VTl; dst = idx;
    } else if (idx < 128 * 384 + 192 * 384) {
        int j2 = idx - 128 * 384;
        int j = j2 / 384, kk = j2 % 384;
        int g = j >> 6, o = j & 63;
        const float* src = (g == 0) ? tw1 : (g == 1) ? tw2 : tw3;
        v = src[kk * 64 + o];
        dh = WTh; dl = WTl; dst = j2;
    } else return;
    splitst(v, dh, dl, dst);
}

// ---------------- kernel 3: Cheb propagation (dense Laplacian, Abuf reused) ----------------
#define LST 52
__global__ __launch_bounds__(256) void k_prop(
    const int* __restrict__ EI,
    const unsigned short* __restrict__ T0h, const unsigned short* __restrict__ T0l,
    unsigned short* __restrict__ P1h, unsigned short* __restrict__ P1l,
    unsigned short* __restrict__ P2h, unsigned short* __restrict__ P2l)
{
    __shared__ float Lm[52 * LST];
    __shared__ float Abuf[52 * HH];
    __shared__ float dis[NN];
    __shared__ int   deg[NN];

    int s = blockIdx.x;
    int tid = threadIdx.x;
    int b = s / TT, t = s % TT;
    const int* row = EI + (size_t)(b * TW + t) * 2 * EE;
    const int* col = row + EE;

    for (int i = tid; i < 52 * LST; i += 256) Lm[i] = 0.f;
    for (int i = tid; i < 52 * HH; i += 256) {
        float v = 0.f;
        if (i < NN * HH) {
            size_t gi = (size_t)s * (NN * HH) + i;
            v = bfu2f(T0h[gi]) + bfu2f(T0l[gi]);
        }
        Abuf[i] = v;
    }
    if (tid < NN) deg[tid] = 0;
    __syncthreads();
    for (int e = tid; e < EE; e += 256) atomicAdd(&deg[row[e]], 1);
    __syncthreads();
    if (tid < NN) dis[tid] = deg[tid] > 0 ? rsqrtf((float)deg[tid]) : 0.f;
    __syncthreads();
    for (int e = tid; e < EE; e += 256) {
        int r = row[e], c = col[e];
        atomicAdd(&Lm[r * LST + c], -dis[r] * dis[c]);
    }
    __syncthreads();

    int c = tid & 63;
    int g = tid >> 6;
    int n0 = g * 13;
    size_t gbase = (size_t)s * (NN * HH);

    float acc0[13], acc1[13];

    // ---- P1 = L @ T0 ----
#pragma unroll
    for (int j = 0; j < 13; j++) { acc0[j] = 0.f; acc1[j] = 0.f; }
    for (int mc = 0; mc < 13; mc++) {
        float a0[4], a1[4];
#pragma unroll
        for (int u = 0; u < 4; u++) {
            a0[u] = Abuf[(mc * 4 + u) * HH + c];
            a1[u] = Abuf[(mc * 4 + u) * HH + c + 64];
        }
        const float* lrow = &Lm[n0 * LST + mc * 4];
#pragma unroll
        for (int j = 0; j < 13; j++) {
            float4 l = *(const float4*)(lrow + j * LST);
            acc0[j] += l.x * a0[0] + l.y * a0[1] + l.z * a0[2] + l.w * a0[3];
            acc1[j] += l.x * a1[0] + l.y * a1[1] + l.z * a1[2] + l.w * a1[3];
        }
    }
    __syncthreads();   // all Abuf reads done before overwrite
#pragma unroll
    for (int j = 0; j < 13; j++) {
        int n = n0 + j;
        if (n < NN) {
            Abuf[n * HH + c] = acc0[j];
            Abuf[n * HH + c + 64] = acc1[j];
            splitst(acc0[j], P1h, P1l, gbase + n * HH + c);
            splitst(acc1[j], P1h, P1l, gbase + n * HH + c + 64);
        }
    }
    __syncthreads();

    // ---- P2 = L @ P1 ----
#pragma unroll
    for (int j = 0; j < 13; j++) { acc0[j] = 0.f; acc1[j] = 0.f; }
    for (int mc = 0; mc < 13; mc++) {
        float a0[4], a1[4];
#pragma unroll
        for (int u = 0; u < 4; u++) {
            a0[u] = Abuf[(mc * 4 + u) * HH + c];
            a1[u] = Abuf[(mc * 4 + u) * HH + c + 64];
        }
        const float* lrow = &Lm[n0 * LST + mc * 4];
#pragma unroll
        for (int j = 0; j < 13; j++) {
            float4 l = *(const float4*)(lrow + j * LST);
            acc0[j] += l.x * a0[0] + l.y * a0[1] + l.z * a0[2] + l.w * a0[3];
            acc1[j] += l.x * a1[0] + l.y * a1[1] + l.z * a1[2] + l.w * a1[3];
        }
    }
#pragma unroll
    for (int j = 0; j < 13; j++) {
        int n = n0 + j;
        if (n < NN) {
            splitst(acc0[j], P2h, P2l, gbase + n * HH + c);
            splitst(acc1[j], P2h, P2l, gbase + n * HH + c + 64);
        }
    }
}

#define MFMA(a, b, c) __builtin_amdgcn_mfma_f32_32x32x16_bf16((a), (b), (c), 0, 0, 0)

// ---------------- kernel 4: cheb einsum via MFMA (pre-split planes, prefetched) ----------------
__global__ __launch_bounds__(256) void k_einsum(
    const unsigned short* __restrict__ T0h, const unsigned short* __restrict__ T0l,
    const unsigned short* __restrict__ P1h, const unsigned short* __restrict__ P1l,
    const unsigned short* __restrict__ P2h, const unsigned short* __restrict__ P2l,
    const unsigned short* __restrict__ VTh, const unsigned short* __restrict__ VTl,
    const float* __restrict__ bias,
    unsigned short* __restrict__ Gh, unsigned short* __restrict__ Gl)
{
    int tid = threadIdx.x;
    int lane = tid & 63;
    int w = tid >> 6;
    int wrow = (w >> 1) * 32, wcol = (w & 1) * 64;
    int nl = lane & 31;
    int kh8 = (lane >> 5) * 8;
    size_t M0 = (size_t)blockIdx.x * 64;
    size_t arow = (M0 + wrow + nl) * 128 + kh8;

    const unsigned short* Ah[3] = {T0h + arow, P1h + arow, P2h + arow};
    const unsigned short* Al[3] = {T0l + arow, P1l + arow, P2l + arow};

    int col0 = wcol + nl;
    const unsigned short* b0h = VTh + (size_t)col0 * 384 + kh8;
    const unsigned short* b0l = VTl + (size_t)col0 * 384 + kh8;
    const unsigned short* b1h = VTh + (size_t)(col0 + 32) * 384 + kh8;
    const unsigned short* b1l = VTl + (size_t)(col0 + 32) * 384 + kh8;

    f32x16 acc0, acc1;
#pragma unroll
    for (int r = 0; r < 16; r++) { acc0[r] = 0.f; acc1[r] = 0.f; }

    // step s in [0,24): term = s>>3, in-row offset = ((s&7)>>1)*32 + (s&1)*16, B koff = s*16
    s16x8 ah, al, bh0, bl0, bh1, bl1;
    {
        ah = *(const s16x8*)(Ah[0]); al = *(const s16x8*)(Al[0]);
        bh0 = *(const s16x8*)(b0h); bl0 = *(const s16x8*)(b0l);
        bh1 = *(const s16x8*)(b1h); bl1 = *(const s16x8*)(b1l);
    }
    for (int s = 0; s < 24; s++) {
        s16x8 nah, nal, nbh0, nbl0, nbh1, nbl1;
        if (s < 23) {
            int sn = s + 1;
            int tm = sn >> 3;
            int off = ((sn & 7) >> 1) * 32 + (sn & 1) * 16;
            nah = *(const s16x8*)(Ah[tm] + off);
            nal = *(const s16x8*)(Al[tm] + off);
            int ko = sn * 16;
            nbh0 = *(const s16x8*)(b0h + ko); nbl0 = *(const s16x8*)(b0l + ko);
            nbh1 = *(const s16x8*)(b1h + ko); nbl1 = *(const s16x8*)(b1l + ko);
        }
        acc0 = MFMA(ah, bh0, acc0);
        acc1 = MFMA(ah, bh1, acc1);
        acc0 = MFMA(ah, bl0, acc0);
        acc1 = MFMA(ah, bl1, acc1);
        acc0 = MFMA(al, bh0, acc0);
        acc1 = MFMA(al, bh1, acc1);
        ah = nah; al = nal; bh0 = nbh0; bl0 = nbl0; bh1 = nbh1; bl1 = nbl1;
    }

    float bv0 = bias[col0], bv1 = bias[col0 + 32];
    int rbase = (lane >> 5) * 4;
#pragma unroll
    for (int r = 0; r < 16; r++) {
        int rowl = (r & 3) + 8 * (r >> 2) + rbase;   // C/D row map (m74/m101)
        size_t row = M0 + wrow + rowl;
        float v0 = acc0[r] + bv0; v0 = v0 > 0.f ? v0 : 0.f;
        float v1 = acc1[r] + bv1; v1 = v1 > 0.f ? v1 : 0.f;
        splitst(v0, Gh, Gl, row * 128 + col0);
        splitst(v1, Gh, Gl, row * 128 + col0 + 32);
    }
}

// ---------------- kernel 5: tconv2 via MFMA (pre-split planes, prefetched) + gate ----------------
__global__ __launch_bounds__(256) void k_tc2(
    const unsigned short* __restrict__ Gh, const unsigned short* __restrict__ Gl,
    const unsigned short* __restrict__ WTh, const unsigned short* __restrict__ WTl,
    const float* __restrict__ tb1, const float* __restrict__ tb2, const float* __restrict__ tb3,
    float* __restrict__ T2)
{
    int tid = threadIdx.x;
    int lane = tid & 63;
    int w = tid >> 6;
    int wrow = (w >> 1) * 32;
    int ohalf = (w & 1) * 32;
    int nl = lane & 31;
    int kh8 = (lane >> 5) * 8;
    int M0 = blockIdx.x * 64;

    int r_ = M0 + wrow + nl;
    int b = r_ / 1800, rem = r_ % 1800;
    int t = rem / 50, n = rem % 50;
    const unsigned short* Ahp[3];
    const unsigned short* Alp[3];
#pragma unroll
    for (int k3 = 0; k3 < 3; k3++) {
        size_t base = ((size_t)((b * TT) + t + k3) * NN + n) * HH + kh8;
        Ahp[k3] = Gh + base;
        Alp[k3] = Gl + base;
    }

    int jb = ohalf + nl;
    const unsigned short* bPh = WTh + (size_t)jb * 384 + kh8;
    const unsigned short* bPl = WTl + (size_t)jb * 384 + kh8;
    const unsigned short* bQh = bPh + (size_t)64 * 384;
    const unsigned short* bQl = bPl + (size_t)64 * 384;
    const unsigned short* bRh = bPh + (size_t)128 * 384;
    const unsigned short* bRl = bPl + (size_t)128 * 384;

    f32x16 aP, aQ, aR;
#pragma unroll
    for (int r = 0; r < 16; r++) { aP[r] = 0.f; aQ[r] = 0.f; aR[r] = 0.f; }

    s16x8 ah, al, ph, pl, qh, ql, rh, rl;
    {
        ah = *(const s16x8*)(Ahp[0]); al = *(const s16x8*)(Alp[0]);
        ph = *(const s16x8*)(bPh); pl = *(const s16x8*)(bPl);
        qh = *(const s16x8*)(bQh); ql = *(const s16x8*)(bQl);
        rh = *(const s16x8*)(bRh); rl = *(const s16x8*)(bRl);
    }
    for (int s = 0; s < 24; s++) {
        s16x8 nah, nal, nph, npl, nqh, nql, nrh, nrl;
        if (s < 23) {
            int sn = s + 1;
            int k3 = sn >> 3;
            int off = ((sn & 7) >> 1) * 32 + (sn & 1) * 16;
            nah = *(const s16x8*)(Ahp[k3] + off);
            nal = *(const s16x8*)(Alp[k3] + off);
            int ko = sn * 16;
            nph = *(const s16x8*)(bPh + ko); npl = *(const s16x8*)(bPl + ko);
            nqh = *(const s16x8*)(bQh + ko); nql = *(const s16x8*)(bQl + ko);
            nrh = *(const s16x8*)(bRh + ko); nrl = *(const s16x8*)(bRl + ko);
        }
        aP = MFMA(ah, ph, aP);
        aQ = MFMA(ah, qh, aQ);
        aR = MFMA(ah, rh, aR);
        aP = MFMA(ah, pl, aP);
        aQ = MFMA(ah, ql, aQ);
        aR = MFMA(ah, rl, aR);
        aP = MFMA(al, ph, aP);
        aQ = MFMA(al, qh, aQ);
        aR = MFMA(al, rh, aR);
        ah = nah; al = nal; ph = nph; pl = npl; qh = nqh; ql = nql; rh = nrh; rl = nrl;
    }

    float bP = tb1[jb], bQ = tb2[jb], bR = tb3[jb];
    int rbase = (lane >> 5) * 4;
#pragma unroll
    for (int r = 0; r < 16; r++) {
        int rowl = (r & 3) + 8 * (r >> 2) + rbase;
        size_t row = (size_t)(M0 + wrow + rowl);
        float P = aP[r] + bP;
        float Q = aQ[r] + bQ;
        float R = aR[r] + bR;
        float sg = 1.f / (1.f + expf(-Q));
        float v = P * sg + R;
        v = v > 0.f ? v : 0.f;
        T2[row * CO + jb] = v;
    }
}

// ---------------- kernel 6a: BN partial sums ----------------
__global__ __launch_bounds__(256) void k_bnpart(const float* __restrict__ T2, float* __restrict__ partial)
{
    int n = blockIdx.x >> 3, c = blockIdx.x & 7;
    int tid = threadIdx.x;
    float s = 0.f, ss = 0.f;
    for (int i = tid; i < 144 * 64; i += 256) {
        int bt = c * 144 + (i >> 6), o = i & 63;
        float v = T2[((size_t)bt * NN + n) * CO + o];
        s += v; ss += v * v;
    }
    for (int off = 32; off > 0; off >>= 1) { s += __shfl_down(s, off, 64); ss += __shfl_down(ss, off, 64); }
    __shared__ float rs[4], rss[4];
    int lane = tid & 63, wv = tid >> 6;
    if (lane == 0) { rs[wv] = s; rss[wv] = ss; }
    __syncthreads();
    if (tid == 0) {
        partial[n * 8 + c] = rs[0] + rs[1] + rs[2] + rs[3];
        partial[400 + n * 8 + c] = rss[0] + rss[1] + rss[2] + rss[3];
    }
}

// ---------------- kernel 6b: BN finalize ----------------
__global__ __launch_bounds__(64) void k_bnfin(const float* __restrict__ partial, float* __restrict__ stats)
{
    int n = threadIdx.x;
    if (n < NN) {
        float s = 0.f, ss = 0.f;
#pragma unroll
        for (int c = 0; c < 8; c++) { s += partial[n * 8 + c]; ss += partial[400 + n * 8 + c]; }
        const float inv = 1.f / (float)(BB * TT2 * CO);
        float m = s * inv;
        float var = ss * inv - m * m;
        stats[n] = m;
        stats[NN + n] = rsqrtf(var + 1e-5f);
    }
}

// ---------------- kernel 7: windowed t-sums, sliding window over k ----------------
__global__ __launch_bounds__(256) void k_u(
    const float* __restrict__ T2, const float* __restrict__ stats,
    const float* __restrict__ gamma, const float* __restrict__ beta,
    float* __restrict__ U)
{
    int idx = blockIdx.x * 256 + threadIdx.x;     // b*NCO + j
    if (idx >= BB * NCO) return;
    int j = idx % NCO;
    int b = idx / NCO;
    int n = j >> 6;
    float m = stats[n], is = stats[NN + n];
    float g = gamma[n], be = beta[n];
    const float* p = T2 + (size_t)b * TT2 * NCO + j;
    float s0 = 0.f;
    for (int t = 0; t < TPOOL; t++) s0 += p[(size_t)t * NCO];
    float s1 = s0 - p[0] + p[(size_t)34 * NCO];
    float s2 = s1 - p[(size_t)1 * NCO] + p[(size_t)35 * NCO];
    float sc = is * g;
    float off = (float)TPOOL * be - (float)TPOOL * m * sc;
    U[((size_t)(0 * NCO + j)) * BB + b] = s0 * sc + off;
    U[((size_t)(1 * NCO + j)) * BB + b] = s1 * sc + off;
    U[((size_t)(2 * NCO + j)) * BB + b] = s2 * sc + off;
}

// ---------------- kernel 8: conv3 reduced GEMM + pool ----------------
__global__ __launch_bounds__(256) void k_pool(
    const float* __restrict__ W3, const float* __restrict__ b3c,
    const float* __restrict__ U, float* __restrict__ pooled)
{
    int o = blockIdx.x;
    int tid = threadIdx.x;
    float acc[32];
#pragma unroll
    for (int b = 0; b < 32; b++) acc[b] = 0.f;
    const float* wp = W3 + (size_t)o * (3 * NCO);
    for (int idx = tid; idx < 3 * NCO; idx += 256) {
        float w = wp[idx];
        const float4* up4 = (const float4*)(U + (size_t)idx * BB);
#pragma unroll
        for (int b4 = 0; b4 < 8; b4++) {
            float4 u = up4[b4];
            acc[b4 * 4 + 0] += w * u.x;
            acc[b4 * 4 + 1] += w * u.y;
            acc[b4 * 4 + 2] += w * u.z;
            acc[b4 * 4 + 3] += w * u.w;
        }
    }
    __shared__ float red[4 * 32];
    int lane = tid & 63, wid = tid >> 6;
#pragma unroll
    for (int b = 0; b < 32; b++) {
        float v = acc[b];
        for (int off = 32; off > 0; off >>= 1) v += __shfl_down(v, off, 64);
        if (lane == 0) red[wid * 32 + b] = v;
    }
    __syncthreads();
    if (tid < 32) {
        float sum = red[tid] + red[32 + tid] + red[64 + tid] + red[96 + tid];
        pooled[tid * 128 + o] = b3c[o] + sum * (1.f / (float)TPOOL);
    }
}

// ---------------- kernel 9: final FC ----------------
__global__ __launch_bounds__(256) void k_final(
    const float* __restrict__ pooled, const float* __restrict__ f1w,
    const float* __restrict__ f1b, float* __restrict__ out)
{
    int idx = blockIdx.x * 256 + threadIdx.x;
    if (idx >= BB * NCO) return;
    int q = idx % NCO;
    int b = idx / NCO;
    float acc = f1b[q];
    const float* pp = pooled + b * 128;
    for (int o = 0; o < 128; o++) acc += pp[o] * f1w[(size_t)o * NCO + q];
    out[idx] = acc;
}

// ---------------- launch ----------------
extern "C" void kernel_launch(void* const* d_in, const int* in_sizes, int n_in,
                              void* d_out, int out_size, void* d_ws, size_t ws_size,
                              hipStream_t stream)
{
    const float* X       = (const float*)d_in[0];
    const int*   EI      = (const int*)d_in[1];
    const float* tc1_w1  = (const float*)d_in[2];
    const float* tc1_b1  = (const float*)d_in[3];
    const float* tc1_w2  = (const float*)d_in[4];
    const float* tc1_b2  = (const float*)d_in[5];
    const float* tc1_w3  = (const float*)d_in[6];
    const float* tc1_b3  = (const float*)d_in[7];
    const float* cheb_w  = (const float*)d_in[8];
    const float* cheb_b  = (const float*)d_in[9];
    const float* tc2_w1  = (const float*)d_in[10];
    const float* tc2_b1  = (const float*)d_in[11];
    const float* tc2_w2  = (const float*)d_in[12];
    const float* tc2_b2  = (const float*)d_in[13];
    const float* tc2_w3  = (const float*)d_in[14];
    const float* tc2_b3  = (const float*)d_in[15];
    const float* bn_g    = (const float*)d_in[16];
    const float* bn_b    = (const float*)d_in[17];
    const float* conv3_w = (const float*)d_in[18];
    const float* conv3_b = (const float*)d_in[19];
    const float* f1_w    = (const float*)d_in[20];
    const float* f1_b    = (const float*)d_in[21];

    float* ws = (float*)d_ws;
    unsigned short* T0h = (unsigned short*)ws;
    unsigned short* T0l = T0h + SZ_T0;
    unsigned short* P1h = (unsigned short*)(ws + SZ_T0);
    unsigned short* P1l = P1h + SZ_T0;
    unsigned short* P2h = P1l + SZ_T0;
    unsigned short* P2l = P2h + SZ_T0;
    unsigned short* VTh = (unsigned short*)(ws + 3 * (size_t)SZ_T0);
    unsigned short* VTl = VTh + 128 * 384;
    unsigned short* WTh = VTl + 128 * 384;
    unsigned short* WTl = WTh + 192 * 384;
    float* T2     = ws + SZ_T0;                    // overlay P1 region
    float* U      = ws + 2 * (size_t)SZ_T0;        // overlay P2 region
    float* pooled = U + 3 * NCO * BB;
    float* stats  = pooled + BB * 128;
    float* partial= stats + 128;

    k_tconv1<<<ME, 128, 0, stream>>>(X, tc1_w1, tc1_b1, tc1_w2, tc1_b2, tc1_w3, tc1_b3, T0h, T0l);
    k_wprep<<<(128 * 384 + 192 * 384 + 255) / 256, 256, 0, stream>>>(cheb_w, tc2_w1, tc2_w2, tc2_w3, VTh, VTl, WTh, WTl);
    k_prop<<<SS, 256, 0, stream>>>(EI, T0h, T0l, P1h, P1l, P2h, P2l);
    k_einsum<<<ME / 64, 256, 0, stream>>>(T0h, T0l, P1h, P1l, P2h, P2l, VTh, VTl, cheb_b, T0h, T0l);
    k_tc2<<<MT / 64, 256, 0, stream>>>(T0h, T0l, WTh, WTl, tc2_b1, tc2_b2, tc2_b3, T2);
    k_bnpart<<<NN * 8, 256, 0, stream>>>(T2, partial);
    k_bnfin<<<1, 64, 0, stream>>>(partial, stats);
    k_u<<<(BB * NCO + 255) / 256, 256, 0, stream>>>(T2, stats, bn_g, bn_b, U);
    k_pool<<<128, 256, 0, stream>>>(conv3_w, conv3_b, U, pooled);
    k_final<<<(BB * NCO + 255) / 256, 256, 0, stream>>>(pooled, f1_w, f1_b, (float*)d_out);
}

// Round 6
// 320.730 us; speedup vs baseline: 6.3042x; 1.2913x over previous
//
#include <hip/hip_runtime.h>
#include <hip/hip_bf16.h>

// ---------------- sizes ----------------
#define BB 32
#define TW 40
#define NN 50
#define HH 128
#define CO 64
#define EE 800
#define TT 38      // Tw - 2
#define TT2 36     // TT - 2
#define TPOOL 34   // TT2 - 2
#define NCO 3200   // N*Co
#define SS (BB*TT)     // 1216 graphs
#define NPAD 64        // padded nodes/graph (tap offsets become multiples of 32)
#define RPAD (SS*NPAD) // 77824 padded rows

// fragment-major plane: addr(r,c) = tile*4096 + (c>>4)*512 + ((c>>3)&1)*256 + (r&31)*8 + (c&7)
// tile = r>>5 ; one (tile,step) fragment = 512 ushorts = 1KB = one coalesced wave load.
#define PB_US ((size_t)RPAD * HH)          // 9,961,472 ushorts per plane (19.92 MB)
#define PB_BYTES (PB_US * 2)

typedef __attribute__((ext_vector_type(8))) short s16x8;
typedef __attribute__((ext_vector_type(16))) float f32x16;
typedef unsigned short us;

static __device__ __forceinline__ unsigned int f2bf_u(float x) {
    unsigned int u = __float_as_uint(x);
    return (u + 0x7fffu + ((u >> 16) & 1u)) >> 16;
}
static __device__ __forceinline__ float bfu2f(unsigned int h) {
    return __uint_as_float(h << 16);
}
static __device__ __forceinline__ void splitst(float v, us* __restrict__ ph,
                                               us* __restrict__ pl, size_t off) {
    unsigned int h = f2bf_u(v);
    ph[off] = (us)h;
    pl[off] = (us)f2bf_u(v - bfu2f(h));
}
static __device__ __forceinline__ size_t fragoff(int n, int c) {
    return (size_t)(n >> 5) * 4096 + (size_t)(c >> 4) * 512 + ((c >> 3) & 1) * 256
         + (n & 31) * 8 + (c & 7);
}
#define MFMA(a, b, c) __builtin_amdgcn_mfma_f32_32x32x16_bf16((a), (b), (c), 0, 0, 0)

// ---------------- kernel 1: gated temporal conv #1 (1 block per graph, frag-major out) --------
__global__ __launch_bounds__(256) void k_tconv1(
    const float* __restrict__ X,
    const float* __restrict__ w1, const float* __restrict__ b1,
    const float* __restrict__ w2, const float* __restrict__ b2,
    const float* __restrict__ w3, const float* __restrict__ b3,
    us* __restrict__ T0h, us* __restrict__ T0l)
{
    __shared__ float Xs[300];        // [k][n][ch]
    __shared__ float Tb[NN * HH];
    int g = blockIdx.x;              // b*38+t
    int tid = threadIdx.x;
    int b = g / TT, t = g % TT;

    for (int i = tid; i < 300; i += 256) {
        int k = i / 100, r = i % 100;
        Xs[i] = X[(size_t)(b * TW + t + k) * 100 + r];
    }
    __syncthreads();

    int c = tid & 127, nh = tid >> 7;
    float wr1[6], wr2[6], wr3[6];
#pragma unroll
    for (int q = 0; q < 6; q++) {
        wr1[q] = w1[q * HH + c];
        wr2[q] = w2[q * HH + c];
        wr3[q] = w3[q * HH + c];
    }
    float bv1 = b1[c], bv2 = b2[c], bv3 = b3[c];
    for (int n = nh; n < NN; n += 2) {
        float P = bv1, Q = bv2, R = bv3;
#pragma unroll
        for (int q = 0; q < 6; q++) {
            float x = Xs[(q >> 1) * 100 + n * 2 + (q & 1)];
            P += x * wr1[q]; Q += x * wr2[q]; R += x * wr3[q];
        }
        float sg = 1.f / (1.f + expf(-Q));
        float v = P * sg + R;
        Tb[n * HH + c] = v > 0.f ? v : 0.f;
    }
    __syncthreads();

    // fragment-major write: graph region = 2 tiles = 8192 ushorts/plane, pads zeroed
    size_t gb = (size_t)g * 8192;
    for (int widx = tid; widx < 1024; widx += 256) {
        int lanef = widx & 63;
        int kh = lanef >> 5, m = lanef & 31;
        int stp = (widx >> 6) & 7, tl = widx >> 9;
        int n = tl * 32 + m;
        int c0 = stp * 16 + kh * 8;
        s16x8 hv, lv;
#pragma unroll
        for (int j = 0; j < 8; j++) {
            float v = (n < NN) ? Tb[n * HH + c0 + j] : 0.f;
            unsigned int h = f2bf_u(v);
            hv[j] = (short)h;
            lv[j] = (short)f2bf_u(v - bfu2f(h));
        }
        *(s16x8*)(T0h + gb + widx * 8) = hv;
        *(s16x8*)(T0l + gb + widx * 8) = lv;
    }
}

// ---------------- kernel 2: weight prep -> fragment-major split bf16 ----------------
__global__ __launch_bounds__(256) void k_wprep(
    const float* __restrict__ cw,
    const float* __restrict__ tw1, const float* __restrict__ tw2, const float* __restrict__ tw3,
    us* __restrict__ VTh, us* __restrict__ VTl,
    us* __restrict__ WTh, us* __restrict__ WTl)
{
    int idx = blockIdx.x * 256 + threadIdx.x;
    float v; us *dh, *dl; int col, k;
    if (idx < 128 * 384) {
        col = idx / 384; k = idx % 384;
        if (k < 128)      v = cw[k * 128 + col] - cw[32768 + k * 128 + col];
        else if (k < 256) v = cw[16384 + (k - 128) * 128 + col];
        else              v = 2.f * cw[32768 + (k - 256) * 128 + col];
        dh = VTh; dl = VTl;
    } else if (idx < 128 * 384 + 192 * 384) {
        int i2 = idx - 128 * 384;
        col = i2 / 384; k = i2 % 384;
        int gg = col >> 6, o = col & 63;
        const float* src = (gg == 0) ? tw1 : (gg == 1) ? tw2 : tw3;
        v = src[k * 64 + o];
        dh = WTh; dl = WTl;
    } else return;
    // B-frag addr: ((coltile*24 + step)*64 + kh*32 + (col&31))*8 + j
    size_t off = ((size_t)((col >> 5) * 24 + (k >> 4)) * 64 + ((k >> 3) & 1) * 32 + (col & 31)) * 8
               + (k & 7);
    dh[off] = (us)f2bf_u(v);
    dl[off] = (us)f2bf_u(v - bfu2f((unsigned int)f2bf_u(v)));
}

// ---------------- kernel 3: Cheb propagation (dense Laplacian in LDS) ----------------
#define LST 52
__global__ __launch_bounds__(256) void k_prop(
    const int* __restrict__ EI,
    const us* __restrict__ T0h, const us* __restrict__ T0l,
    us* __restrict__ P1h, us* __restrict__ P2h)
{
    __shared__ float Lm[52 * LST];
    __shared__ float Abuf[52 * HH];
    __shared__ float dis[NN];
    __shared__ int   deg[NN];

    int g = blockIdx.x;
    int tid = threadIdx.x;
    int b = g / TT, t = g % TT;
    const int* row = EI + (size_t)(b * TW + t) * 2 * EE;
    const int* col = row + EE;
    size_t gb = (size_t)g * 8192;

    for (int i = tid; i < 52 * LST; i += 256) Lm[i] = 0.f;
    // decode fragment-major T0 -> Abuf[n][c] fp32 (pads are zero from tconv1)
    for (int widx = tid; widx < 1024; widx += 256) {
        int lanef = widx & 63;
        int kh = lanef >> 5, m = lanef & 31;
        int stp = (widx >> 6) & 7, tl = widx >> 9;
        int n = tl * 32 + m;
        if (n < 52) {
            s16x8 hv = *(const s16x8*)(T0h + gb + widx * 8);
            s16x8 lv = *(const s16x8*)(T0l + gb + widx * 8);
            int c0 = stp * 16 + kh * 8;
#pragma unroll
            for (int j = 0; j < 8; j++)
                Abuf[n * HH + c0 + j] = bfu2f((us)hv[j]) + bfu2f((us)lv[j]);
        }
    }
    if (tid < NN) deg[tid] = 0;
    __syncthreads();
    for (int e = tid; e < EE; e += 256) atomicAdd(&deg[row[e]], 1);
    __syncthreads();
    if (tid < NN) dis[tid] = deg[tid] > 0 ? rsqrtf((float)deg[tid]) : 0.f;
    __syncthreads();
    for (int e = tid; e < EE; e += 256) {
        int r = row[e], cc = col[e];
        atomicAdd(&Lm[r * LST + cc], -dis[r] * dis[cc]);
    }
    __syncthreads();

    int c = tid & 63;
    int wg = tid >> 6;
    int n0 = wg * 13;

    float acc0[13], acc1[13];

    // ---- P1 = L @ T0 ----
#pragma unroll
    for (int j = 0; j < 13; j++) { acc0[j] = 0.f; acc1[j] = 0.f; }
    for (int mc = 0; mc < 13; mc++) {
        float a0[4], a1[4];
#pragma unroll
        for (int u = 0; u < 4; u++) {
            a0[u] = Abuf[(mc * 4 + u) * HH + c];
            a1[u] = Abuf[(mc * 4 + u) * HH + c + 64];
        }
        const float* lrow = &Lm[n0 * LST + mc * 4];
#pragma unroll
        for (int j = 0; j < 13; j++) {
            float4 l = *(const float4*)(lrow + j * LST);
            acc0[j] += l.x * a0[0] + l.y * a0[1] + l.z * a0[2] + l.w * a0[3];
            acc1[j] += l.x * a1[0] + l.y * a1[1] + l.z * a1[2] + l.w * a1[3];
        }
    }
    __syncthreads();
#pragma unroll
    for (int j = 0; j < 13; j++) {
        int n = n0 + j;
        if (n < NN) {
            Abuf[n * HH + c] = acc0[j];
            Abuf[n * HH + c + 64] = acc1[j];
            P1h[gb + fragoff(n, c)] = (us)f2bf_u(acc0[j]);
            P1h[gb + fragoff(n, c + 64)] = (us)f2bf_u(acc1[j]);
        }
    }
    __syncthreads();

    // ---- P2 = L @ P1 ----
#pragma unroll
    for (int j = 0; j < 13; j++) { acc0[j] = 0.f; acc1[j] = 0.f; }
    for (int mc = 0; mc < 13; mc++) {
        float a0[4], a1[4];
#pragma unroll
        for (int u = 0; u < 4; u++) {
            a0[u] = Abuf[(mc * 4 + u) * HH + c];
            a1[u] = Abuf[(mc * 4 + u) * HH + c + 64];
        }
        const float* lrow = &Lm[n0 * LST + mc * 4];
#pragma unroll
        for (int j = 0; j < 13; j++) {
            float4 l = *(const float4*)(lrow + j * LST);
            acc0[j] += l.x * a0[0] + l.y * a0[1] + l.z * a0[2] + l.w * a0[3];
            acc1[j] += l.x * a1[0] + l.y * a1[1] + l.z * a1[2] + l.w * a1[3];
        }
    }
#pragma unroll
    for (int j = 0; j < 13; j++) {
        int n = n0 + j;
        if (n < NN) {
            P2h[gb + fragoff(n, c)] = (us)f2bf_u(acc0[j]);
            P2h[gb + fragoff(n, c + 64)] = (us)f2bf_u(acc1[j]);
        }
    }
}

// ---------------- kernel 4: cheb einsum via MFMA, all-coalesced fragment loads --------
// block: 128 rows x 128 cols. wave: 64 rows (2 tiles) x 64 cols (2 coltiles), 4 acc.
__global__ __launch_bounds__(256) void k_einsum(
    const us* __restrict__ T0h, const us* __restrict__ T0l,
    const us* __restrict__ P1h, const us* __restrict__ P2h,
    const us* __restrict__ VTh, const us* __restrict__ VTl,
    const float* __restrict__ bias,
    us* __restrict__ Gh, us* __restrict__ Gl)
{
    int tid = threadIdx.x;
    int lane = tid & 63;
    int w = tid >> 6;
    int rg = w >> 1, ch = w & 1;
    int nl = lane & 31;
    size_t laneoff = (size_t)lane * 8;
    int blk = blockIdx.x;

    size_t tb0 = ((size_t)blk * 4 + rg * 2) * 4096;   // A tile0 base (tile1 = +4096)
    const us* ah0B[3] = {T0h + tb0 + laneoff, P1h + tb0 + laneoff, P2h + tb0 + laneoff};
    const us* al0B = T0l + tb0 + laneoff;             // lo exists for term 0 only
    int ct0 = ch * 2;
    const us* bh0B = VTh + (size_t)ct0 * 12288 + laneoff;
    const us* bh1B = VTh + (size_t)(ct0 + 1) * 12288 + laneoff;
    const us* bl0B = VTl + (size_t)ct0 * 12288 + laneoff;
    const us* bl1B = VTl + (size_t)(ct0 + 1) * 12288 + laneoff;

    f32x16 a00, a01, a10, a11;
#pragma unroll
    for (int r = 0; r < 16; r++) { a00[r] = 0.f; a01[r] = 0.f; a10[r] = 0.f; a11[r] = 0.f; }

    // term 0: split A (hi+lo)
#pragma unroll
    for (int ls = 0; ls < 8; ls++) {
        int offA = ls * 512, offB = ls * 512;
        s16x8 ah0 = *(const s16x8*)(ah0B[0] + offA);
        s16x8 ah1 = *(const s16x8*)(ah0B[0] + 4096 + offA);
        s16x8 al0 = *(const s16x8*)(al0B + offA);
        s16x8 al1 = *(const s16x8*)(al0B + 4096 + offA);
        s16x8 bh0 = *(const s16x8*)(bh0B + offB);
        s16x8 bh1 = *(const s16x8*)(bh1B + offB);
        s16x8 bl0 = *(const s16x8*)(bl0B + offB);
        s16x8 bl1 = *(const s16x8*)(bl1B + offB);
        a00 = MFMA(ah0, bh0, a00); a00 = MFMA(ah0, bl0, a00); a00 = MFMA(al0, bh0, a00);
        a01 = MFMA(ah0, bh1, a01); a01 = MFMA(ah0, bl1, a01); a01 = MFMA(al0, bh1, a01);
        a10 = MFMA(ah1, bh0, a10); a10 = MFMA(ah1, bl0, a10); a10 = MFMA(al1, bh0, a10);
        a11 = MFMA(ah1, bh1, a11); a11 = MFMA(ah1, bl1, a11); a11 = MFMA(al1, bh1, a11);
    }
    // terms 1,2: A hi only
#pragma unroll
    for (int p = 1; p < 3; p++) {
#pragma unroll
        for (int ls = 0; ls < 8; ls++) {
            int offA = ls * 512, offB = (p * 8 + ls) * 512;
            s16x8 ah0 = *(const s16x8*)(ah0B[p] + offA);
            s16x8 ah1 = *(const s16x8*)(ah0B[p] + 4096 + offA);
            s16x8 bh0 = *(const s16x8*)(bh0B + offB);
            s16x8 bh1 = *(const s16x8*)(bh1B + offB);
            s16x8 bl0 = *(const s16x8*)(bl0B + offB);
            s16x8 bl1 = *(const s16x8*)(bl1B + offB);
            a00 = MFMA(ah0, bh0, a00); a00 = MFMA(ah0, bl0, a00);
            a01 = MFMA(ah0, bh1, a01); a01 = MFMA(ah0, bl1, a01);
            a10 = MFMA(ah1, bh0, a10); a10 = MFMA(ah1, bl0, a10);
            a11 = MFMA(ah1, bh1, a11); a11 = MFMA(ah1, bl1, a11);
        }
    }

    __syncthreads();   // all T0 reads complete before in-place G writes (WAR across waves)

    int c0 = ch * 64 + nl, c1 = c0 + 32;
    float bv0 = bias[c0], bv1 = bias[c1];
    int rbase = (lane >> 5) * 4;
#pragma unroll
    for (int r = 0; r < 16; r++) {
        int m = (r & 3) + 8 * (r >> 2) + rbase;
        size_t t0 = tb0 + (size_t)0;        // tile rt0
        size_t t1 = tb0 + 4096;             // tile rt1
        float v;
        v = a00[r] + bv0; v = v > 0.f ? v : 0.f;
        splitst(v, Gh, Gl, t0 + fragoff(m, c0) - (size_t)(m >> 5) * 4096);
        v = a01[r] + bv1; v = v > 0.f ? v : 0.f;
        splitst(v, Gh, Gl, t0 + fragoff(m, c1) - (size_t)(m >> 5) * 4096);
        v = a10[r] + bv0; v = v > 0.f ? v : 0.f;
        splitst(v, Gh, Gl, t1 + fragoff(m, c0) - (size_t)(m >> 5) * 4096);
        v = a11[r] + bv1; v = v > 0.f ? v : 0.f;
        splitst(v, Gh, Gl, t1 + fragoff(m, c1) - (size_t)(m >> 5) * 4096);
    }
}

// ---------------- kernel 5: tconv2 via MFMA + fused gate ----------------
// block: 128 rows (2 bt-groups of 64) x 64 cols. wave: 64 rows (2 tiles) x 32 o x 3 gates.
__global__ __launch_bounds__(256) void k_tc2(
    const us* __restrict__ Gh, const us* __restrict__ Gl,
    const us* __restrict__ WTh, const us* __restrict__ WTl,
    const float* __restrict__ tb1, const float* __restrict__ tb2, const float* __restrict__ tb3,
    float* __restrict__ T2)
{
    int tid = threadIdx.x;
    int lane = tid & 63;
    int w = tid >> 6;
    int rg = w >> 1, oh = (w & 1) * 32;
    int nl = lane & 31;
    size_t laneoff = (size_t)lane * 8;

    int bt36 = blockIdx.x * 2 + rg;          // (b*36+t), 64 rows each
    int b = bt36 / 36, t = bt36 % 36;

    const us* AhB[3];
    const us* AlB[3];
#pragma unroll
    for (int k3 = 0; k3 < 3; k3++) {
        size_t tb = ((size_t)(b * TT + t + k3) * 2) * 4096;
        AhB[k3] = Gh + tb + laneoff;
        AlB[k3] = Gl + tb + laneoff;
    }
    const us* BhB[3];
    const us* BlB[3];
#pragma unroll
    for (int g3 = 0; g3 < 3; g3++) {
        size_t cb = (size_t)(g3 * 2 + (w & 1)) * 12288;
        BhB[g3] = WTh + cb + laneoff;
        BlB[g3] = WTl + cb + laneoff;
    }

    f32x16 aP0, aQ0, aR0, aP1, aQ1, aR1;
#pragma unroll
    for (int r = 0; r < 16; r++) {
        aP0[r] = 0.f; aQ0[r] = 0.f; aR0[r] = 0.f;
        aP1[r] = 0.f; aQ1[r] = 0.f; aR1[r] = 0.f;
    }

#pragma unroll
    for (int k3 = 0; k3 < 3; k3++) {
#pragma unroll
        for (int ls = 0; ls < 8; ls++) {
            int offA = ls * 512, offB = (k3 * 8 + ls) * 512;
            s16x8 ah0 = *(const s16x8*)(AhB[k3] + offA);
            s16x8 ah1 = *(const s16x8*)(AhB[k3] + 4096 + offA);
            s16x8 al0 = *(const s16x8*)(AlB[k3] + offA);
            s16x8 al1 = *(const s16x8*)(AlB[k3] + 4096 + offA);
            s16x8 ph = *(const s16x8*)(BhB[0] + offB);
            s16x8 pl = *(const s16x8*)(BlB[0] + offB);
            s16x8 qh = *(const s16x8*)(BhB[1] + offB);
            s16x8 ql = *(const s16x8*)(BlB[1] + offB);
            s16x8 rh = *(const s16x8*)(BhB[2] + offB);
            s16x8 rl = *(const s16x8*)(BlB[2] + offB);
            aP0 = MFMA(ah0, ph, aP0); aP0 = MFMA(ah0, pl, aP0); aP0 = MFMA(al0, ph, aP0);
            aQ0 = MFMA(ah0, qh, aQ0); aQ0 = MFMA(ah0, ql, aQ0); aQ0 = MFMA(al0, qh, aQ0);
            aR0 = MFMA(ah0, rh, aR0); aR0 = MFMA(ah0, rl, aR0); aR0 = MFMA(al0, rh, aR0);
            aP1 = MFMA(ah1, ph, aP1); aP1 = MFMA(ah1, pl, aP1); aP1 = MFMA(al1, ph, aP1);
            aQ1 = MFMA(ah1, qh, aQ1); aQ1 = MFMA(ah1, ql, aQ1); aQ1 = MFMA(al1, qh, aQ1);
            aR1 = MFMA(ah1, rh, aR1); aR1 = MFMA(ah1, rl, aR1); aR1 = MFMA(al1, rh, aR1);
        }
    }

    int o = oh + nl;
    float bP = tb1[o], bQ = tb2[o], bR = tb3[o];
    int rbase = (lane >> 5) * 4;
#pragma unroll
    for (int r = 0; r < 16; r++) {
        int m = (r & 3) + 8 * (r >> 2) + rbase;
        // rt0: n = m
        if (m < NN) {
            float P = aP0[r] + bP, Q = aQ0[r] + bQ, R = aR0[r] + bR;
            float sg = 1.f / (1.f + expf(-Q));
            float v = P * sg + R;
            T2[((size_t)bt36 * NN + m) * CO + o] = v > 0.f ? v : 0.f;
        }
        int n1 = 32 + m;
        if (n1 < NN) {
            float P = aP1[r] + bP, Q = aQ1[r] + bQ, R = aR1[r] + bR;
            float sg = 1.f / (1.f + expf(-Q));
            float v = P * sg + R;
            T2[((size_t)bt36 * NN + n1) * CO + o] = v > 0.f ? v : 0.f;
        }
    }
}

// ---------------- kernel 6a: BN partial sums ----------------
__global__ __launch_bounds__(256) void k_bnpart(const float* __restrict__ T2, float* __restrict__ partial)
{
    int n = blockIdx.x >> 3, c = blockIdx.x & 7;
    int tid = threadIdx.x;
    float s = 0.f, ss = 0.f;
    for (int i = tid; i < 144 * 64; i += 256) {
        int bt = c * 144 + (i >> 6), o = i & 63;
        float v = T2[((size_t)bt * NN + n) * CO + o];
        s += v; ss += v * v;
    }
    for (int off = 32; off > 0; off >>= 1) { s += __shfl_down(s, off, 64); ss += __shfl_down(ss, off, 64); }
    __shared__ float rs[4], rss[4];
    int lane = tid & 63, wv = tid >> 6;
    if (lane == 0) { rs[wv] = s; rss[wv] = ss; }
    __syncthreads();
    if (tid == 0) {
        partial[n * 8 + c] = rs[0] + rs[1] + rs[2] + rs[3];
        partial[400 + n * 8 + c] = rss[0] + rss[1] + rss[2] + rss[3];
    }
}

// ---------------- kernel 6b: BN finalize + zero pooled accumulator ----------------
__global__ __launch_bounds__(64) void k_bnfin(const float* __restrict__ partial, float* __restrict__ stats,
                                              float* __restrict__ pooled)
{
    int n = threadIdx.x;
    if (n < NN) {
        float s = 0.f, ss = 0.f;
#pragma unroll
        for (int c = 0; c < 8; c++) { s += partial[n * 8 + c]; ss += partial[400 + n * 8 + c]; }
        const float inv = 1.f / (float)(BB * TT2 * CO);
        float m = s * inv;
        float var = ss * inv - m * m;
        stats[n] = m;
        stats[NN + n] = rsqrtf(var + 1e-5f);
    }
    for (int i = threadIdx.x; i < BB * 128; i += 64) pooled[i] = 0.f;
}

// ---------------- kernel 7: windowed t-sums, sliding window over k ----------------
__global__ __launch_bounds__(256) void k_u(
    const float* __restrict__ T2, const float* __restrict__ stats,
    const float* __restrict__ gamma, const float* __restrict__ beta,
    float* __restrict__ U)
{
    int idx = blockIdx.x * 256 + threadIdx.x;     // b*NCO + j
    if (idx >= BB * NCO) return;
    int j = idx % NCO;
    int b = idx / NCO;
    int n = j >> 6;
    float m = stats[n], is = stats[NN + n];
    float g = gamma[n], be = beta[n];
    const float* p = T2 + (size_t)b * TT2 * NCO + j;
    float s0 = 0.f;
    for (int t = 0; t < TPOOL; t++) s0 += p[(size_t)t * NCO];
    float s1 = s0 - p[0] + p[(size_t)34 * NCO];
    float s2 = s1 - p[(size_t)1 * NCO] + p[(size_t)35 * NCO];
    float sc = is * g;
    float off = (float)TPOOL * be - (float)TPOOL * m * sc;
    U[((size_t)(0 * NCO + j)) * BB + b] = s0 * sc + off;
    U[((size_t)(1 * NCO + j)) * BB + b] = s1 * sc + off;
    U[((size_t)(2 * NCO + j)) * BB + b] = s2 * sc + off;
}

// ---------------- kernel 8: conv3 reduced GEMM + pool (K-split, atomic accumulate) -------
__global__ __launch_bounds__(256) void k_pool(
    const float* __restrict__ W3,
    const float* __restrict__ U, float* __restrict__ pooled)
{
    int o = blockIdx.x & 127;
    int kc = blockIdx.x >> 7;       // 0..3, chunks of 2400
    int tid = threadIdx.x;
    float acc[32];
#pragma unroll
    for (int b = 0; b < 32; b++) acc[b] = 0.f;
    const float* wp = W3 + (size_t)o * (3 * NCO);
    for (int idx = kc * 2400 + tid; idx < (kc + 1) * 2400; idx += 256) {
        float wv = wp[idx];
        const float4* up4 = (const float4*)(U + (size_t)idx * BB);
#pragma unroll
        for (int b4 = 0; b4 < 8; b4++) {
            float4 u = up4[b4];
            acc[b4 * 4 + 0] += wv * u.x;
            acc[b4 * 4 + 1] += wv * u.y;
            acc[b4 * 4 + 2] += wv * u.z;
            acc[b4 * 4 + 3] += wv * u.w;
        }
    }
    __shared__ float red[4 * 32];
    int lane = tid & 63, wid = tid >> 6;
#pragma unroll
    for (int b = 0; b < 32; b++) {
        float v = acc[b];
        for (int off = 32; off > 0; off >>= 1) v += __shfl_down(v, off, 64);
        if (lane == 0) red[wid * 32 + b] = v;
    }
    __syncthreads();
    if (tid < 32) {
        float sum = red[tid] + red[32 + tid] + red[64 + tid] + red[96 + tid];
        atomicAdd(&pooled[tid * 128 + o], sum);
    }
}

// ---------------- kernel 9: final FC (bias + 1/34 folded here) ----------------
__global__ __launch_bounds__(256) void k_final(
    const float* __restrict__ pooled, const float* __restrict__ b3c,
    const float* __restrict__ f1w, const float* __restrict__ f1b,
    float* __restrict__ out)
{
    int idx = blockIdx.x * 256 + threadIdx.x;
    if (idx >= BB * NCO) return;
    int q = idx % NCO;
    int b = idx / NCO;
    const float inv = 1.f / (float)TPOOL;
    float acc = f1b[q];
    const float* pp = pooled + b * 128;
    for (int o = 0; o < 128; o++) acc += (pp[o] * inv + b3c[o]) * f1w[(size_t)o * NCO + q];
    out[idx] = acc;
}

// ---------------- launch ----------------
extern "C" void kernel_launch(void* const* d_in, const int* in_sizes, int n_in,
                              void* d_out, int out_size, void* d_ws, size_t ws_size,
                              hipStream_t stream)
{
    const float* X       = (const float*)d_in[0];
    const int*   EI      = (const int*)d_in[1];
    const float* tc1_w1  = (const float*)d_in[2];
    const float* tc1_b1  = (const float*)d_in[3];
    const float* tc1_w2  = (const float*)d_in[4];
    const float* tc1_b2  = (const float*)d_in[5];
    const float* tc1_w3  = (const float*)d_in[6];
    const float* tc1_b3  = (const float*)d_in[7];
    const float* cheb_w  = (const float*)d_in[8];
    const float* cheb_b  = (const float*)d_in[9];
    const float* tc2_w1  = (const float*)d_in[10];
    const float* tc2_b1  = (const float*)d_in[11];
    const float* tc2_w2  = (const float*)d_in[12];
    const float* tc2_b2  = (const float*)d_in[13];
    const float* tc2_w3  = (const float*)d_in[14];
    const float* tc2_b3  = (const float*)d_in[15];
    const float* bn_g    = (const float*)d_in[16];
    const float* bn_b    = (const float*)d_in[17];
    const float* conv3_w = (const float*)d_in[18];
    const float* conv3_b = (const float*)d_in[19];
    const float* f1_w    = (const float*)d_in[20];
    const float* f1_b    = (const float*)d_in[21];

    char* base = (char*)d_ws;
    us* T0h = (us*)base;                         // 19.92 MB each plane
    us* T0l = (us*)(base + PB_BYTES);
    us* P1h = (us*)(base + 2 * PB_BYTES);
    us* P2h = (us*)(base + 3 * PB_BYTES);
    us* VTh = (us*)(base + 4 * PB_BYTES);        // 96 KB
    us* VTl = VTh + 49152;
    us* WTh = VTl + 49152;                       // 144 KB
    us* WTl = WTh + 73728;
    float* T2     = (float*)(base + 2 * PB_BYTES);   // overlay P1h (dead after einsum)
    float* U      = (float*)(base + 3 * PB_BYTES);   // overlay P2h (dead after einsum)
    float* pooled = U + 3 * NCO * BB;
    float* stats  = pooled + BB * 128;
    float* partial= stats + 128;

    k_tconv1<<<SS, 256, 0, stream>>>(X, tc1_w1, tc1_b1, tc1_w2, tc1_b2, tc1_w3, tc1_b3, T0h, T0l);
    k_wprep<<<480, 256, 0, stream>>>(cheb_w, tc2_w1, tc2_w2, tc2_w3, VTh, VTl, WTh, WTl);
    k_prop<<<SS, 256, 0, stream>>>(EI, T0h, T0l, P1h, P2h);
    k_einsum<<<RPAD / 128, 256, 0, stream>>>(T0h, T0l, P1h, P2h, VTh, VTl, cheb_b, T0h, T0l);
    k_tc2<<<(BB * TT2) / 2, 256, 0, stream>>>(T0h, T0l, WTh, WTl, tc2_b1, tc2_b2, tc2_b3, T2);
    k_bnpart<<<NN * 8, 256, 0, stream>>>(T2, partial);
    k_bnfin<<<1, 64, 0, stream>>>(partial, stats, pooled);
    k_u<<<(BB * NCO + 255) / 256, 256, 0, stream>>>(T2, stats, bn_g, bn_b, U);
    k_pool<<<512, 256, 0, stream>>>(conv3_w, U, pooled);
    k_final<<<(BB * NCO + 255) / 256, 256, 0, stream>>>(pooled, conv3_b, f1_w, f1_b, (float*)d_out);
}

// Round 7
// 274.066 us; speedup vs baseline: 7.3776x; 1.1703x over previous
//
#include <hip/hip_runtime.h>
#include <hip/hip_bf16.h>

// ---------------- sizes ----------------
#define BB 32
#define TW 40
#define NN 50
#define HH 128
#define CO 64
#define EE 800
#define TT 38      // Tw - 2
#define TT2 36     // TT - 2
#define TPOOL 34   // TT2 - 2
#define NCO 3200   // N*Co
#define SS (BB*TT)     // 1216 graphs
#define NPAD 64
#define RPAD (SS*NPAD) // 77824 padded rows

// fragment-major plane: addr(node,feat) = g*8192 + (node>>5)*4096 + (feat>>4)*512
//                                       + ((feat>>3)&1)*256 + (node&31)*8 + (feat&7)
#define PB_US ((size_t)RPAD * HH)
#define PB_BYTES (PB_US * 2)

typedef __attribute__((ext_vector_type(8))) short s16x8;
typedef __attribute__((ext_vector_type(16))) float f32x16;
typedef unsigned short us;

static __device__ __forceinline__ unsigned int f2bf_u(float x) {
    unsigned int u = __float_as_uint(x);
    return (u + 0x7fffu + ((u >> 16) & 1u)) >> 16;
}
static __device__ __forceinline__ float bfu2f(unsigned int h) {
    return __uint_as_float(h << 16);
}
static __device__ __forceinline__ size_t fragoff(int n, int c) {
    return (size_t)(n >> 5) * 4096 + (size_t)(c >> 4) * 512 + ((c >> 3) & 1) * 256
         + (n & 31) * 8 + (c & 7);
}
#define MFMA(a, b, c) __builtin_amdgcn_mfma_f32_32x32x16_bf16((a), (b), (c), 0, 0, 0)

// ---------------- kernel 1: gated temporal conv #1 (frag-major split out) ----------------
__global__ __launch_bounds__(256) void k_tconv1(
    const float* __restrict__ X,
    const float* __restrict__ w1, const float* __restrict__ b1,
    const float* __restrict__ w2, const float* __restrict__ b2,
    const float* __restrict__ w3, const float* __restrict__ b3,
    us* __restrict__ T0h, us* __restrict__ T0l)
{
    __shared__ float Xs[300];
    __shared__ float Tb[NN * HH];
    int g = blockIdx.x;
    int tid = threadIdx.x;
    int b = g / TT, t = g % TT;

    for (int i = tid; i < 300; i += 256) {
        int k = i / 100, r = i % 100;
        Xs[i] = X[(size_t)(b * TW + t + k) * 100 + r];
    }
    __syncthreads();

    int c = tid & 127, nh = tid >> 7;
    float wr1[6], wr2[6], wr3[6];
#pragma unroll
    for (int q = 0; q < 6; q++) {
        wr1[q] = w1[q * HH + c];
        wr2[q] = w2[q * HH + c];
        wr3[q] = w3[q * HH + c];
    }
    float bv1 = b1[c], bv2 = b2[c], bv3 = b3[c];
    for (int n = nh; n < NN; n += 2) {
        float P = bv1, Q = bv2, R = bv3;
#pragma unroll
        for (int q = 0; q < 6; q++) {
            float x = Xs[(q >> 1) * 100 + n * 2 + (q & 1)];
            P += x * wr1[q]; Q += x * wr2[q]; R += x * wr3[q];
        }
        float sg = 1.f / (1.f + expf(-Q));
        float v = P * sg + R;
        Tb[n * HH + c] = v > 0.f ? v : 0.f;
    }
    __syncthreads();

    size_t gb = (size_t)g * 8192;
    for (int widx = tid; widx < 1024; widx += 256) {
        int lanef = widx & 63;
        int kh = lanef >> 5, m = lanef & 31;
        int stp = (widx >> 6) & 7, tl = widx >> 9;
        int n = tl * 32 + m;
        int c0 = stp * 16 + kh * 8;
        s16x8 hv, lv;
#pragma unroll
        for (int j = 0; j < 8; j++) {
            float v = (n < NN) ? Tb[n * HH + c0 + j] : 0.f;
            unsigned int h = f2bf_u(v);
            hv[j] = (short)h;
            lv[j] = (short)f2bf_u(v - bfu2f(h));
        }
        *(s16x8*)(T0h + gb + widx * 8) = hv;
        *(s16x8*)(T0l + gb + widx * 8) = lv;
    }
}

// ---------------- kernel 2: weight prep -> fragment-major split bf16 ----------------
__global__ __launch_bounds__(256) void k_wprep(
    const float* __restrict__ cw,
    const float* __restrict__ tw1, const float* __restrict__ tw2, const float* __restrict__ tw3,
    us* __restrict__ VTh, us* __restrict__ VTl,
    us* __restrict__ WTh, us* __restrict__ WTl)
{
    int idx = blockIdx.x * 256 + threadIdx.x;
    float v; us *dh, *dl; int col, k;
    if (idx < 128 * 384) {
        col = idx / 384; k = idx % 384;
        if (k < 128)      v = cw[k * 128 + col] - cw[32768 + k * 128 + col];
        else if (k < 256) v = cw[16384 + (k - 128) * 128 + col];
        else              v = 2.f * cw[32768 + (k - 256) * 128 + col];
        dh = VTh; dl = VTl;
    } else if (idx < 128 * 384 + 192 * 384) {
        int i2 = idx - 128 * 384;
        col = i2 / 384; k = i2 % 384;
        int gg = col >> 6, o = col & 63;
        const float* src = (gg == 0) ? tw1 : (gg == 1) ? tw2 : tw3;
        v = src[k * 64 + o];
        dh = WTh; dl = WTl;
    } else return;
    size_t off = ((size_t)((col >> 5) * 24 + (k >> 4)) * 64 + ((k >> 3) & 1) * 32 + (col & 31)) * 8
               + (k & 7);
    dh[off] = (us)f2bf_u(v);
    dl[off] = (us)f2bf_u(v - bfu2f((unsigned int)f2bf_u(v)));
}

// ---------------- kernel 3: fused Cheb prop (MFMA) + einsum (MFMA), one block/graph ------
// P1 = L@T0, P2 = L@P1 via MFMA (A=L bf16 frags in LDS, B from Pbuf fp32 cols, hi/lo split)
// G = relu(bias + T0*V0' + P1*V1' + P2*V2'), A-term0 from global frags, t1/t2 from Pbuf.
// G stored hi-only, in-place over T0h.
#define LMS 53
#define PST 131
__global__ __launch_bounds__(256) void k_cheb(
    const int* __restrict__ EI,
    const us* __restrict__ T0h, const us* __restrict__ T0l,
    const us* __restrict__ VTh, const us* __restrict__ VTl,
    const float* __restrict__ bias,
    us* __restrict__ Gh)
{
    __shared__ float Lm[52 * LMS];       // 11.0 KB
    __shared__ float Pbuf[64 * PST];     // 33.5 KB  (T0 -> P1 -> P2)
    __shared__ us    LA[2 * 4 * 64 * 8]; // 8 KB  L A-fragments bf16
    __shared__ float dis[NN];
    __shared__ int   deg[NN];

    int g = blockIdx.x;
    int tid = threadIdx.x;
    int b = g / TT, t = g % TT;
    const int* row = EI + (size_t)(b * TW + t) * 2 * EE;
    const int* col = row + EE;
    size_t gb = (size_t)g * 8192;

    // phase 0: zero L, decode T0 frags -> Pbuf fp32 (rows 50..63 zero via frag pads)
    for (int i = tid; i < 52 * LMS; i += 256) Lm[i] = 0.f;
    for (int widx = tid; widx < 1024; widx += 256) {
        int lanef = widx & 63;
        int kh = lanef >> 5, m = lanef & 31;
        int stp = (widx >> 6) & 7, tl = widx >> 9;
        int n = tl * 32 + m;
        s16x8 hv = *(const s16x8*)(T0h + gb + widx * 8);
        s16x8 lv = *(const s16x8*)(T0l + gb + widx * 8);
        int c0 = stp * 16 + kh * 8;
#pragma unroll
        for (int j = 0; j < 8; j++)
            Pbuf[n * PST + c0 + j] = bfu2f((us)hv[j]) + bfu2f((us)lv[j]);
    }
    if (tid < NN) deg[tid] = 0;
    __syncthreads();
    for (int e = tid; e < EE; e += 256) atomicAdd(&deg[row[e]], 1);
    __syncthreads();
    if (tid < NN) dis[tid] = deg[tid] > 0 ? rsqrtf((float)deg[tid]) : 0.f;
    __syncthreads();
    for (int e = tid; e < EE; e += 256) {
        int r = row[e], cc = col[e];
        atomicAdd(&Lm[r * LMS + cc], -dis[r] * dis[cc]);
    }
    __syncthreads();
    // LA fill: LA[(mt*4+ks)*64+lane][0..7] = bf16(L[mt*32+(lane&31)][ks*16+(lane>>5)*8+j])
    for (int ent = tid; ent < 512; ent += 256) {
        int lanee = ent & 63;
        int ks = (ent >> 6) & 3;
        int mt = ent >> 8;
        int m = mt * 32 + (lanee & 31);
        int kb = ks * 16 + (lanee >> 5) * 8;
        s16x8 v;
#pragma unroll
        for (int j = 0; j < 8; j++) {
            int k = kb + j;
            float lv = (m < NN && k < NN) ? Lm[m * LMS + k] : 0.f;
            v[j] = (short)f2bf_u(lv);
        }
        *(s16x8*)(LA + ent * 8) = v;
    }
    __syncthreads();

    int lane = tid & 63;
    int w = tid >> 6;
    int rg = w >> 1, fh = w & 1;       // M-tile, feature/N half (wave-uniform)
    int nl = lane & 31;
    int khalf = lane >> 5;
    size_t laneoff = (size_t)lane * 8;

    const us* vh0 = VTh + (size_t)(fh * 2) * 12288 + laneoff;
    const us* vh1 = VTh + (size_t)(fh * 2 + 1) * 12288 + laneoff;
    const us* vl0 = VTl + (size_t)(fh * 2) * 12288 + laneoff;
    const us* vl1 = VTl + (size_t)(fh * 2 + 1) * 12288 + laneoff;

    f32x16 gacc0, gacc1, d0, d1;
#pragma unroll
    for (int r = 0; r < 16; r++) { gacc0[r] = 0.f; gacc1[r] = 0.f; d0[r] = 0.f; d1[r] = 0.f; }

    // ---- phase 2: prop1 (D = L @ T0) + einsum term 0 ----
#pragma unroll
    for (int ks = 0; ks < 4; ks++) {
        s16x8 afr = *(const s16x8*)(LA + ((rg * 4 + ks) * 64 + lane) * 8);
        int kb = ks * 16 + khalf * 8;
#pragma unroll
        for (int nt = 0; nt < 2; nt++) {
            int n = fh * 64 + nt * 32 + nl;
            s16x8 bh, bl;
#pragma unroll
            for (int j = 0; j < 8; j++) {
                float bv = Pbuf[(kb + j) * PST + n];
                unsigned int h = f2bf_u(bv);
                bh[j] = (short)h;
                bl[j] = (short)f2bf_u(bv - bfu2f(h));
            }
            if (nt == 0) { d0 = MFMA(afr, bh, d0); d0 = MFMA(afr, bl, d0); }
            else         { d1 = MFMA(afr, bh, d1); d1 = MFMA(afr, bl, d1); }
        }
    }
    {
        const us* a0h = T0h + gb + (size_t)rg * 4096 + laneoff;
        const us* a0l = T0l + gb + (size_t)rg * 4096 + laneoff;
#pragma unroll
        for (int ks = 0; ks < 8; ks++) {
            s16x8 ah = *(const s16x8*)(a0h + ks * 512);
            s16x8 al = *(const s16x8*)(a0l + ks * 512);
            s16x8 bh0 = *(const s16x8*)(vh0 + ks * 512);
            s16x8 bl0 = *(const s16x8*)(vl0 + ks * 512);
            s16x8 bh1 = *(const s16x8*)(vh1 + ks * 512);
            s16x8 bl1 = *(const s16x8*)(vl1 + ks * 512);
            gacc0 = MFMA(ah, bh0, gacc0); gacc0 = MFMA(ah, bl0, gacc0); gacc0 = MFMA(al, bh0, gacc0);
            gacc1 = MFMA(ah, bh1, gacc1); gacc1 = MFMA(ah, bl1, gacc1); gacc1 = MFMA(al, bh1, gacc1);
        }
    }
    __syncthreads();
    // ---- phase 3: write P1 (overwrites T0 in LDS; pad rows get zeros from zero L rows) ----
#pragma unroll
    for (int r = 0; r < 16; r++) {
        int mrow = (r & 3) + 8 * (r >> 2) + 4 * khalf;
        int node = rg * 32 + mrow;
        Pbuf[node * PST + fh * 64 + nl] = d0[r];
        Pbuf[node * PST + fh * 64 + 32 + nl] = d1[r];
    }
    __syncthreads();

    // ---- phase 4: prop2 (D = L @ P1) + einsum term 1 (A = P1 hi) ----
#pragma unroll
    for (int r = 0; r < 16; r++) { d0[r] = 0.f; d1[r] = 0.f; }
#pragma unroll
    for (int ks = 0; ks < 4; ks++) {
        s16x8 afr = *(const s16x8*)(LA + ((rg * 4 + ks) * 64 + lane) * 8);
        int kb = ks * 16 + khalf * 8;
#pragma unroll
        for (int nt = 0; nt < 2; nt++) {
            int n = fh * 64 + nt * 32 + nl;
            s16x8 bh, bl;
#pragma unroll
            for (int j = 0; j < 8; j++) {
                float bv = Pbuf[(kb + j) * PST + n];
                unsigned int h = f2bf_u(bv);
                bh[j] = (short)h;
                bl[j] = (short)f2bf_u(bv - bfu2f(h));
            }
            if (nt == 0) { d0 = MFMA(afr, bh, d0); d0 = MFMA(afr, bl, d0); }
            else         { d1 = MFMA(afr, bh, d1); d1 = MFMA(afr, bl, d1); }
        }
    }
#pragma unroll
    for (int ks = 0; ks < 8; ks++) {
        int kb = ks * 16 + khalf * 8;
        int m = rg * 32 + nl;
        s16x8 ah;
#pragma unroll
        for (int j = 0; j < 8; j++) ah[j] = (short)f2bf_u(Pbuf[m * PST + kb + j]);
        s16x8 bh0 = *(const s16x8*)(vh0 + (8 + ks) * 512);
        s16x8 bl0 = *(const s16x8*)(vl0 + (8 + ks) * 512);
        s16x8 bh1 = *(const s16x8*)(vh1 + (8 + ks) * 512);
        s16x8 bl1 = *(const s16x8*)(vl1 + (8 + ks) * 512);
        gacc0 = MFMA(ah, bh0, gacc0); gacc0 = MFMA(ah, bl0, gacc0);
        gacc1 = MFMA(ah, bh1, gacc1); gacc1 = MFMA(ah, bl1, gacc1);
    }
    __syncthreads();
    // ---- phase 5: write P2 ----
#pragma unroll
    for (int r = 0; r < 16; r++) {
        int mrow = (r & 3) + 8 * (r >> 2) + 4 * khalf;
        int node = rg * 32 + mrow;
        Pbuf[node * PST + fh * 64 + nl] = d0[r];
        Pbuf[node * PST + fh * 64 + 32 + nl] = d1[r];
    }
    __syncthreads();
    // ---- phase 6: einsum term 2 (A = P2 hi) ----
#pragma unroll
    for (int ks = 0; ks < 8; ks++) {
        int kb = ks * 16 + khalf * 8;
        int m = rg * 32 + nl;
        s16x8 ah;
#pragma unroll
        for (int j = 0; j < 8; j++) ah[j] = (short)f2bf_u(Pbuf[m * PST + kb + j]);
        s16x8 bh0 = *(const s16x8*)(vh0 + (16 + ks) * 512);
        s16x8 bl0 = *(const s16x8*)(vl0 + (16 + ks) * 512);
        s16x8 bh1 = *(const s16x8*)(vh1 + (16 + ks) * 512);
        s16x8 bl1 = *(const s16x8*)(vl1 + (16 + ks) * 512);
        gacc0 = MFMA(ah, bh0, gacc0); gacc0 = MFMA(ah, bl0, gacc0);
        gacc1 = MFMA(ah, bh1, gacc1); gacc1 = MFMA(ah, bl1, gacc1);
    }

    // ---- epilogue: bias + relu, store G hi-only, frag-major in-place (Gh == T0h) ----
    int c0 = fh * 64 + nl, c1 = c0 + 32;
    float bv0 = bias[c0], bv1 = bias[c1];
#pragma unroll
    for (int r = 0; r < 16; r++) {
        int mrow = (r & 3) + 8 * (r >> 2) + 4 * khalf;
        float v0 = gacc0[r] + bv0; v0 = v0 > 0.f ? v0 : 0.f;
        float v1 = gacc1[r] + bv1; v1 = v1 > 0.f ? v1 : 0.f;
        Gh[gb + (size_t)rg * 4096 + fragoff(mrow, c0)] = (us)f2bf_u(v0);
        Gh[gb + (size_t)rg * 4096 + fragoff(mrow, c1)] = (us)f2bf_u(v1);
    }
}

// ---------------- kernel 4: tconv2 via MFMA + fused gate (G hi-only, 1 bt36/block) -------
__global__ __launch_bounds__(128) void k_tc2(
    const us* __restrict__ Gh,
    const us* __restrict__ WTh, const us* __restrict__ WTl,
    const float* __restrict__ tb1, const float* __restrict__ tb2, const float* __restrict__ tb3,
    float* __restrict__ T2)
{
    int tid = threadIdx.x;
    int lane = tid & 63;
    int w = tid >> 6;                 // o-half (wave-uniform)
    int nl = lane & 31;
    size_t laneoff = (size_t)lane * 8;
    int bt36 = blockIdx.x;
    int b = bt36 / TT2, t = bt36 % TT2;

    const us* A0[3];
    const us* A1[3];
#pragma unroll
    for (int k3 = 0; k3 < 3; k3++) {
        size_t tb = (size_t)(b * TT + t + k3) * 8192;
        A0[k3] = Gh + tb + laneoff;
        A1[k3] = Gh + tb + 4096 + laneoff;
    }
    const us* Bh[3];
    const us* Bl[3];
#pragma unroll
    for (int g3 = 0; g3 < 3; g3++) {
        size_t cb = (size_t)(g3 * 2 + w) * 12288 + laneoff;
        Bh[g3] = WTh + cb;
        Bl[g3] = WTl + cb;
    }

    f32x16 aP0, aQ0, aR0, aP1, aQ1, aR1;
#pragma unroll
    for (int r = 0; r < 16; r++) {
        aP0[r] = 0.f; aQ0[r] = 0.f; aR0[r] = 0.f;
        aP1[r] = 0.f; aQ1[r] = 0.f; aR1[r] = 0.f;
    }

#pragma unroll
    for (int k3 = 0; k3 < 3; k3++) {
#pragma unroll
        for (int ls = 0; ls < 8; ls++) {
            int offB = (k3 * 8 + ls) * 512;
            s16x8 a0 = *(const s16x8*)(A0[k3] + ls * 512);
            s16x8 a1 = *(const s16x8*)(A1[k3] + ls * 512);
            s16x8 ph = *(const s16x8*)(Bh[0] + offB);
            s16x8 pl = *(const s16x8*)(Bl[0] + offB);
            s16x8 qh = *(const s16x8*)(Bh[1] + offB);
            s16x8 ql = *(const s16x8*)(Bl[1] + offB);
            s16x8 rh = *(const s16x8*)(Bh[2] + offB);
            s16x8 rl = *(const s16x8*)(Bl[2] + offB);
            aP0 = MFMA(a0, ph, aP0); aP0 = MFMA(a0, pl, aP0);
            aQ0 = MFMA(a0, qh, aQ0); aQ0 = MFMA(a0, ql, aQ0);
            aR0 = MFMA(a0, rh, aR0); aR0 = MFMA(a0, rl, aR0);
            aP1 = MFMA(a1, ph, aP1); aP1 = MFMA(a1, pl, aP1);
            aQ1 = MFMA(a1, qh, aQ1); aQ1 = MFMA(a1, ql, aQ1);
            aR1 = MFMA(a1, rh, aR1); aR1 = MFMA(a1, rl, aR1);
        }
    }

    int o = w * 32 + nl;
    float bP = tb1[o], bQ = tb2[o], bR = tb3[o];
    int rbase = (lane >> 5) * 4;
#pragma unroll
    for (int r = 0; r < 16; r++) {
        int m = (r & 3) + 8 * (r >> 2) + rbase;
        {
            float P = aP0[r] + bP, Q = aQ0[r] + bQ, R = aR0[r] + bR;
            float sg = 1.f / (1.f + expf(-Q));
            float v = P * sg + R;
            T2[((size_t)bt36 * NN + m) * CO + o] = v > 0.f ? v : 0.f;
        }
        int n1 = 32 + m;
        if (n1 < NN) {
            float P = aP1[r] + bP, Q = aQ1[r] + bQ, R = aR1[r] + bR;
            float sg = 1.f / (1.f + expf(-Q));
            float v = P * sg + R;
            T2[((size_t)bt36 * NN + n1) * CO + o] = v > 0.f ? v : 0.f;
        }
    }
}

// ---------------- kernel 5a: BN partial sums ----------------
__global__ __launch_bounds__(256) void k_bnpart(const float* __restrict__ T2, float* __restrict__ partial)
{
    int n = blockIdx.x >> 3, c = blockIdx.x & 7;
    int tid = threadIdx.x;
    float s = 0.f, ss = 0.f;
    for (int i = tid; i < 144 * 64; i += 256) {
        int bt = c * 144 + (i >> 6), o = i & 63;
        float v = T2[((size_t)bt * NN + n) * CO + o];
        s += v; ss += v * v;
    }
    for (int off = 32; off > 0; off >>= 1) { s += __shfl_down(s, off, 64); ss += __shfl_down(ss, off, 64); }
    __shared__ float rs[4], rss[4];
    int lane = tid & 63, wv = tid >> 6;
    if (lane == 0) { rs[wv] = s; rss[wv] = ss; }
    __syncthreads();
    if (tid == 0) {
        partial[n * 8 + c] = rs[0] + rs[1] + rs[2] + rs[3];
        partial[400 + n * 8 + c] = rss[0] + rss[1] + rss[2] + rss[3];
    }
}

// ---------------- kernel 5b: BN finalize + zero pooled accumulator ----------------
__global__ __launch_bounds__(64) void k_bnfin(const float* __restrict__ partial, float* __restrict__ stats,
                                              float* __restrict__ pooled)
{
    int n = threadIdx.x;
    if (n < NN) {
        float s = 0.f, ss = 0.f;
#pragma unroll
        for (int c = 0; c < 8; c++) { s += partial[n * 8 + c]; ss += partial[400 + n * 8 + c]; }
        const float inv = 1.f / (float)(BB * TT2 * CO);
        float m = s * inv;
        float var = ss * inv - m * m;
        stats[n] = m;
        stats[NN + n] = rsqrtf(var + 1e-5f);
    }
    for (int i = threadIdx.x; i < BB * 128; i += 64) pooled[i] = 0.f;
}

// ---------------- kernel 6: windowed t-sums, sliding window over k ----------------
__global__ __launch_bounds__(256) void k_u(
    const float* __restrict__ T2, const float* __restrict__ stats,
    const float* __restrict__ gamma, const float* __restrict__ beta,
    float* __restrict__ U)
{
    int idx = blockIdx.x * 256 + threadIdx.x;
    if (idx >= BB * NCO) return;
    int j = idx % NCO;
    int b = idx / NCO;
    int n = j >> 6;
    float m = stats[n], is = stats[NN + n];
    float g = gamma[n], be = beta[n];
    const float* p = T2 + (size_t)b * TT2 * NCO + j;
    float s0 = 0.f;
    for (int t = 0; t < TPOOL; t++) s0 += p[(size_t)t * NCO];
    float s1 = s0 - p[0] + p[(size_t)34 * NCO];
    float s2 = s1 - p[(size_t)1 * NCO] + p[(size_t)35 * NCO];
    float sc = is * g;
    float off = (float)TPOOL * be - (float)TPOOL * m * sc;
    U[((size_t)(0 * NCO + j)) * BB + b] = s0 * sc + off;
    U[((size_t)(1 * NCO + j)) * BB + b] = s1 * sc + off;
    U[((size_t)(2 * NCO + j)) * BB + b] = s2 * sc + off;
}

// ---------------- kernel 7: conv3 reduced GEMM + pool (K-split, atomic accumulate) -------
__global__ __launch_bounds__(256) void k_pool(
    const float* __restrict__ W3,
    const float* __restrict__ U, float* __restrict__ pooled)
{
    int o = blockIdx.x & 127;
    int kc = blockIdx.x >> 7;
    int tid = threadIdx.x;
    float acc[32];
#pragma unroll
    for (int b = 0; b < 32; b++) acc[b] = 0.f;
    const float* wp = W3 + (size_t)o * (3 * NCO);
    for (int idx = kc * 2400 + tid; idx < (kc + 1) * 2400; idx += 256) {
        float wv = wp[idx];
        const float4* up4 = (const float4*)(U + (size_t)idx * BB);
#pragma unroll
        for (int b4 = 0; b4 < 8; b4++) {
            float4 u = up4[b4];
            acc[b4 * 4 + 0] += wv * u.x;
            acc[b4 * 4 + 1] += wv * u.y;
            acc[b4 * 4 + 2] += wv * u.z;
            acc[b4 * 4 + 3] += wv * u.w;
        }
    }
    __shared__ float red[4 * 32];
    int lane = tid & 63, wid = tid >> 6;
#pragma unroll
    for (int b = 0; b < 32; b++) {
        float v = acc[b];
        for (int off = 32; off > 0; off >>= 1) v += __shfl_down(v, off, 64);
        if (lane == 0) red[wid * 32 + b] = v;
    }
    __syncthreads();
    if (tid < 32) {
        float sum = red[tid] + red[32 + tid] + red[64 + tid] + red[96 + tid];
        atomicAdd(&pooled[tid * 128 + o], sum);
    }
}

// ---------------- kernel 8: final FC (conv3 bias + 1/34 folded here) ----------------
__global__ __launch_bounds__(256) void k_final(
    const float* __restrict__ pooled, const float* __restrict__ b3c,
    const float* __restrict__ f1w, const float* __restrict__ f1b,
    float* __restrict__ out)
{
    int idx = blockIdx.x * 256 + threadIdx.x;
    if (idx >= BB * NCO) return;
    int q = idx % NCO;
    int b = idx / NCO;
    const float inv = 1.f / (float)TPOOL;
    float acc = f1b[q];
    const float* pp = pooled + b * 128;
    for (int o = 0; o < 128; o++) acc += (pp[o] * inv + b3c[o]) * f1w[(size_t)o * NCO + q];
    out[idx] = acc;
}

// ---------------- launch ----------------
extern "C" void kernel_launch(void* const* d_in, const int* in_sizes, int n_in,
                              void* d_out, int out_size, void* d_ws, size_t ws_size,
                              hipStream_t stream)
{
    const float* X       = (const float*)d_in[0];
    const int*   EI      = (const int*)d_in[1];
    const float* tc1_w1  = (const float*)d_in[2];
    const float* tc1_b1  = (const float*)d_in[3];
    const float* tc1_w2  = (const float*)d_in[4];
    const float* tc1_b2  = (const float*)d_in[5];
    const float* tc1_w3  = (const float*)d_in[6];
    const float* tc1_b3  = (const float*)d_in[7];
    const float* cheb_w  = (const float*)d_in[8];
    const float* cheb_b  = (const float*)d_in[9];
    const float* tc2_w1  = (const float*)d_in[10];
    const float* tc2_b1  = (const float*)d_in[11];
    const float* tc2_w2  = (const float*)d_in[12];
    const float* tc2_b2  = (const float*)d_in[13];
    const float* tc2_w3  = (const float*)d_in[14];
    const float* tc2_b3  = (const float*)d_in[15];
    const float* bn_g    = (const float*)d_in[16];
    const float* bn_b    = (const float*)d_in[17];
    const float* conv3_w = (const float*)d_in[18];
    const float* conv3_b = (const float*)d_in[19];
    const float* f1_w    = (const float*)d_in[20];
    const float* f1_b    = (const float*)d_in[21];

    char* base = (char*)d_ws;
    us* T0h = (us*)base;
    us* T0l = (us*)(base + PB_BYTES);
    us* VTh = (us*)(base + 4 * PB_BYTES);
    us* VTl = VTh + 49152;
    us* WTh = VTl + 49152;
    us* WTl = WTh + 73728;
    float* T2     = (float*)(base + 2 * PB_BYTES);
    float* U      = (float*)(base + 3 * PB_BYTES);
    float* pooled = U + 3 * NCO * BB;
    float* stats  = pooled + BB * 128;
    float* partial= stats + 128;

    k_tconv1<<<SS, 256, 0, stream>>>(X, tc1_w1, tc1_b1, tc1_w2, tc1_b2, tc1_w3, tc1_b3, T0h, T0l);
    k_wprep<<<480, 256, 0, stream>>>(cheb_w, tc2_w1, tc2_w2, tc2_w3, VTh, VTl, WTh, WTl);
    k_cheb<<<SS, 256, 0, stream>>>(EI, T0h, T0l, VTh, VTl, cheb_b, T0h /* Gh in-place */);
    k_tc2<<<BB * TT2, 128, 0, stream>>>(T0h, WTh, WTl, tc2_b1, tc2_b2, tc2_b3, T2);
    k_bnpart<<<NN * 8, 256, 0, stream>>>(T2, partial);
    k_bnfin<<<1, 64, 0, stream>>>(partial, stats, pooled);
    k_u<<<(BB * NCO + 255) / 256, 256, 0, stream>>>(T2, stats, bn_g, bn_b, U);
    k_pool<<<512, 256, 0, stream>>>(conv3_w, U, pooled);
    k_final<<<(BB * NCO + 255) / 256, 256, 0, stream>>>(pooled, conv3_b, f1_w, f1_b, (float*)d_out);
}

// Round 8
// 249.179 us; speedup vs baseline: 8.1145x; 1.0999x over previous
//
#include <hip/hip_runtime.h>
#include <hip/hip_bf16.h>

// ---------------- sizes ----------------
#define BB 32
#define TW 40
#define NN 50
#define HH 128
#define CO 64
#define EE 800
#define TT 38      // Tw - 2
#define TT2 36     // TT - 2
#define TPOOL 34   // TT2 - 2
#define NCO 3200   // N*Co
#define SS (BB*TT)     // 1216 graphs
#define NPAD 64
#define RPAD (SS*NPAD)

// fragment-major G plane: addr(node,feat) = g*8192 + (node>>5)*4096 + (feat>>4)*512
//                                         + ((feat>>3)&1)*256 + (node&31)*8 + (feat&7)
#define PB_US ((size_t)RPAD * HH)
#define PB_BYTES (PB_US * 2)          // 19,922,944

typedef __attribute__((ext_vector_type(8))) short s16x8;
typedef __attribute__((ext_vector_type(16))) float f32x16;
typedef unsigned short us;

static __device__ __forceinline__ unsigned int f2bf_u(float x) {
    unsigned int u = __float_as_uint(x);
    return (u + 0x7fffu + ((u >> 16) & 1u)) >> 16;
}
static __device__ __forceinline__ float bfu2f(unsigned int h) {
    return __uint_as_float(h << 16);
}
static __device__ __forceinline__ size_t fragoff32(int m, int c) {  // m<32
    return (size_t)(c >> 4) * 512 + ((c >> 3) & 1) * 256 + m * 8 + (c & 7);
}
#define MFMA(a, b, c) __builtin_amdgcn_mfma_f32_32x32x16_bf16((a), (b), (c), 0, 0, 0)

// ---------------- kernel 1: weight prep + zero atomic accumulators ----------------
__global__ __launch_bounds__(256) void k_wprep(
    const float* __restrict__ cw,
    const float* __restrict__ tw1, const float* __restrict__ tw2, const float* __restrict__ tw3,
    us* __restrict__ VTh, us* __restrict__ VTl,
    us* __restrict__ WTh, us* __restrict__ WTl,
    float* __restrict__ pooled, float* __restrict__ gpart)
{
    int idx = blockIdx.x * 256 + threadIdx.x;
    float v; us *dh, *dl; int col, k;
    if (idx < 128 * 384) {
        col = idx / 384; k = idx % 384;
        if (k < 128)      v = cw[k * 128 + col] - cw[32768 + k * 128 + col];
        else if (k < 256) v = cw[16384 + (k - 128) * 128 + col];
        else              v = 2.f * cw[32768 + (k - 256) * 128 + col];
        dh = VTh; dl = VTl;
    } else if (idx < 128 * 384 + 192 * 384) {
        int i2 = idx - 128 * 384;
        col = i2 / 384; k = i2 % 384;
        int gg = col >> 6, o = col & 63;
        const float* src = (gg == 0) ? tw1 : (gg == 1) ? tw2 : tw3;
        v = src[k * 64 + o];
        dh = WTh; dl = WTl;
    } else {
        int z = idx - (128 * 384 + 192 * 384);
        if (z < 4096) pooled[z] = 0.f;
        else if (z < 4224) gpart[z - 4096] = 0.f;
        return;
    }
    size_t off = ((size_t)((col >> 5) * 24 + (k >> 4)) * 64 + ((k >> 3) & 1) * 32 + (col & 31)) * 8
               + (k & 7);
    unsigned int h = f2bf_u(v);
    dh[off] = (us)h;
    dl[off] = (us)f2bf_u(v - bfu2f(h));
}

// ---------------- kernel 2: fused tconv1 + Cheb prop + einsum, one block/graph ----------
// LDS layouts: A-layout [node][feat] stride 136 us; B-layout [feat][node] stride 72 us.
// All MFMA operands are single ds_read_b128 fragment loads. G hi-only to global.
#define TAS 136
#define TBS 72
#define LMS 53
__global__ __launch_bounds__(256) void k_cheb(
    const int* __restrict__ EI, const float* __restrict__ X,
    const float* __restrict__ w1, const float* __restrict__ b1,
    const float* __restrict__ w2, const float* __restrict__ b2,
    const float* __restrict__ w3, const float* __restrict__ b3,
    const us* __restrict__ VTh, const us* __restrict__ VTl,
    const float* __restrict__ bias,
    us* __restrict__ Gh)
{
    __shared__ __align__(16) char smem[61440];
    us* TbA = (us*)smem;                       // 64*136 us = 17408 B
    us* TbB = (us*)(smem + 17408);             // 128*72 us = 18432 B (T0-B, then P1-B)
    us* Pa  = (us*)(smem + 35840);             // 64*136 us (P1-A, then P2-A)
    float* Lm = (float*)(smem + 35840);        // 52*53 f32 overlay (dead before Pa)
    us* LA  = (us*)(smem + 53248);             // 4096 us = 8192 B
    float* Xs = (float*)(smem + 53248);        // 300 f overlay (dead before LA fill)
    int* deg  = (int*)(smem + 53248 + 1216);   // 50
    float* dis = (float*)(smem + 53248 + 1216 + 224); // 50

    int g = blockIdx.x;
    int tid = threadIdx.x;
    int b = g / TT, t = g % TT;
    const int* row = EI + (size_t)(b * TW + t) * 2 * EE;
    const int* col = row + EE;

    // phase 0: zero TbA+TbB (35840 B), zero Lm, load X slice, zero deg
    {
        s16x8 zz = {0, 0, 0, 0, 0, 0, 0, 0};
        for (int i = tid; i < 2240; i += 256) ((s16x8*)smem)[i] = zz;
    }
    for (int i = tid; i < 52 * LMS; i += 256) Lm[i] = 0.f;
    for (int i = tid; i < 300; i += 256) Xs[i] = X[(size_t)(b * TW + t) * 100 + i];
    if (tid < NN) deg[tid] = 0;
    __syncthreads();

    // phase 0b: tconv1 compute -> TbA (hi) + TbB (hi)
    {
        int c = tid & 127, nh = tid >> 7;
        float wr1[6], wr2[6], wr3[6];
#pragma unroll
        for (int q = 0; q < 6; q++) {
            wr1[q] = w1[q * HH + c];
            wr2[q] = w2[q * HH + c];
            wr3[q] = w3[q * HH + c];
        }
        float bv1 = b1[c], bv2 = b2[c], bv3 = b3[c];
        for (int n = nh; n < NN; n += 2) {
            float P = bv1, Q = bv2, R = bv3;
#pragma unroll
            for (int q = 0; q < 6; q++) {
                float x = Xs[(q >> 1) * 100 + n * 2 + (q & 1)];
                P += x * wr1[q]; Q += x * wr2[q]; R += x * wr3[q];
            }
            float sg = 1.f / (1.f + expf(-Q));
            float v = P * sg + R;
            v = v > 0.f ? v : 0.f;
            us h = (us)f2bf_u(v);
            TbA[n * TAS + c] = h;
            TbB[c * TBS + n] = h;
        }
    }
    __syncthreads();
    for (int e = tid; e < EE; e += 256) atomicAdd(&deg[row[e]], 1);
    __syncthreads();
    if (tid < NN) dis[tid] = deg[tid] > 0 ? rsqrtf((float)deg[tid]) : 0.f;
    __syncthreads();
    for (int e = tid; e < EE; e += 256) {
        int r = row[e], cc = col[e];
        atomicAdd(&Lm[r * LMS + cc], -dis[r] * dis[cc]);
    }
    __syncthreads();
    // LA fill (overwrites Xs/deg/dis region — all dead now)
    for (int ent = tid; ent < 512; ent += 256) {
        int lanee = ent & 63;
        int ks = (ent >> 6) & 3;
        int mt = ent >> 8;
        int m = mt * 32 + (lanee & 31);
        int kb = ks * 16 + (lanee >> 5) * 8;
        s16x8 v;
#pragma unroll
        for (int j = 0; j < 8; j++) {
            int k = kb + j;
            float lv = (m < NN && k < NN) ? Lm[m * LMS + k] : 0.f;
            v[j] = (short)f2bf_u(lv);
        }
        *(s16x8*)(LA + ent * 8) = v;
    }
    __syncthreads();

    int lane = tid & 63;
    int w = tid >> 6;
    int rg = w >> 1, fh = w & 1;       // wave-uniform: M-tile / feature-half
    int nl = lane & 31;
    int khalf = lane >> 5;
    size_t laneoff = (size_t)lane * 8;

    const us* vh0 = VTh + (size_t)(fh * 2) * 12288 + laneoff;
    const us* vh1 = VTh + (size_t)(fh * 2 + 1) * 12288 + laneoff;
    const us* vl0 = VTl + (size_t)(fh * 2) * 12288 + laneoff;
    const us* vl1 = VTl + (size_t)(fh * 2 + 1) * 12288 + laneoff;

    int mrowA = rg * 32 + nl;
    int kbb = khalf * 8;

    f32x16 gacc0, gacc1, d0, d1;
#pragma unroll
    for (int r = 0; r < 16; r++) { gacc0[r] = 0.f; gacc1[r] = 0.f; d0[r] = 0.f; d1[r] = 0.f; }

    // ---- phase 2: prop1 (P1 = L@T0, B hi-only) + einsum term 0 ----
#pragma unroll
    for (int ks = 0; ks < 4; ks++) {
        s16x8 afr = *(const s16x8*)(LA + ((rg * 4 + ks) * 64 + lane) * 8);
        int kb = ks * 16 + kbb;
        s16x8 bf0 = *(const s16x8*)(TbB + (fh * 64 + nl) * TBS + kb);
        s16x8 bf1 = *(const s16x8*)(TbB + (fh * 64 + 32 + nl) * TBS + kb);
        d0 = MFMA(afr, bf0, d0);
        d1 = MFMA(afr, bf1, d1);
    }
#pragma unroll
    for (int ks = 0; ks < 8; ks++) {
        s16x8 ah = *(const s16x8*)(TbA + mrowA * TAS + ks * 16 + kbb);
        s16x8 bh0 = *(const s16x8*)(vh0 + ks * 512);
        s16x8 bl0 = *(const s16x8*)(vl0 + ks * 512);
        s16x8 bh1 = *(const s16x8*)(vh1 + ks * 512);
        s16x8 bl1 = *(const s16x8*)(vl1 + ks * 512);
        gacc0 = MFMA(ah, bh0, gacc0); gacc0 = MFMA(ah, bl0, gacc0);
        gacc1 = MFMA(ah, bh1, gacc1); gacc1 = MFMA(ah, bl1, gacc1);
    }
    __syncthreads();
    // ---- phase 3: write P1 (A-layout into Pa, B-layout into TbB) ----
#pragma unroll
    for (int r = 0; r < 16; r++) {
        int mrow = (r & 3) + 8 * (r >> 2) + 4 * khalf;
        int node = rg * 32 + mrow;
        int f0 = fh * 64 + nl, f1 = f0 + 32;
        us h0 = (us)f2bf_u(d0[r]);
        us h1 = (us)f2bf_u(d1[r]);
        Pa[node * TAS + f0] = h0;
        Pa[node * TAS + f1] = h1;
        TbB[f0 * TBS + node] = h0;
        TbB[f1 * TBS + node] = h1;
    }
    __syncthreads();

    // ---- phase 4: prop2 (P2 = L@P1) + einsum term 1 (A = P1 hi) ----
#pragma unroll
    for (int r = 0; r < 16; r++) { d0[r] = 0.f; d1[r] = 0.f; }
#pragma unroll
    for (int ks = 0; ks < 4; ks++) {
        s16x8 afr = *(const s16x8*)(LA + ((rg * 4 + ks) * 64 + lane) * 8);
        int kb = ks * 16 + kbb;
        s16x8 bf0 = *(const s16x8*)(TbB + (fh * 64 + nl) * TBS + kb);
        s16x8 bf1 = *(const s16x8*)(TbB + (fh * 64 + 32 + nl) * TBS + kb);
        d0 = MFMA(afr, bf0, d0);
        d1 = MFMA(afr, bf1, d1);
    }
#pragma unroll
    for (int ks = 0; ks < 8; ks++) {
        s16x8 ah = *(const s16x8*)(Pa + mrowA * TAS + ks * 16 + kbb);
        s16x8 bh0 = *(const s16x8*)(vh0 + (8 + ks) * 512);
        s16x8 bl0 = *(const s16x8*)(vl0 + (8 + ks) * 512);
        s16x8 bh1 = *(const s16x8*)(vh1 + (8 + ks) * 512);
        s16x8 bl1 = *(const s16x8*)(vl1 + (8 + ks) * 512);
        gacc0 = MFMA(ah, bh0, gacc0); gacc0 = MFMA(ah, bl0, gacc0);
        gacc1 = MFMA(ah, bh1, gacc1); gacc1 = MFMA(ah, bl1, gacc1);
    }
    __syncthreads();
    // ---- phase 5: write P2 (A-layout only) ----
#pragma unroll
    for (int r = 0; r < 16; r++) {
        int mrow = (r & 3) + 8 * (r >> 2) + 4 * khalf;
        int node = rg * 32 + mrow;
        int f0 = fh * 64 + nl, f1 = f0 + 32;
        Pa[node * TAS + f0] = (us)f2bf_u(d0[r]);
        Pa[node * TAS + f1] = (us)f2bf_u(d1[r]);
    }
    __syncthreads();
    // ---- phase 6: einsum term 2 (A = P2 hi) ----
#pragma unroll
    for (int ks = 0; ks < 8; ks++) {
        s16x8 ah = *(const s16x8*)(Pa + mrowA * TAS + ks * 16 + kbb);
        s16x8 bh0 = *(const s16x8*)(vh0 + (16 + ks) * 512);
        s16x8 bl0 = *(const s16x8*)(vl0 + (16 + ks) * 512);
        s16x8 bh1 = *(const s16x8*)(vh1 + (16 + ks) * 512);
        s16x8 bl1 = *(const s16x8*)(vl1 + (16 + ks) * 512);
        gacc0 = MFMA(ah, bh0, gacc0); gacc0 = MFMA(ah, bl0, gacc0);
        gacc1 = MFMA(ah, bh1, gacc1); gacc1 = MFMA(ah, bl1, gacc1);
    }

    // ---- epilogue: bias + relu, G hi-only, frag-major ----
    int c0 = fh * 64 + nl, c1 = c0 + 32;
    float bv0 = bias[c0], bv1 = bias[c1];
    size_t gb = (size_t)g * 8192 + (size_t)rg * 4096;
#pragma unroll
    for (int r = 0; r < 16; r++) {
        int mrow = (r & 3) + 8 * (r >> 2) + 4 * khalf;
        float v0 = gacc0[r] + bv0; v0 = v0 > 0.f ? v0 : 0.f;
        float v1 = gacc1[r] + bv1; v1 = v1 > 0.f ? v1 : 0.f;
        Gh[gb + fragoff32(mrow, c0)] = (us)f2bf_u(v0);
        Gh[gb + fragoff32(mrow, c1)] = (us)f2bf_u(v1);
    }
}

// ---------------- kernel 3: tconv2 MFMA + gate + fused BN partial sums ----------------
__global__ __launch_bounds__(128) void k_tc2(
    const us* __restrict__ Gh,
    const us* __restrict__ WTh, const us* __restrict__ WTl,
    const float* __restrict__ tb1, const float* __restrict__ tb2, const float* __restrict__ tb3,
    float* __restrict__ T2, float* __restrict__ gpart)
{
    __shared__ float nsum[64], nss[64];
    int tid = threadIdx.x;
    int lane = tid & 63;
    int w = tid >> 6;
    int nl = lane & 31;
    size_t laneoff = (size_t)lane * 8;
    int bt36 = blockIdx.x;
    int b = bt36 / TT2, t = bt36 % TT2;
    if (tid < 64) { nsum[tid] = 0.f; nss[tid] = 0.f; }
    __syncthreads();

    const us* A0[3];
    const us* A1[3];
#pragma unroll
    for (int k3 = 0; k3 < 3; k3++) {
        size_t tb = (size_t)(b * TT + t + k3) * 8192;
        A0[k3] = Gh + tb + laneoff;
        A1[k3] = Gh + tb + 4096 + laneoff;
    }
    const us* Bh[3];
    const us* Bl[3];
#pragma unroll
    for (int g3 = 0; g3 < 3; g3++) {
        size_t cb = (size_t)(g3 * 2 + w) * 12288 + laneoff;
        Bh[g3] = WTh + cb;
        Bl[g3] = WTl + cb;
    }

    f32x16 aP0, aQ0, aR0, aP1, aQ1, aR1;
#pragma unroll
    for (int r = 0; r < 16; r++) {
        aP0[r] = 0.f; aQ0[r] = 0.f; aR0[r] = 0.f;
        aP1[r] = 0.f; aQ1[r] = 0.f; aR1[r] = 0.f;
    }

#pragma unroll
    for (int k3 = 0; k3 < 3; k3++) {
#pragma unroll
        for (int ls = 0; ls < 8; ls++) {
            int offB = (k3 * 8 + ls) * 512;
            s16x8 a0 = *(const s16x8*)(A0[k3] + ls * 512);
            s16x8 a1 = *(const s16x8*)(A1[k3] + ls * 512);
            s16x8 ph = *(const s16x8*)(Bh[0] + offB);
            s16x8 pl = *(const s16x8*)(Bl[0] + offB);
            s16x8 qh = *(const s16x8*)(Bh[1] + offB);
            s16x8 ql = *(const s16x8*)(Bl[1] + offB);
            s16x8 rh = *(const s16x8*)(Bh[2] + offB);
            s16x8 rl = *(const s16x8*)(Bl[2] + offB);
            aP0 = MFMA(a0, ph, aP0); aP0 = MFMA(a0, pl, aP0);
            aQ0 = MFMA(a0, qh, aQ0); aQ0 = MFMA(a0, ql, aQ0);
            aR0 = MFMA(a0, rh, aR0); aR0 = MFMA(a0, rl, aR0);
            aP1 = MFMA(a1, ph, aP1); aP1 = MFMA(a1, pl, aP1);
            aQ1 = MFMA(a1, qh, aQ1); aQ1 = MFMA(a1, ql, aQ1);
            aR1 = MFMA(a1, rh, aR1); aR1 = MFMA(a1, rl, aR1);
        }
    }

    int o = w * 32 + nl;
    float bP = tb1[o], bQ = tb2[o], bR = tb3[o];
    int rbase = (lane >> 5) * 4;
#pragma unroll
    for (int r = 0; r < 16; r++) {
        int m = (r & 3) + 8 * (r >> 2) + rbase;
        {
            float P = aP0[r] + bP, Q = aQ0[r] + bQ, R = aR0[r] + bR;
            float sg = 1.f / (1.f + expf(-Q));
            float v = P * sg + R;
            v = v > 0.f ? v : 0.f;
            T2[((size_t)bt36 * NN + m) * CO + o] = v;
            float sv = v, sq = v * v;
#pragma unroll
            for (int off = 16; off > 0; off >>= 1) {
                sv += __shfl_down(sv, off, 32);
                sq += __shfl_down(sq, off, 32);
            }
            if (nl == 0) { atomicAdd(&nsum[m], sv); atomicAdd(&nss[m], sq); }
        }
        int n1 = 32 + m;
        if (n1 < NN) {
            float P = aP1[r] + bP, Q = aQ1[r] + bQ, R = aR1[r] + bR;
            float sg = 1.f / (1.f + expf(-Q));
            float v = P * sg + R;
            v = v > 0.f ? v : 0.f;
            T2[((size_t)bt36 * NN + n1) * CO + o] = v;
            float sv = v, sq = v * v;
#pragma unroll
            for (int off = 16; off > 0; off >>= 1) {
                sv += __shfl_down(sv, off, 32);
                sq += __shfl_down(sq, off, 32);
            }
            if (nl == 0) { atomicAdd(&nsum[n1], sv); atomicAdd(&nss[n1], sq); }
        }
    }
    __syncthreads();
    if (tid < NN) {
        atomicAdd(&gpart[tid], nsum[tid]);
        atomicAdd(&gpart[64 + tid], nss[tid]);
    }
}

// ---------------- kernel 4: BN finalize ----------------
__global__ __launch_bounds__(64) void k_bnfin(const float* __restrict__ gpart, float* __restrict__ stats)
{
    int n = threadIdx.x;
    if (n < NN) {
        const float inv = 1.f / (float)(BB * TT2 * CO);
        float m = gpart[n] * inv;
        float var = gpart[64 + n] * inv - m * m;
        stats[n] = m;
        stats[64 + n] = rsqrtf(var + 1e-5f);
    }
}

// ---------------- kernel 5: fused windowed t-sums + conv3 GEMM + pool ----------------
// block = 16 j-columns (single node). Phase1: U[k][j][b] into LDS (sliding window + BN).
// Phase2: pooled[b,o] += sum_{k,j} W3[o,k,j]*U -- W3 staged in LDS, atomic accumulate.
__global__ __launch_bounds__(256) void k_upool(
    const float* __restrict__ T2, const float* __restrict__ stats,
    const float* __restrict__ gamma, const float* __restrict__ beta,
    const float* __restrict__ W3, float* __restrict__ pooled)
{
    __shared__ __align__(16) float Ul[48 * 36 + 32];   // [kj] stride 36, +b
    __shared__ float Ws[128 * 9];
    int blk = blockIdx.x;             // 200 blocks
    int jc = blk * 16;
    int n0 = jc >> 6;
    int tid = threadIdx.x;
    float mn = stats[n0], is = stats[64 + n0];
    float sc = is * gamma[n0];
    float off = (float)TPOOL * beta[n0] - (float)TPOOL * mn * sc;

    {
        int j = tid & 15, b0 = tid >> 4;
#pragma unroll
        for (int bp = 0; bp < 2; bp++) {
            int bb = b0 + 16 * bp;
            const float* p = T2 + (size_t)bb * TT2 * NCO + jc + j;
            float s0 = 0.f;
            for (int t = 0; t < TPOOL; t++) s0 += p[(size_t)t * NCO];
            float s1 = s0 - p[0] + p[(size_t)34 * NCO];
            float s2 = s1 - p[(size_t)1 * NCO] + p[(size_t)35 * NCO];
            Ul[(0 * 16 + j) * 36 + bb] = s0 * sc + off;
            Ul[(1 * 16 + j) * 36 + bb] = s1 * sc + off;
            Ul[(2 * 16 + j) * 36 + bb] = s2 * sc + off;
        }
    }
    __syncthreads();

    int o = tid & 127, bq = tid >> 7;
    float acc[16];
#pragma unroll
    for (int i = 0; i < 16; i++) acc[i] = 0.f;

    for (int kjc = 0; kjc < 48; kjc += 8) {
        __syncthreads();
#pragma unroll
        for (int p4 = 0; p4 < 4; p4++) {
            int idx = p4 * 256 + tid;
            int oo = idx >> 3, q = idx & 7;
            int kj = kjc + q;
            Ws[oo * 9 + q] = W3[(size_t)oo * 9600 + (kj >> 4) * 3200 + jc + (kj & 15)];
        }
        __syncthreads();
#pragma unroll
        for (int q = 0; q < 8; q++) {
            float wv = Ws[o * 9 + q];
            const float* up = &Ul[(kjc + q) * 36 + bq * 16];
#pragma unroll
            for (int i4 = 0; i4 < 4; i4++) {
                float4 u = *(const float4*)(up + i4 * 4);
                acc[i4 * 4 + 0] += wv * u.x;
                acc[i4 * 4 + 1] += wv * u.y;
                acc[i4 * 4 + 2] += wv * u.z;
                acc[i4 * 4 + 3] += wv * u.w;
            }
        }
    }
#pragma unroll
    for (int i = 0; i < 16; i++)
        atomicAdd(&pooled[(size_t)(bq * 16 + i) * 128 + o], acc[i]);
}

// ---------------- kernel 6: final FC (conv3 bias + 1/34 folded) ----------------
__global__ __launch_bounds__(256) void k_final(
    const float* __restrict__ pooled, const float* __restrict__ b3c,
    const float* __restrict__ f1w, const float* __restrict__ f1b,
    float* __restrict__ out)
{
    int idx = blockIdx.x * 256 + threadIdx.x;
    if (idx >= BB * NCO) return;
    int q = idx % NCO;
    int b = idx / NCO;
    const float inv = 1.f / (float)TPOOL;
    float acc = f1b[q];
    const float* pp = pooled + b * 128;
    for (int o = 0; o < 128; o++) acc += (pp[o] * inv + b3c[o]) * f1w[(size_t)o * NCO + q];
    out[idx] = acc;
}

// ---------------- launch ----------------
extern "C" void kernel_launch(void* const* d_in, const int* in_sizes, int n_in,
                              void* d_out, int out_size, void* d_ws, size_t ws_size,
                              hipStream_t stream)
{
    const float* X       = (const float*)d_in[0];
    const int*   EI      = (const int*)d_in[1];
    const float* tc1_w1  = (const float*)d_in[2];
    const float* tc1_b1  = (const float*)d_in[3];
    const float* tc1_w2  = (const float*)d_in[4];
    const float* tc1_b2  = (const float*)d_in[5];
    const float* tc1_w3  = (const float*)d_in[6];
    const float* tc1_b3  = (const float*)d_in[7];
    const float* cheb_w  = (const float*)d_in[8];
    const float* cheb_b  = (const float*)d_in[9];
    const float* tc2_w1  = (const float*)d_in[10];
    const float* tc2_b1  = (const float*)d_in[11];
    const float* tc2_w2  = (const float*)d_in[12];
    const float* tc2_b2  = (const float*)d_in[13];
    const float* tc2_w3  = (const float*)d_in[14];
    const float* tc2_b3  = (const float*)d_in[15];
    const float* bn_g    = (const float*)d_in[16];
    const float* bn_b    = (const float*)d_in[17];
    const float* conv3_w = (const float*)d_in[18];
    const float* conv3_b = (const float*)d_in[19];
    const float* f1_w    = (const float*)d_in[20];
    const float* f1_b    = (const float*)d_in[21];

    char* base = (char*)d_ws;
    us*    Gh     = (us*)base;                              // 19,922,944 B
    float* T2     = (float*)(base + PB_BYTES);              // 14,745,600 B
    float* pooled = (float*)(base + PB_BYTES + 14745600);   // 16,384 B
    float* stats  = (float*)(base + PB_BYTES + 14761984);   // 512 B
    float* gpart  = (float*)(base + PB_BYTES + 14762496);   // 512 B
    us*    VTh    = (us*)(base + PB_BYTES + 14763008);
    us*    VTl    = VTh + 49152;
    us*    WTh    = VTl + 49152;
    us*    WTl    = WTh + 73728;

    k_wprep<<<497, 256, 0, stream>>>(cheb_w, tc2_w1, tc2_w2, tc2_w3, VTh, VTl, WTh, WTl, pooled, gpart);
    k_cheb<<<SS, 256, 0, stream>>>(EI, X, tc1_w1, tc1_b1, tc1_w2, tc1_b2, tc1_w3, tc1_b3,
                                   VTh, VTl, cheb_b, Gh);
    k_tc2<<<BB * TT2, 128, 0, stream>>>(Gh, WTh, WTl, tc2_b1, tc2_b2, tc2_b3, T2, gpart);
    k_bnfin<<<1, 64, 0, stream>>>(gpart, stats);
    k_upool<<<200, 256, 0, stream>>>(T2, stats, bn_g, bn_b, conv3_w, pooled);
    k_final<<<(BB * NCO + 255) / 256, 256, 0, stream>>>(pooled, conv3_b, f1_w, f1_b, (float*)d_out);
}

// Round 9
// 234.550 us; speedup vs baseline: 8.6206x; 1.0624x over previous
//
#include <hip/hip_runtime.h>
#include <hip/hip_bf16.h>

// ---------------- sizes ----------------
#define BB 32
#define TW 40
#define NN 50
#define HH 128
#define CO 64
#define EE 800
#define TT 38      // Tw - 2
#define TT2 36     // TT - 2
#define TPOOL 34   // TT2 - 2
#define NCO 3200   // N*Co
#define SS (BB*TT)     // 1216 graphs
#define NPAD 64
#define RPAD (SS*NPAD)

// fragment-major G plane: addr(node,feat) = g*8192 + (node>>5)*4096 + (feat>>4)*512
//                                         + ((feat>>3)&1)*256 + (node&31)*8 + (feat&7)
#define PB_US ((size_t)RPAD * HH)
#define PB_BYTES (PB_US * 2)          // 19,922,944

typedef __attribute__((ext_vector_type(8))) short s16x8;
typedef __attribute__((ext_vector_type(16))) float f32x16;
typedef unsigned short us;

static __device__ __forceinline__ unsigned int f2bf_u(float x) {
    unsigned int u = __float_as_uint(x);
    return (u + 0x7fffu + ((u >> 16) & 1u)) >> 16;
}
static __device__ __forceinline__ float bfu2f(unsigned int h) {
    return __uint_as_float(h << 16);
}
static __device__ __forceinline__ size_t fragoff32(int m, int c) {  // m<32
    return (size_t)(c >> 4) * 512 + ((c >> 3) & 1) * 256 + m * 8 + (c & 7);
}
#define MFMA(a, b, c) __builtin_amdgcn_mfma_f32_32x32x16_bf16((a), (b), (c), 0, 0, 0)

// ---------------- kernel 1: weight prep + zero pooled accumulator ----------------
__global__ __launch_bounds__(256) void k_wprep(
    const float* __restrict__ cw,
    const float* __restrict__ tw1, const float* __restrict__ tw2, const float* __restrict__ tw3,
    us* __restrict__ VTh, us* __restrict__ VTl,
    us* __restrict__ WTh, us* __restrict__ WTl,
    float* __restrict__ pooled)
{
    int idx = blockIdx.x * 256 + threadIdx.x;
    float v; us *dh, *dl; int col, k;
    if (idx < 128 * 384) {
        col = idx / 384; k = idx % 384;
        if (k < 128)      v = cw[k * 128 + col] - cw[32768 + k * 128 + col];
        else if (k < 256) v = cw[16384 + (k - 128) * 128 + col];
        else              v = 2.f * cw[32768 + (k - 256) * 128 + col];
        dh = VTh; dl = VTl;
    } else if (idx < 128 * 384 + 192 * 384) {
        int i2 = idx - 128 * 384;
        col = i2 / 384; k = i2 % 384;
        int gg = col >> 6, o = col & 63;
        const float* src = (gg == 0) ? tw1 : (gg == 1) ? tw2 : tw3;
        v = src[k * 64 + o];
        dh = WTh; dl = WTl;
    } else {
        int z = idx - (128 * 384 + 192 * 384);
        if (z < 4096) pooled[z] = 0.f;
        return;
    }
    size_t off = ((size_t)((col >> 5) * 24 + (k >> 4)) * 64 + ((k >> 3) & 1) * 32 + (col & 31)) * 8
               + (k & 7);
    unsigned int h = f2bf_u(v);
    dh[off] = (us)h;
    dl[off] = (us)f2bf_u(v - bfu2f(h));
}

// ---------------- kernel 2: fused tconv1 + Cheb prop + einsum, one block/graph ----------
#define TAS 136
#define TBS 72
#define LMS 53
__global__ __launch_bounds__(256) void k_cheb(
    const int* __restrict__ EI, const float* __restrict__ X,
    const float* __restrict__ w1, const float* __restrict__ b1,
    const float* __restrict__ w2, const float* __restrict__ b2,
    const float* __restrict__ w3, const float* __restrict__ b3,
    const us* __restrict__ VTh, const us* __restrict__ VTl,
    const float* __restrict__ bias,
    us* __restrict__ Gh)
{
    __shared__ __align__(16) char smem[61440];
    us* TbA = (us*)smem;                       // 64*136 us
    us* TbB = (us*)(smem + 17408);             // 128*72 us (T0-B, then P1-B)
    us* Pa  = (us*)(smem + 35840);             // 64*136 us (P1-A, then P2-A)
    float* Lm = (float*)(smem + 35840);        // 52*53 f32 overlay
    us* LA  = (us*)(smem + 53248);             // 4096 us
    float* Xs = (float*)(smem + 53248);        // 300 f overlay
    int* deg  = (int*)(smem + 53248 + 1216);
    float* dis = (float*)(smem + 53248 + 1216 + 224);

    int g = blockIdx.x;
    int tid = threadIdx.x;
    int b = g / TT, t = g % TT;
    const int* row = EI + (size_t)(b * TW + t) * 2 * EE;
    const int* col = row + EE;

    {
        s16x8 zz = {0, 0, 0, 0, 0, 0, 0, 0};
        for (int i = tid; i < 2240; i += 256) ((s16x8*)smem)[i] = zz;
    }
    for (int i = tid; i < 52 * LMS; i += 256) Lm[i] = 0.f;
    for (int i = tid; i < 300; i += 256) Xs[i] = X[(size_t)(b * TW + t) * 100 + i];
    if (tid < NN) deg[tid] = 0;
    __syncthreads();

    {
        int c = tid & 127, nh = tid >> 7;
        float wr1[6], wr2[6], wr3[6];
#pragma unroll
        for (int q = 0; q < 6; q++) {
            wr1[q] = w1[q * HH + c];
            wr2[q] = w2[q * HH + c];
            wr3[q] = w3[q * HH + c];
        }
        float bv1 = b1[c], bv2 = b2[c], bv3 = b3[c];
        for (int n = nh; n < NN; n += 2) {
            float P = bv1, Q = bv2, R = bv3;
#pragma unroll
            for (int q = 0; q < 6; q++) {
                float x = Xs[(q >> 1) * 100 + n * 2 + (q & 1)];
                P += x * wr1[q]; Q += x * wr2[q]; R += x * wr3[q];
            }
            float sg = 1.f / (1.f + expf(-Q));
            float v = P * sg + R;
            v = v > 0.f ? v : 0.f;
            us h = (us)f2bf_u(v);
            TbA[n * TAS + c] = h;
            TbB[c * TBS + n] = h;
        }
    }
    __syncthreads();
    for (int e = tid; e < EE; e += 256) atomicAdd(&deg[row[e]], 1);
    __syncthreads();
    if (tid < NN) dis[tid] = deg[tid] > 0 ? rsqrtf((float)deg[tid]) : 0.f;
    __syncthreads();
    for (int e = tid; e < EE; e += 256) {
        int r = row[e], cc = col[e];
        atomicAdd(&Lm[r * LMS + cc], -dis[r] * dis[cc]);
    }
    __syncthreads();
    for (int ent = tid; ent < 512; ent += 256) {
        int lanee = ent & 63;
        int ks = (ent >> 6) & 3;
        int mt = ent >> 8;
        int m = mt * 32 + (lanee & 31);
        int kb = ks * 16 + (lanee >> 5) * 8;
        s16x8 v;
#pragma unroll
        for (int j = 0; j < 8; j++) {
            int k = kb + j;
            float lv = (m < NN && k < NN) ? Lm[m * LMS + k] : 0.f;
            v[j] = (short)f2bf_u(lv);
        }
        *(s16x8*)(LA + ent * 8) = v;
    }
    __syncthreads();

    int lane = tid & 63;
    int w = tid >> 6;
    int rg = w >> 1, fh = w & 1;
    int nl = lane & 31;
    int khalf = lane >> 5;
    size_t laneoff = (size_t)lane * 8;

    const us* vh0 = VTh + (size_t)(fh * 2) * 12288 + laneoff;
    const us* vh1 = VTh + (size_t)(fh * 2 + 1) * 12288 + laneoff;
    const us* vl0 = VTl + (size_t)(fh * 2) * 12288 + laneoff;
    const us* vl1 = VTl + (size_t)(fh * 2 + 1) * 12288 + laneoff;

    int mrowA = rg * 32 + nl;
    int kbb = khalf * 8;

    f32x16 gacc0, gacc1, d0, d1;
#pragma unroll
    for (int r = 0; r < 16; r++) { gacc0[r] = 0.f; gacc1[r] = 0.f; d0[r] = 0.f; d1[r] = 0.f; }

    // prop1 + einsum term 0
#pragma unroll
    for (int ks = 0; ks < 4; ks++) {
        s16x8 afr = *(const s16x8*)(LA + ((rg * 4 + ks) * 64 + lane) * 8);
        int kb = ks * 16 + kbb;
        s16x8 bf0 = *(const s16x8*)(TbB + (fh * 64 + nl) * TBS + kb);
        s16x8 bf1 = *(const s16x8*)(TbB + (fh * 64 + 32 + nl) * TBS + kb);
        d0 = MFMA(afr, bf0, d0);
        d1 = MFMA(afr, bf1, d1);
    }
#pragma unroll
    for (int ks = 0; ks < 8; ks++) {
        s16x8 ah = *(const s16x8*)(TbA + mrowA * TAS + ks * 16 + kbb);
        s16x8 bh0 = *(const s16x8*)(vh0 + ks * 512);
        s16x8 bl0 = *(const s16x8*)(vl0 + ks * 512);
        s16x8 bh1 = *(const s16x8*)(vh1 + ks * 512);
        s16x8 bl1 = *(const s16x8*)(vl1 + ks * 512);
        gacc0 = MFMA(ah, bh0, gacc0); gacc0 = MFMA(ah, bl0, gacc0);
        gacc1 = MFMA(ah, bh1, gacc1); gacc1 = MFMA(ah, bl1, gacc1);
    }
    __syncthreads();
#pragma unroll
    for (int r = 0; r < 16; r++) {
        int mrow = (r & 3) + 8 * (r >> 2) + 4 * khalf;
        int node = rg * 32 + mrow;
        int f0 = fh * 64 + nl, f1 = f0 + 32;
        us h0 = (us)f2bf_u(d0[r]);
        us h1 = (us)f2bf_u(d1[r]);
        Pa[node * TAS + f0] = h0;
        Pa[node * TAS + f1] = h1;
        TbB[f0 * TBS + node] = h0;
        TbB[f1 * TBS + node] = h1;
    }
    __syncthreads();

    // prop2 + einsum term 1
#pragma unroll
    for (int r = 0; r < 16; r++) { d0[r] = 0.f; d1[r] = 0.f; }
#pragma unroll
    for (int ks = 0; ks < 4; ks++) {
        s16x8 afr = *(const s16x8*)(LA + ((rg * 4 + ks) * 64 + lane) * 8);
        int kb = ks * 16 + kbb;
        s16x8 bf0 = *(const s16x8*)(TbB + (fh * 64 + nl) * TBS + kb);
        s16x8 bf1 = *(const s16x8*)(TbB + (fh * 64 + 32 + nl) * TBS + kb);
        d0 = MFMA(afr, bf0, d0);
        d1 = MFMA(afr, bf1, d1);
    }
#pragma unroll
    for (int ks = 0; ks < 8; ks++) {
        s16x8 ah = *(const s16x8*)(Pa + mrowA * TAS + ks * 16 + kbb);
        s16x8 bh0 = *(const s16x8*)(vh0 + (8 + ks) * 512);
        s16x8 bl0 = *(const s16x8*)(vl0 + (8 + ks) * 512);
        s16x8 bh1 = *(const s16x8*)(vh1 + (8 + ks) * 512);
        s16x8 bl1 = *(const s16x8*)(vl1 + (8 + ks) * 512);
        gacc0 = MFMA(ah, bh0, gacc0); gacc0 = MFMA(ah, bl0, gacc0);
        gacc1 = MFMA(ah, bh1, gacc1); gacc1 = MFMA(ah, bl1, gacc1);
    }
    __syncthreads();
#pragma unroll
    for (int r = 0; r < 16; r++) {
        int mrow = (r & 3) + 8 * (r >> 2) + 4 * khalf;
        int node = rg * 32 + mrow;
        int f0 = fh * 64 + nl, f1 = f0 + 32;
        Pa[node * TAS + f0] = (us)f2bf_u(d0[r]);
        Pa[node * TAS + f1] = (us)f2bf_u(d1[r]);
    }
    __syncthreads();
    // einsum term 2
#pragma unroll
    for (int ks = 0; ks < 8; ks++) {
        s16x8 ah = *(const s16x8*)(Pa + mrowA * TAS + ks * 16 + kbb);
        s16x8 bh0 = *(const s16x8*)(vh0 + (16 + ks) * 512);
        s16x8 bl0 = *(const s16x8*)(vl0 + (16 + ks) * 512);
        s16x8 bh1 = *(const s16x8*)(vh1 + (16 + ks) * 512);
        s16x8 bl1 = *(const s16x8*)(vl1 + (16 + ks) * 512);
        gacc0 = MFMA(ah, bh0, gacc0); gacc0 = MFMA(ah, bl0, gacc0);
        gacc1 = MFMA(ah, bh1, gacc1); gacc1 = MFMA(ah, bl1, gacc1);
    }

    int c0 = fh * 64 + nl, c1 = c0 + 32;
    float bv0 = bias[c0], bv1 = bias[c1];
    size_t gb = (size_t)g * 8192 + (size_t)rg * 4096;
#pragma unroll
    for (int r = 0; r < 16; r++) {
        int mrow = (r & 3) + 8 * (r >> 2) + 4 * khalf;
        float v0 = gacc0[r] + bv0; v0 = v0 > 0.f ? v0 : 0.f;
        float v1 = gacc1[r] + bv1; v1 = v1 > 0.f ? v1 : 0.f;
        Gh[gb + fragoff32(mrow, c0)] = (us)f2bf_u(v0);
        Gh[gb + fragoff32(mrow, c1)] = (us)f2bf_u(v1);
    }
}

// ---------------- kernel 3: tconv2 MFMA + gate (32-row tiles, XCD-swizzled) ----------------
// grid 2304 = 1152 bt36 x 2 ntiles. vb=(i&7)*288+(i>>3): each XCD gets a contiguous
// bt36 range -> tap re-reads hit that XCD's L2. T2 stored bf16-hi.
__global__ __launch_bounds__(128) void k_tc2(
    const us* __restrict__ Gh,
    const us* __restrict__ WTh, const us* __restrict__ WTl,
    const float* __restrict__ tb1, const float* __restrict__ tb2, const float* __restrict__ tb3,
    us* __restrict__ T2)
{
    int tid = threadIdx.x;
    int lane = tid & 63;
    int w = tid >> 6;
    int nl = lane & 31;
    size_t laneoff = (size_t)lane * 8;
    int i = blockIdx.x;
    int vb = (i & 7) * 288 + (i >> 3);
    int bt36 = vb >> 1, ntile = vb & 1;
    int b = bt36 / TT2, t = bt36 % TT2;

    const us* A[3];
#pragma unroll
    for (int k3 = 0; k3 < 3; k3++)
        A[k3] = Gh + (size_t)(b * TT + t + k3) * 8192 + (size_t)ntile * 4096 + laneoff;
    const us* Bh[3];
    const us* Bl[3];
#pragma unroll
    for (int g3 = 0; g3 < 3; g3++) {
        size_t cb = (size_t)(g3 * 2 + w) * 12288 + laneoff;
        Bh[g3] = WTh + cb;
        Bl[g3] = WTl + cb;
    }

    f32x16 aP, aQ, aR;
#pragma unroll
    for (int r = 0; r < 16; r++) { aP[r] = 0.f; aQ[r] = 0.f; aR[r] = 0.f; }

#pragma unroll
    for (int k3 = 0; k3 < 3; k3++) {
#pragma unroll
        for (int ls = 0; ls < 8; ls++) {
            int offB = (k3 * 8 + ls) * 512;
            s16x8 a0 = *(const s16x8*)(A[k3] + ls * 512);
            s16x8 ph = *(const s16x8*)(Bh[0] + offB);
            s16x8 pl = *(const s16x8*)(Bl[0] + offB);
            s16x8 qh = *(const s16x8*)(Bh[1] + offB);
            s16x8 ql = *(const s16x8*)(Bl[1] + offB);
            s16x8 rh = *(const s16x8*)(Bh[2] + offB);
            s16x8 rl = *(const s16x8*)(Bl[2] + offB);
            aP = MFMA(a0, ph, aP); aP = MFMA(a0, pl, aP);
            aQ = MFMA(a0, qh, aQ); aQ = MFMA(a0, ql, aQ);
            aR = MFMA(a0, rh, aR); aR = MFMA(a0, rl, aR);
        }
    }

    int o = w * 32 + nl;
    float bP = tb1[o], bQ = tb2[o], bR = tb3[o];
    int rbase = (lane >> 5) * 4;
#pragma unroll
    for (int r = 0; r < 16; r++) {
        int m = (r & 3) + 8 * (r >> 2) + rbase;
        int node = ntile * 32 + m;
        if (node < NN) {
            float P = aP[r] + bP, Q = aQ[r] + bQ, R = aR[r] + bR;
            float sg = 1.f / (1.f + expf(-Q));
            float v = P * sg + R;
            v = v > 0.f ? v : 0.f;
            T2[((size_t)bt36 * NN + node) * CO + o] = (us)f2bf_u(v);
        }
    }
}

// ---------------- kernel 4: BN partial sums (bf16 T2) ----------------
__global__ __launch_bounds__(256) void k_bnpart(const us* __restrict__ T2, float* __restrict__ partial)
{
    int n = blockIdx.x >> 3, c = blockIdx.x & 7;
    int tid = threadIdx.x;
    float s = 0.f, ss = 0.f;
    for (int i = tid; i < 144 * 64; i += 256) {
        int bt = c * 144 + (i >> 6), o = i & 63;
        float v = bfu2f(T2[((size_t)bt * NN + n) * CO + o]);
        s += v; ss += v * v;
    }
    for (int off = 32; off > 0; off >>= 1) { s += __shfl_down(s, off, 64); ss += __shfl_down(ss, off, 64); }
    __shared__ float rs[4], rss[4];
    int lane = tid & 63, wv = tid >> 6;
    if (lane == 0) { rs[wv] = s; rss[wv] = ss; }
    __syncthreads();
    if (tid == 0) {
        partial[n * 8 + c] = rs[0] + rs[1] + rs[2] + rs[3];
        partial[400 + n * 8 + c] = rss[0] + rss[1] + rss[2] + rss[3];
    }
}

// ---------------- kernel 5: BN finalize ----------------
__global__ __launch_bounds__(64) void k_bnfin(const float* __restrict__ partial, float* __restrict__ stats)
{
    int n = threadIdx.x;
    if (n < NN) {
        float s = 0.f, ss = 0.f;
#pragma unroll
        for (int c = 0; c < 8; c++) { s += partial[n * 8 + c]; ss += partial[400 + n * 8 + c]; }
        const float inv = 1.f / (float)(BB * TT2 * CO);
        float m = s * inv;
        float var = ss * inv - m * m;
        stats[n] = m;
        stats[64 + n] = rsqrtf(var + 1e-5f);
    }
}

// ---------------- kernel 6: fused windowed t-sums + conv3 GEMM + pool ----------------
__global__ __launch_bounds__(256) void k_upool(
    const us* __restrict__ T2, const float* __restrict__ stats,
    const float* __restrict__ gamma, const float* __restrict__ beta,
    const float* __restrict__ W3, float* __restrict__ pooled)
{
    __shared__ __align__(16) float Ul[48 * 36 + 32];
    __shared__ float Ws[128 * 9];
    int blk = blockIdx.x;             // 200 blocks
    int jc = blk * 16;
    int n0 = jc >> 6;
    int tid = threadIdx.x;
    float mn = stats[n0], is = stats[64 + n0];
    float sc = is * gamma[n0];
    float off = (float)TPOOL * beta[n0] - (float)TPOOL * mn * sc;

    {
        int j = tid & 15, b0 = tid >> 4;
#pragma unroll
        for (int bp = 0; bp < 2; bp++) {
            int bb = b0 + 16 * bp;
            const us* p = T2 + (size_t)bb * TT2 * NCO + jc + j;
            float s0 = 0.f;
            for (int t = 0; t < TPOOL; t++) s0 += bfu2f(p[(size_t)t * NCO]);
            float s1 = s0 - bfu2f(p[0]) + bfu2f(p[(size_t)34 * NCO]);
            float s2 = s1 - bfu2f(p[(size_t)1 * NCO]) + bfu2f(p[(size_t)35 * NCO]);
            Ul[(0 * 16 + j) * 36 + bb] = s0 * sc + off;
            Ul[(1 * 16 + j) * 36 + bb] = s1 * sc + off;
            Ul[(2 * 16 + j) * 36 + bb] = s2 * sc + off;
        }
    }
    __syncthreads();

    int o = tid & 127, bq = tid >> 7;
    float acc[16];
#pragma unroll
    for (int i = 0; i < 16; i++) acc[i] = 0.f;

    for (int kjc = 0; kjc < 48; kjc += 8) {
        __syncthreads();
#pragma unroll
        for (int p4 = 0; p4 < 4; p4++) {
            int idx = p4 * 256 + tid;
            int oo = idx >> 3, q = idx & 7;
            int kj = kjc + q;
            Ws[oo * 9 + q] = W3[(size_t)oo * 9600 + (kj >> 4) * 3200 + jc + (kj & 15)];
        }
        __syncthreads();
#pragma unroll
        for (int q = 0; q < 8; q++) {
            float wv = Ws[o * 9 + q];
            const float* up = &Ul[(kjc + q) * 36 + bq * 16];
#pragma unroll
            for (int i4 = 0; i4 < 4; i4++) {
                float4 u = *(const float4*)(up + i4 * 4);
                acc[i4 * 4 + 0] += wv * u.x;
                acc[i4 * 4 + 1] += wv * u.y;
                acc[i4 * 4 + 2] += wv * u.z;
                acc[i4 * 4 + 3] += wv * u.w;
            }
        }
    }
#pragma unroll
    for (int i = 0; i < 16; i++)
        atomicAdd(&pooled[(size_t)(bq * 16 + i) * 128 + o], acc[i]);
}

// ---------------- kernel 7: final FC — f1_w read exactly once ----------------
// block: 8 q-cols x 32 b. pb (pooled/34 + conv3_b) staged in LDS, stride 129 (bank-safe).
__global__ __launch_bounds__(256) void k_final(
    const float* __restrict__ pooled, const float* __restrict__ b3c,
    const float* __restrict__ f1w, const float* __restrict__ f1b,
    float* __restrict__ out)
{
    __shared__ float pb[32 * 129];
    int tid = threadIdx.x;
    const float inv = 1.f / (float)TPOOL;
    for (int i = tid; i < 4096; i += 256) {
        int b = i >> 7, o = i & 127;
        pb[b * 129 + o] = pooled[b * 128 + o] * inv + b3c[o];
    }
    __syncthreads();
    int q = blockIdx.x * 8 + (tid & 7);
    int b = tid >> 3;
    float acc = f1b[q];
    const float* wq = f1w + q;
    const float* pbb = pb + b * 129;
#pragma unroll 4
    for (int o = 0; o < 128; o++) acc += pbb[o] * wq[(size_t)o * NCO];
    out[(size_t)b * NCO + q] = acc;
}

// ---------------- launch ----------------
extern "C" void kernel_launch(void* const* d_in, const int* in_sizes, int n_in,
                              void* d_out, int out_size, void* d_ws, size_t ws_size,
                              hipStream_t stream)
{
    const float* X       = (const float*)d_in[0];
    const int*   EI      = (const int*)d_in[1];
    const float* tc1_w1  = (const float*)d_in[2];
    const float* tc1_b1  = (const float*)d_in[3];
    const float* tc1_w2  = (const float*)d_in[4];
    const float* tc1_b2  = (const float*)d_in[5];
    const float* tc1_w3  = (const float*)d_in[6];
    const float* tc1_b3  = (const float*)d_in[7];
    const float* cheb_w  = (const float*)d_in[8];
    const float* cheb_b  = (const float*)d_in[9];
    const float* tc2_w1  = (const float*)d_in[10];
    const float* tc2_b1  = (const float*)d_in[11];
    const float* tc2_w2  = (const float*)d_in[12];
    const float* tc2_b2  = (const float*)d_in[13];
    const float* tc2_w3  = (const float*)d_in[14];
    const float* tc2_b3  = (const float*)d_in[15];
    const float* bn_g    = (const float*)d_in[16];
    const float* bn_b    = (const float*)d_in[17];
    const float* conv3_w = (const float*)d_in[18];
    const float* conv3_b = (const float*)d_in[19];
    const float* f1_w    = (const float*)d_in[20];
    const float* f1_b    = (const float*)d_in[21];

    char* base = (char*)d_ws;
    us*    Gh     = (us*)base;                                   // 19,922,944 B
    us*    T2     = (us*)(base + PB_BYTES);                      // 7,372,800 B (bf16)
    float* pooled = (float*)(base + PB_BYTES + 7372800);         // 16,384 B
    float* stats  = (float*)(base + PB_BYTES + 7389184);         // 512 B
    float* partial= (float*)(base + PB_BYTES + 7389696);         // 3,200 B
    us*    VTh    = (us*)(base + PB_BYTES + 7392896);
    us*    VTl    = VTh + 49152;
    us*    WTh    = VTl + 49152;
    us*    WTl    = WTh + 73728;

    k_wprep<<<496, 256, 0, stream>>>(cheb_w, tc2_w1, tc2_w2, tc2_w3, VTh, VTl, WTh, WTl, pooled);
    k_cheb<<<SS, 256, 0, stream>>>(EI, X, tc1_w1, tc1_b1, tc1_w2, tc1_b2, tc1_w3, tc1_b3,
                                   VTh, VTl, cheb_b, Gh);
    k_tc2<<<2304, 128, 0, stream>>>(Gh, WTh, WTl, tc2_b1, tc2_b2, tc2_b3, T2);
    k_bnpart<<<NN * 8, 256, 0, stream>>>(T2, partial);
    k_bnfin<<<1, 64, 0, stream>>>(partial, stats);
    k_upool<<<200, 256, 0, stream>>>(T2, stats, bn_g, bn_b, conv3_w, pooled);
    k_final<<<NCO / 8, 256, 0, stream>>>(pooled, conv3_b, f1_w, f1_b, (float*)d_out);
}